// Round 2
// baseline (18818.309 us; speedup 1.0000x reference)
//
#include <hip/hip_runtime.h>
#include <hip/hip_bf16.h>
#include <math.h>

#define N_NODES 50000
#define NE      100000
#define NH      8
#define HD      96
#define FDIM    768
#define NB      256
#define NC      31

typedef __hip_bfloat16 bf16;

__device__ inline float u2f(unsigned short u) { return __uint_as_float(((unsigned int)u) << 16); }

// ---------------- convert f32 -> bf16 ----------------
__global__ __launch_bounds__(256) void cvt_kernel(const float* __restrict__ in,
                                                  bf16* __restrict__ out) {
    const size_t total = (size_t)N_NODES * FDIM;
    const size_t stride = (size_t)gridDim.x * blockDim.x;
    for (size_t i = blockIdx.x * (size_t)blockDim.x + threadIdx.x; i < total; i += stride) {
        out[i] = __float2bfloat16(in[i]);
    }
}

// ---------------- GEMM: C[M,768](bf16) = A[M,768](bf16) @ W[768,768](f32) + bias ----------------
#define BM 128
#define BN 128
#define BK 16

__global__ __launch_bounds__(256) void gemm_bias(const bf16* __restrict__ A,
                                                 const float* __restrict__ W,
                                                 const float* __restrict__ bias,
                                                 bf16* __restrict__ Cmat, int M) {
    __shared__ float As[BK][BM + 8];  // [k][m]
    __shared__ float Ws[BK][BN + 8];  // [k][n]
    const int t  = threadIdx.x;
    const int tx = t & 15;   // n-block
    const int ty = t >> 4;   // m-block
    const int m0 = blockIdx.x * BM;
    const int n0 = blockIdx.y * BN;

    float acc[8][8];
#pragma unroll
    for (int i = 0; i < 8; ++i)
#pragma unroll
        for (int j = 0; j < 8; ++j) acc[i][j] = 0.f;

    for (int k0 = 0; k0 < FDIM; k0 += BK) {
        // Stage A tile (BM x BK) transposed -> As[k][m]
        {
            const int c  = t & 15;
            const int r0 = t >> 4;
#pragma unroll
            for (int p = 0; p < 8; ++p) {
                const int r  = r0 + p * 16;
                const int gm = m0 + r;
                float v = 0.f;
                if (gm < M) v = __bfloat162float(A[(size_t)gm * FDIM + k0 + c]);
                As[c][r] = v;
            }
        }
        // Stage W tile (BK x BN)
        {
            const int c   = t & 127;
            const int kk0 = t >> 7;
#pragma unroll
            for (int p = 0; p < 8; ++p) {
                const int kk = kk0 + p * 2;
                Ws[kk][c] = W[(size_t)(k0 + kk) * FDIM + n0 + c];
            }
        }
        __syncthreads();
#pragma unroll
        for (int k = 0; k < BK; ++k) {
            float a[8], b[8];
            *(float4*)&a[0] = *(const float4*)&As[k][ty * 8];
            *(float4*)&a[4] = *(const float4*)&As[k][ty * 8 + 4];
            *(float4*)&b[0] = *(const float4*)&Ws[k][tx * 8];
            *(float4*)&b[4] = *(const float4*)&Ws[k][tx * 8 + 4];
#pragma unroll
            for (int i = 0; i < 8; ++i)
#pragma unroll
                for (int j = 0; j < 8; ++j) acc[i][j] += a[i] * b[j];
        }
        __syncthreads();
    }

#pragma unroll
    for (int i = 0; i < 8; ++i) {
        const int gm = m0 + ty * 8 + i;
        if (gm < M) {
#pragma unroll
            for (int j = 0; j < 8; ++j) {
                const int gn = n0 + tx * 8 + j;
                Cmat[(size_t)gm * FDIM + gn] = __float2bfloat16(acc[i][j] + bias[gn]);
            }
        }
    }
}

// ---------------- ordered-uint float max encoding ----------------
__device__ inline unsigned int enc_f(float f) {
    unsigned int u = __float_as_uint(f);
    return (u & 0x80000000u) ? ~u : (u | 0x80000000u);
}
__device__ inline float dec_f(unsigned int u) {
    return __uint_as_float((u & 0x80000000u) ? (u ^ 0x80000000u) : ~u);
}

// ---------------- edge scoring ----------------
__global__ __launch_bounds__(256) void score_kernel(const bf16* __restrict__ fs,
                                                    const bf16* __restrict__ fd,
                                                    const float* __restrict__ attn,
                                                    const int* __restrict__ src,
                                                    const int* __restrict__ dst,
                                                    float* __restrict__ score,
                                                    unsigned int* __restrict__ mx) {
    const int wave = threadIdx.x >> 6;
    const int lane = threadIdx.x & 63;
    const int e = blockIdx.x * 4 + wave;
    if (e >= NE) return;
    const int s = src[e], d = dst[e];
    const ushort4* pfs = (const ushort4*)(fs + (size_t)s * FDIM + lane * 12);
    const ushort4* pfd = (const ushort4*)(fd + (size_t)d * FDIM + lane * 12);
    const float4* pat = (const float4*)(attn + lane * 12);
    float partial = 0.f;
#pragma unroll
    for (int q = 0; q < 3; ++q) {
        ushort4 av = pfs[q], bv = pfd[q];
        float4 w = pat[q];
        float x;
        x = u2f(av.x) + u2f(bv.x); x = (x > 0.f) ? x : 0.2f * x; partial += x * w.x;
        x = u2f(av.y) + u2f(bv.y); x = (x > 0.f) ? x : 0.2f * x; partial += x * w.y;
        x = u2f(av.z) + u2f(bv.z); x = (x > 0.f) ? x : 0.2f * x; partial += x * w.z;
        x = u2f(av.w) + u2f(bv.w); x = (x > 0.f) ? x : 0.2f * x; partial += x * w.w;
    }
    partial += __shfl_xor(partial, 1);
    partial += __shfl_xor(partial, 2);
    partial += __shfl_xor(partial, 4);
    if ((lane & 7) == 0) {
        const int hh = lane >> 3;
        score[e * NH + hh] = partial;
        atomicMax(&mx[d * NH + hh], enc_f(partial));
    }
}

// ---------------- ex = exp(score - mx[dst]); den[dst] += ex ----------------
__global__ __launch_bounds__(256) void ex_kernel(const int* __restrict__ dst,
                                                 float* __restrict__ score,
                                                 const unsigned int* __restrict__ mx,
                                                 float* __restrict__ den) {
    const int tid = blockIdx.x * 256 + threadIdx.x;
    if (tid >= NE * NH) return;
    const int e = tid >> 3, hh = tid & 7;
    const int d = dst[e];
    const float m = dec_f(mx[d * NH + hh]);
    const float ex = expf(score[tid] - m);
    score[tid] = ex;
    atomicAdd(&den[d * NH + hh], ex);
}

// ---------------- o[dst] += fs[src] * alpha ----------------
__global__ __launch_bounds__(256) void agg_kernel(const bf16* __restrict__ fs,
                                                  const float* __restrict__ ex,
                                                  const float* __restrict__ den,
                                                  const int* __restrict__ src,
                                                  const int* __restrict__ dst,
                                                  float* __restrict__ o) {
    const int wave = threadIdx.x >> 6;
    const int lane = threadIdx.x & 63;
    const int e = blockIdx.x * 4 + wave;
    if (e >= NE) return;
    const int s = src[e], d = dst[e];
    const int hh = lane >> 3;
    const float alpha = ex[e * NH + hh] / den[d * NH + hh];
    const ushort4* pfs = (const ushort4*)(fs + (size_t)s * FDIM + lane * 12);
    float* po = o + (size_t)d * FDIM + lane * 12;
#pragma unroll
    for (int q = 0; q < 3; ++q) {
        ushort4 a = pfs[q];
        atomicAdd(po + q * 4 + 0, u2f(a.x) * alpha);
        atomicAdd(po + q * 4 + 1, u2f(a.y) * alpha);
        atomicAdd(po + q * 4 + 2, u2f(a.z) * alpha);
        atomicAdd(po + q * 4 + 3, u2f(a.w) * alpha);
    }
}

// ---------------- residual: h = bf16(h + o) ----------------
__global__ __launch_bounds__(256) void residual_kernel(bf16* __restrict__ h,
                                                       const float* __restrict__ o) {
    const size_t total = (size_t)N_NODES * FDIM / 4;
    const size_t stride = (size_t)gridDim.x * blockDim.x;
    for (size_t i = blockIdx.x * (size_t)blockDim.x + threadIdx.x; i < total; i += stride) {
        ushort4 hv = ((const ushort4*)h)[i];
        float4 ov = ((const float4*)o)[i];
        ushort4 r;
        r.x = __bfloat16_as_ushort(__float2bfloat16(u2f(hv.x) + ov.x));
        r.y = __bfloat16_as_ushort(__float2bfloat16(u2f(hv.y) + ov.y));
        r.z = __bfloat16_as_ushort(__float2bfloat16(u2f(hv.z) + ov.z));
        r.w = __bfloat16_as_ushort(__float2bfloat16(u2f(hv.w) + ov.w));
        ((ushort4*)h)[i] = r;
    }
}

// ---------------- MLP head ----------------
__global__ __launch_bounds__(256) void head_kernel(const bf16* __restrict__ h,
                                                   const int* __restrict__ gsi,
                                                   const float* __restrict__ fc1w,
                                                   const float* __restrict__ fc1b,
                                                   const float* __restrict__ fc2w,
                                                   const float* __restrict__ fc2b,
                                                   float* __restrict__ out) {
    __shared__ float fe[FDIM];
    __shared__ float hid[256];
    const int b = blockIdx.x, t = threadIdx.x;
    const int node = gsi[b];
    for (int i = t; i < FDIM; i += 256) fe[i] = __bfloat162float(h[(size_t)node * FDIM + i]);
    __syncthreads();
    float acc = fc1b[t];
    for (int k = 0; k < FDIM; ++k) acc += fe[k] * fc1w[k * 256 + t];
    hid[t] = (acc > 0.f) ? acc : 0.f;
    __syncthreads();
    if (t < NC) {
        float acc2 = fc2b[t];
        for (int k = 0; k < 256; ++k) acc2 += hid[k] * fc2w[k * NC + t];
        out[1 + b * NC + t] = acc2;
    }
}

// ---------------- loss ----------------
__global__ __launch_bounds__(256) void loss_kernel(const float* __restrict__ logits,
                                                   const int* __restrict__ labels,
                                                   float* __restrict__ out) {
    __shared__ float red[256];
    const int b = threadIdx.x;
    float m = -INFINITY;
    for (int c = 0; c < NC; ++c) m = fmaxf(m, logits[b * NC + c]);
    float sum = 0.f;
    for (int c = 0; c < NC; ++c) sum += expf(logits[b * NC + c] - m);
    const float lse = m + logf(sum);
    const float ll = logits[b * NC + labels[b]];
    red[b] = lse - ll;
    __syncthreads();
    for (int s = 128; s > 0; s >>= 1) {
        if (b < s) red[b] += red[b + s];
        __syncthreads();
    }
    if (b == 0) out[0] = red[0] / (float)NB;
}

extern "C" void kernel_launch(void* const* d_in, const int* in_sizes, int n_in,
                              void* d_out, int out_size, void* d_ws, size_t ws_size,
                              hipStream_t stream) {
    const float* feats = (const float*)d_in[0];
    const float* fc1w  = (const float*)d_in[11];
    const float* fc1b  = (const float*)d_in[12];
    const float* fc2w  = (const float*)d_in[13];
    const float* fc2b  = (const float*)d_in[14];
    const int* gsi     = (const int*)d_in[19];
    const int* labels  = (const int*)d_in[20];

    const size_t NF = (size_t)N_NODES * FDIM;
    char* p = (char*)d_ws;
    bf16* h  = (bf16*)p;            p += NF * 2;
    bf16* fs = (bf16*)p;            p += NF * 2;
    bf16* fd = (bf16*)p;            p += NF * 2;
    float* o = (float*)p;           p += NF * 4;
    float* score = (float*)p;       p += (size_t)NE * NH * 4;
    unsigned int* mx = (unsigned int*)p; p += (size_t)N_NODES * NH * 4;
    float* den = (float*)p;

    cvt_kernel<<<2048, 256, 0, stream>>>(feats, h);

    dim3 gemm_grid((N_NODES + BM - 1) / BM, FDIM / BN);
    const int edge_blocks = (NE + 3) / 4;

    for (int l = 0; l < 2; ++l) {
        hipMemsetAsync(o, 0, sizeof(float) * NF, stream);
        for (int r = 0; r < 2; ++r) {
            const float* Wsrc = (const float*)d_in[r == 0 ? 1 : 6] + (size_t)l * FDIM * FDIM;
            const float* bsrc = (const float*)d_in[r == 0 ? 2 : 7] + (size_t)l * FDIM;
            const float* Wdst = (const float*)d_in[r == 0 ? 3 : 8] + (size_t)l * FDIM * FDIM;
            const float* bdst = (const float*)d_in[r == 0 ? 4 : 9] + (size_t)l * FDIM;
            const float* attn = (const float*)d_in[r == 0 ? 5 : 10] + (size_t)l * FDIM;
            const int* src = (const int*)d_in[r == 0 ? 15 : 17];
            const int* dst = (const int*)d_in[r == 0 ? 16 : 18];

            hipMemsetAsync(mx, 0, sizeof(unsigned int) * (size_t)N_NODES * NH, stream);
            hipMemsetAsync(den, 0, sizeof(float) * (size_t)N_NODES * NH, stream);

            gemm_bias<<<gemm_grid, 256, 0, stream>>>(h, Wsrc, bsrc, fs, N_NODES);
            gemm_bias<<<gemm_grid, 256, 0, stream>>>(h, Wdst, bdst, fd, N_NODES);
            score_kernel<<<edge_blocks, 256, 0, stream>>>(fs, fd, attn, src, dst, score, mx);
            ex_kernel<<<(NE * NH + 255) / 256, 256, 0, stream>>>(dst, score, mx, den);
            agg_kernel<<<edge_blocks, 256, 0, stream>>>(fs, score, den, src, dst, o);
        }
        residual_kernel<<<2048, 256, 0, stream>>>(h, o);
    }

    head_kernel<<<NB, 256, 0, stream>>>(h, gsi, fc1w, fc1b, fc2w, fc2b, (float*)d_out);
    loss_kernel<<<1, 256, 0, stream>>>((float*)d_out + 1, labels, (float*)d_out);
}

// Round 3
// 1858.148 us; speedup vs baseline: 10.1275x; 10.1275x over previous
//
#include <hip/hip_runtime.h>
#include <hip/hip_bf16.h>
#include <math.h>

#define N_NODES 50000
#define NE      100000
#define NH      8
#define HD      96
#define FDIM    768
#define NB      256
#define NC      31

typedef __hip_bfloat16 bf16;
typedef __attribute__((ext_vector_type(8))) short bf16x8;
typedef __attribute__((ext_vector_type(4))) float f32x4;

__device__ inline float u2f(unsigned short u) { return __uint_as_float(((unsigned int)u) << 16); }

__device__ inline void load_lds16(const void* g, void* l) {
    __builtin_amdgcn_global_load_lds(
        (const __attribute__((address_space(1))) void*)g,
        (__attribute__((address_space(3))) void*)l, 16, 0, 0);
}

// ---------------- convert f32 -> bf16 ----------------
__global__ __launch_bounds__(256) void cvt_kernel(const float* __restrict__ in,
                                                  bf16* __restrict__ out) {
    const size_t total = (size_t)N_NODES * FDIM;
    const size_t stride = (size_t)gridDim.x * blockDim.x;
    for (size_t i = blockIdx.x * (size_t)blockDim.x + threadIdx.x; i < total; i += stride)
        out[i] = __float2bfloat16(in[i]);
}

// ---------------- weight transpose+convert: dst[n][k] = bf16(src[k][n]) ----------------
__global__ __launch_bounds__(256) void twt_kernel(const float* __restrict__ src,
                                                  bf16* __restrict__ dst) {
    __shared__ float tile[32][33];
    const int tx = threadIdx.x & 31, ty = threadIdx.x >> 5;
    const int x0 = blockIdx.x * 32, y0 = blockIdx.y * 32;
#pragma unroll
    for (int q = 0; q < 4; ++q)
        tile[ty + q * 8][tx] = src[(size_t)(y0 + ty + q * 8) * FDIM + x0 + tx];
    __syncthreads();
#pragma unroll
    for (int q = 0; q < 4; ++q)
        dst[(size_t)(x0 + ty + q * 8) * FDIM + y0 + tx] = __float2bfloat16(tile[tx][ty + q * 8]);
}

// ---------------- MFMA GEMM: C[M,768](bf16) = A[M,768](bf16) @ Wt^T + bias ----------------
// Wt is [N=768][K=768] bf16 (pre-transposed weights).
#define GBM 128
#define GBN 128
#define GBK 64

__global__ __launch_bounds__(256) void gemm_mfma(const bf16* __restrict__ A,
                                                 const bf16* __restrict__ Wt,
                                                 const float* __restrict__ bias,
                                                 bf16* __restrict__ C, int M) {
    __shared__ __align__(16) short Abuf[GBM * GBK];  // 16 KB, swizzled k-chunks
    __shared__ __align__(16) short Bbuf[GBN * GBK];  // 16 KB
    const int t = threadIdx.x;
    const int wid = t >> 6, lane = t & 63;
    const int wr = wid >> 1, wc = wid & 1;
    const int lr = lane & 15, lk = lane >> 4;
    const int m0 = blockIdx.x * GBM, n0 = blockIdx.y * GBN;

    const f32x4 zero4 = {0.f, 0.f, 0.f, 0.f};
    f32x4 acc[4][4];
#pragma unroll
    for (int i = 0; i < 4; ++i)
#pragma unroll
        for (int j = 0; j < 4; ++j) acc[i][j] = zero4;

    for (int kt = 0; kt < FDIM / GBK; ++kt) {
        const int k0 = kt * GBK;
        // Stage A and B tiles: slot s=(row, chunk p); LDS linear, source chunk (p ^ (row&7)).
#pragma unroll
        for (int i = 0; i < 4; ++i) {
            const int s = i * 256 + t;
            const int ldsoff = (i * 256 + wid * 64) * 16;  // wave-uniform base
            {
                const int m = s >> 3, p = s & 7;
                int row = m0 + m; if (row >= M) row = M - 1;
                const int col = k0 + ((p ^ (m & 7)) << 3);
                load_lds16(A + (size_t)row * FDIM + col, (char*)Abuf + ldsoff);
            }
            {
                const int n = s >> 3, p = s & 7;
                const int col = k0 + ((p ^ (n & 7)) << 3);
                load_lds16(Wt + (size_t)(n0 + n) * FDIM + col, (char*)Bbuf + ldsoff);
            }
        }
        __syncthreads();
#pragma unroll
        for (int kh = 0; kh < 2; ++kh) {
            bf16x8 av[4], bv[4];
            const int c = kh * 4 + lk;
#pragma unroll
            for (int i = 0; i < 4; ++i) {
                const int m = wr * 64 + i * 16 + lr;
                av[i] = *(const bf16x8*)((const char*)Abuf + m * 128 + ((c ^ (m & 7)) << 4));
            }
#pragma unroll
            for (int j = 0; j < 4; ++j) {
                const int n = wc * 64 + j * 16 + lr;
                bv[j] = *(const bf16x8*)((const char*)Bbuf + n * 128 + ((c ^ (n & 7)) << 4));
            }
#pragma unroll
            for (int i = 0; i < 4; ++i)
#pragma unroll
                for (int j = 0; j < 4; ++j)
                    acc[i][j] = __builtin_amdgcn_mfma_f32_16x16x32_bf16(av[i], bv[j], acc[i][j], 0, 0, 0);
        }
        __syncthreads();
    }
    // Epilogue: D mapping col=lane&15, row=(lane>>4)*4+reg
#pragma unroll
    for (int j = 0; j < 4; ++j) {
        const int col = n0 + wc * 64 + j * 16 + lr;
        const float bj = bias[col];
#pragma unroll
        for (int i = 0; i < 4; ++i) {
#pragma unroll
            for (int r = 0; r < 4; ++r) {
                const int row = m0 + wr * 64 + i * 16 + lk * 4 + r;
                if (row < M) C[(size_t)row * FDIM + col] = __float2bfloat16(acc[i][j][r] + bj);
            }
        }
    }
}

// ---------------- CSR build ----------------
__global__ __launch_bounds__(256) void hist_kernel(const int* __restrict__ dst, int* __restrict__ deg) {
    const int e = blockIdx.x * 256 + threadIdx.x;
    if (e < NE) atomicAdd(&deg[dst[e]], 1);
}

__global__ __launch_bounds__(256) void scan_kernel(const int* __restrict__ deg,
                                                   int* __restrict__ rowp,
                                                   int* __restrict__ cursor) {
    __shared__ int pref[257];
    const int t = threadIdx.x;
    const int CH = (N_NODES + 255) / 256;
    const int b0 = t * CH;
    const int b1 = (b0 + CH < N_NODES) ? b0 + CH : N_NODES;
    int s = 0;
    for (int i = b0; i < b1; ++i) s += deg[i];
    __shared__ int part[256];
    part[t] = s;
    __syncthreads();
    if (t == 0) {
        int acc = 0;
        for (int i = 0; i < 256; ++i) { pref[i] = acc; acc += part[i]; }
        pref[256] = acc;
    }
    __syncthreads();
    int run = pref[t];
    for (int i = b0; i < b1; ++i) { rowp[i] = run; cursor[i] = run; run += deg[i]; }
    if (t == 255) rowp[N_NODES] = run;
}

__global__ __launch_bounds__(256) void scatter_kernel(const int* __restrict__ dst,
                                                      int* __restrict__ cursor,
                                                      int* __restrict__ eid) {
    const int e = blockIdx.x * 256 + threadIdx.x;
    if (e < NE) {
        const int p = atomicAdd(&cursor[dst[e]], 1);
        eid[p] = e;
    }
}

// ---------------- edge scoring: raw score[e,h] ----------------
__global__ __launch_bounds__(256) void score_kernel(const bf16* __restrict__ fs,
                                                    const bf16* __restrict__ fd,
                                                    const float* __restrict__ attn,
                                                    const int* __restrict__ src,
                                                    const int* __restrict__ dst,
                                                    float* __restrict__ score) {
    const int wave = threadIdx.x >> 6;
    const int lane = threadIdx.x & 63;
    const int e = blockIdx.x * 4 + wave;
    if (e >= NE) return;
    const int s = src[e], d = dst[e];
    const ushort4* pfs = (const ushort4*)(fs + (size_t)s * FDIM + lane * 12);
    const ushort4* pfd = (const ushort4*)(fd + (size_t)d * FDIM + lane * 12);
    const float4* pat = (const float4*)(attn + lane * 12);
    float partial = 0.f;
#pragma unroll
    for (int q = 0; q < 3; ++q) {
        ushort4 av = pfs[q], bv = pfd[q];
        float4 w = pat[q];
        float x;
        x = u2f(av.x) + u2f(bv.x); x = (x > 0.f) ? x : 0.2f * x; partial += x * w.x;
        x = u2f(av.y) + u2f(bv.y); x = (x > 0.f) ? x : 0.2f * x; partial += x * w.y;
        x = u2f(av.z) + u2f(bv.z); x = (x > 0.f) ? x : 0.2f * x; partial += x * w.z;
        x = u2f(av.w) + u2f(bv.w); x = (x > 0.f) ? x : 0.2f * x; partial += x * w.w;
    }
    partial += __shfl_xor(partial, 1);
    partial += __shfl_xor(partial, 2);
    partial += __shfl_xor(partial, 4);
    if ((lane & 7) == 0) score[e * NH + (lane >> 3)] = partial;
}

// ---------------- CSR aggregation: wave per dst node, no atomics ----------------
// mode 0: o[n] = bf16(sum)          (relation A)
// mode 1: h[n] = bf16(h + o + sum)  (relation B + fused residual)
__global__ __launch_bounds__(256) void agg_csr_kernel(const bf16* __restrict__ fs,
                                                      const float* __restrict__ score,
                                                      const int* __restrict__ rowp,
                                                      const int* __restrict__ eid,
                                                      const int* __restrict__ src,
                                                      bf16* __restrict__ o,
                                                      bf16* __restrict__ h,
                                                      int mode) {
    const int wid = threadIdx.x >> 6;
    const int lane = threadIdx.x & 63;
    const int n = blockIdx.x * 4 + wid;
    if (n >= N_NODES) return;
    const int hh = lane >> 3;
    const int beg = rowp[n], end = rowp[n + 1];

    float m = -INFINITY;
    for (int i = beg; i < end; ++i) m = fmaxf(m, score[eid[i] * NH + hh]);
    float den = 0.f;
    for (int i = beg; i < end; ++i) den += expf(score[eid[i] * NH + hh] - m);

    float acc[12];
#pragma unroll
    for (int j = 0; j < 12; ++j) acc[j] = 0.f;

    for (int i = beg; i < end; ++i) {
        const int e = eid[i];
        const float al = expf(score[e * NH + hh] - m) / den;
        const ushort4* pf = (const ushort4*)(fs + (size_t)src[e] * FDIM + lane * 12);
        const ushort4 a0 = pf[0], a1 = pf[1], a2 = pf[2];
        acc[0] += u2f(a0.x) * al; acc[1] += u2f(a0.y) * al; acc[2] += u2f(a0.z) * al; acc[3] += u2f(a0.w) * al;
        acc[4] += u2f(a1.x) * al; acc[5] += u2f(a1.y) * al; acc[6] += u2f(a1.z) * al; acc[7] += u2f(a1.w) * al;
        acc[8] += u2f(a2.x) * al; acc[9] += u2f(a2.y) * al; acc[10] += u2f(a2.z) * al; acc[11] += u2f(a2.w) * al;
    }

    const size_t base = (size_t)n * FDIM + lane * 12;
    if (mode == 0) {
        ushort4 r0, r1, r2;
        r0.x = __bfloat16_as_ushort(__float2bfloat16(acc[0]));  r0.y = __bfloat16_as_ushort(__float2bfloat16(acc[1]));
        r0.z = __bfloat16_as_ushort(__float2bfloat16(acc[2]));  r0.w = __bfloat16_as_ushort(__float2bfloat16(acc[3]));
        r1.x = __bfloat16_as_ushort(__float2bfloat16(acc[4]));  r1.y = __bfloat16_as_ushort(__float2bfloat16(acc[5]));
        r1.z = __bfloat16_as_ushort(__float2bfloat16(acc[6]));  r1.w = __bfloat16_as_ushort(__float2bfloat16(acc[7]));
        r2.x = __bfloat16_as_ushort(__float2bfloat16(acc[8]));  r2.y = __bfloat16_as_ushort(__float2bfloat16(acc[9]));
        r2.z = __bfloat16_as_ushort(__float2bfloat16(acc[10])); r2.w = __bfloat16_as_ushort(__float2bfloat16(acc[11]));
        ((ushort4*)(o + base))[0] = r0; ((ushort4*)(o + base))[1] = r1; ((ushort4*)(o + base))[2] = r2;
    } else {
        const ushort4* ph = (const ushort4*)(h + base);
        const ushort4* po = (const ushort4*)(o + base);
        ushort4 hv[3] = {ph[0], ph[1], ph[2]};
        ushort4 ov[3] = {po[0], po[1], po[2]};
        float v[12];
        v[0] = u2f(hv[0].x) + u2f(ov[0].x) + acc[0];  v[1] = u2f(hv[0].y) + u2f(ov[0].y) + acc[1];
        v[2] = u2f(hv[0].z) + u2f(ov[0].z) + acc[2];  v[3] = u2f(hv[0].w) + u2f(ov[0].w) + acc[3];
        v[4] = u2f(hv[1].x) + u2f(ov[1].x) + acc[4];  v[5] = u2f(hv[1].y) + u2f(ov[1].y) + acc[5];
        v[6] = u2f(hv[1].z) + u2f(ov[1].z) + acc[6];  v[7] = u2f(hv[1].w) + u2f(ov[1].w) + acc[7];
        v[8] = u2f(hv[2].x) + u2f(ov[2].x) + acc[8];  v[9] = u2f(hv[2].y) + u2f(ov[2].y) + acc[9];
        v[10] = u2f(hv[2].z) + u2f(ov[2].z) + acc[10]; v[11] = u2f(hv[2].w) + u2f(ov[2].w) + acc[11];
        ushort4 r0, r1, r2;
        r0.x = __bfloat16_as_ushort(__float2bfloat16(v[0]));  r0.y = __bfloat16_as_ushort(__float2bfloat16(v[1]));
        r0.z = __bfloat16_as_ushort(__float2bfloat16(v[2]));  r0.w = __bfloat16_as_ushort(__float2bfloat16(v[3]));
        r1.x = __bfloat16_as_ushort(__float2bfloat16(v[4]));  r1.y = __bfloat16_as_ushort(__float2bfloat16(v[5]));
        r1.z = __bfloat16_as_ushort(__float2bfloat16(v[6]));  r1.w = __bfloat16_as_ushort(__float2bfloat16(v[7]));
        r2.x = __bfloat16_as_ushort(__float2bfloat16(v[8]));  r2.y = __bfloat16_as_ushort(__float2bfloat16(v[9]));
        r2.z = __bfloat16_as_ushort(__float2bfloat16(v[10])); r2.w = __bfloat16_as_ushort(__float2bfloat16(v[11]));
        ((ushort4*)(h + base))[0] = r0; ((ushort4*)(h + base))[1] = r1; ((ushort4*)(h + base))[2] = r2;
    }
}

// ---------------- MLP head ----------------
__global__ __launch_bounds__(256) void head_kernel(const bf16* __restrict__ h,
                                                   const int* __restrict__ gsi,
                                                   const float* __restrict__ fc1w,
                                                   const float* __restrict__ fc1b,
                                                   const float* __restrict__ fc2w,
                                                   const float* __restrict__ fc2b,
                                                   float* __restrict__ out) {
    __shared__ float fe[FDIM];
    __shared__ float hid[256];
    const int b = blockIdx.x, t = threadIdx.x;
    const int node = gsi[b];
    for (int i = t; i < FDIM; i += 256) fe[i] = __bfloat162float(h[(size_t)node * FDIM + i]);
    __syncthreads();
    float acc = fc1b[t];
    for (int k = 0; k < FDIM; ++k) acc += fe[k] * fc1w[k * 256 + t];
    hid[t] = (acc > 0.f) ? acc : 0.f;
    __syncthreads();
    if (t < NC) {
        float acc2 = fc2b[t];
        for (int k = 0; k < 256; ++k) acc2 += hid[k] * fc2w[k * NC + t];
        out[1 + b * NC + t] = acc2;
    }
}

// ---------------- loss ----------------
__global__ __launch_bounds__(256) void loss_kernel(const float* __restrict__ logits,
                                                   const int* __restrict__ labels,
                                                   float* __restrict__ out) {
    __shared__ float red[256];
    const int b = threadIdx.x;
    float m = -INFINITY;
    for (int c = 0; c < NC; ++c) m = fmaxf(m, logits[b * NC + c]);
    float sum = 0.f;
    for (int c = 0; c < NC; ++c) sum += expf(logits[b * NC + c] - m);
    const float lse = m + logf(sum);
    const float ll = logits[b * NC + labels[b]];
    red[b] = lse - ll;
    __syncthreads();
    for (int s = 128; s > 0; s >>= 1) {
        if (b < s) red[b] += red[b + s];
        __syncthreads();
    }
    if (b == 0) out[0] = red[0] / (float)NB;
}

extern "C" void kernel_launch(void* const* d_in, const int* in_sizes, int n_in,
                              void* d_out, int out_size, void* d_ws, size_t ws_size,
                              hipStream_t stream) {
    const float* feats = (const float*)d_in[0];
    const float* fc1w  = (const float*)d_in[11];
    const float* fc1b  = (const float*)d_in[12];
    const float* fc2w  = (const float*)d_in[13];
    const float* fc2b  = (const float*)d_in[14];
    const int* gsi     = (const int*)d_in[19];
    const int* labels  = (const int*)d_in[20];

    const size_t NF = (size_t)N_NODES * FDIM;
    const size_t WSZ = (size_t)FDIM * FDIM;
    char* p = (char*)d_ws;
    bf16* h  = (bf16*)p;  p += NF * 2;
    bf16* fs = (bf16*)p;  p += NF * 2;
    bf16* fd = (bf16*)p;  p += NF * 2;
    bf16* o  = (bf16*)p;  p += NF * 2;
    bf16* Wt = (bf16*)p;  p += 8 * WSZ * 2;          // [rel*4 + l*2 + sd][768][768]
    float* score = (float*)p; p += (size_t)NE * NH * 4;
    int* deg[2];  int* rowp[2];  int* cursor[2];  int* eid[2];
    for (int r = 0; r < 2; ++r) {
        deg[r]    = (int*)p; p += (size_t)N_NODES * 4 + 256;
        rowp[r]   = (int*)p; p += ((size_t)N_NODES + 1) * 4 + 256;
        cursor[r] = (int*)p; p += (size_t)N_NODES * 4 + 256;
        eid[r]    = (int*)p; p += (size_t)NE * 4 + 256;
    }

    cvt_kernel<<<2048, 256, 0, stream>>>(feats, h);

    // Transpose+convert the 8 weight matrices.
    dim3 tgrid(FDIM / 32, FDIM / 32);
    for (int r = 0; r < 2; ++r)
        for (int l = 0; l < 2; ++l)
            for (int sd = 0; sd < 2; ++sd) {
                const float* src = (const float*)d_in[r == 0 ? (sd == 0 ? 1 : 3) : (sd == 0 ? 6 : 8)] + (size_t)l * WSZ;
                twt_kernel<<<tgrid, 256, 0, stream>>>(src, Wt + (size_t)(r * 4 + l * 2 + sd) * WSZ);
            }

    // Build CSR per relation (dst is layer-invariant).
    for (int r = 0; r < 2; ++r) {
        const int* dst = (const int*)d_in[r == 0 ? 16 : 18];
        hipMemsetAsync(deg[r], 0, sizeof(int) * N_NODES, stream);
        hist_kernel<<<(NE + 255) / 256, 256, 0, stream>>>(dst, deg[r]);
        scan_kernel<<<1, 256, 0, stream>>>(deg[r], rowp[r], cursor[r]);
        scatter_kernel<<<(NE + 255) / 256, 256, 0, stream>>>(dst, cursor[r], eid[r]);
    }

    dim3 gemm_grid((N_NODES + GBM - 1) / GBM, FDIM / GBN);
    const int edge_blocks = (NE + 3) / 4;
    const int node_blocks = (N_NODES + 3) / 4;

    for (int l = 0; l < 2; ++l) {
        for (int r = 0; r < 2; ++r) {
            const float* bsrc = (const float*)d_in[r == 0 ? 2 : 7] + (size_t)l * FDIM;
            const float* bdst = (const float*)d_in[r == 0 ? 4 : 9] + (size_t)l * FDIM;
            const float* attn = (const float*)d_in[r == 0 ? 5 : 10] + (size_t)l * FDIM;
            const int* src = (const int*)d_in[r == 0 ? 15 : 17];
            const int* dst = (const int*)d_in[r == 0 ? 16 : 18];
            const bf16* WtS = Wt + (size_t)(r * 4 + l * 2 + 0) * WSZ;
            const bf16* WtD = Wt + (size_t)(r * 4 + l * 2 + 1) * WSZ;

            gemm_mfma<<<gemm_grid, 256, 0, stream>>>(h, WtS, bsrc, fs, N_NODES);
            gemm_mfma<<<gemm_grid, 256, 0, stream>>>(h, WtD, bdst, fd, N_NODES);
            score_kernel<<<edge_blocks, 256, 0, stream>>>(fs, fd, attn, src, dst, score);
            agg_csr_kernel<<<node_blocks, 256, 0, stream>>>(fs, score, rowp[r], eid[r], src, o, h, r);
        }
    }

    head_kernel<<<NB, 256, 0, stream>>>(h, gsi, fc1w, fc1b, fc2w, fc2b, (float*)d_out);
    loss_kernel<<<1, 256, 0, stream>>>((float*)d_out + 1, labels, (float*)d_out);
}

// Round 4
// 1460.345 us; speedup vs baseline: 12.8862x; 1.2724x over previous
//
#include <hip/hip_runtime.h>
#include <hip/hip_bf16.h>
#include <math.h>

#define N_NODES 50000
#define NE      100000
#define NH      8
#define HD      96
#define FDIM    768
#define NFUSE   1536
#define NB      256
#define NC      31

typedef __hip_bfloat16 bf16;
typedef __attribute__((ext_vector_type(8))) short bf16x8;
typedef __attribute__((ext_vector_type(4))) float f32x4;

__device__ inline float u2f(unsigned short u) { return __uint_as_float(((unsigned int)u) << 16); }

__device__ inline void load_lds16(const void* g, void* l) {
    __builtin_amdgcn_global_load_lds(
        (const __attribute__((address_space(1))) void*)g,
        (__attribute__((address_space(3))) void*)l, 16, 0, 0);
}

// ---------------- convert f32 -> bf16 ----------------
__global__ __launch_bounds__(256) void cvt_kernel(const float* __restrict__ in,
                                                  bf16* __restrict__ out) {
    const size_t total = (size_t)N_NODES * FDIM;
    const size_t stride = (size_t)gridDim.x * blockDim.x;
    for (size_t i = blockIdx.x * (size_t)blockDim.x + threadIdx.x; i < total; i += stride)
        out[i] = __float2bfloat16(in[i]);
}

// ---------------- weight transpose+convert: dst[n][k] = bf16(src[k][n]) ----------------
__global__ __launch_bounds__(256) void twt_kernel(const float* __restrict__ src,
                                                  bf16* __restrict__ dst) {
    __shared__ float tile[32][33];
    const int tx = threadIdx.x & 31, ty = threadIdx.x >> 5;
    const int x0 = blockIdx.x * 32, y0 = blockIdx.y * 32;
#pragma unroll
    for (int q = 0; q < 4; ++q)
        tile[ty + q * 8][tx] = src[(size_t)(y0 + ty + q * 8) * FDIM + x0 + tx];
    __syncthreads();
#pragma unroll
    for (int q = 0; q < 4; ++q)
        dst[(size_t)(x0 + ty + q * 8) * FDIM + y0 + tx] = __float2bfloat16(tile[tx][ty + q * 8]);
}

// ---------------- fused MFMA GEMM: C[M,1536](bf16) = A[M,768](bf16) @ WtF^T + bias ----------------
// WtF is [1536][768] bf16 (rows 0:768 = Ws^T, 768:1536 = Wd^T).
// 256x256 tile, 8 waves (2x4), BK=64, double-buffered LDS, 2-phase pipeline.
#define GBM 256
#define GBN 256
#define GBK 64
#define NKT (FDIM / GBK)  // 12

__global__ __launch_bounds__(512, 2) void gemm_fused(const bf16* __restrict__ A,
                                                     const bf16* __restrict__ Wt,
                                                     const float* __restrict__ bsrc,
                                                     const float* __restrict__ bdst,
                                                     bf16* __restrict__ C, int M) {
    __shared__ __align__(16) short lds[2][2][GBM * GBK];  // 128 KB total
    const int t = threadIdx.x;
    const int wid = t >> 6, lane = t & 63;
    const int wr = wid >> 2, wc = wid & 3;
    const int lr = lane & 15, lk = lane >> 4;

    // n-fastest + bijective XCD swizzle (grid = 196*6 = 1176 = 8*147)
    const int bid = blockIdx.x;
    const int swz = (bid & 7) * 147 + (bid >> 3);
    const int tm = swz / 6, tn = swz % 6;
    const int m0 = tm * GBM, n0 = tn * GBN;

    const f32x4 zero4 = {0.f, 0.f, 0.f, 0.f};
    f32x4 acc[8][4];
#pragma unroll
    for (int i = 0; i < 8; ++i)
#pragma unroll
        for (int j = 0; j < 4; ++j) acc[i][j] = zero4;

    // Per-thread staging addresses: slot s = i*512+t -> row s>>3, chunk p=s&7.
    // LDS linear; global source chunk = p ^ (row&7) (bank-conflict-free read swizzle).
    int arow[4], brow[4], acol[4], ldsoff[4];
#pragma unroll
    for (int i = 0; i < 4; ++i) {
        const int s = i * 512 + t;
        const int rr = s >> 3, p = s & 7;
        int r = m0 + rr; if (r >= M) r = M - 1;
        arow[i] = r;
        brow[i] = n0 + rr;
        acol[i] = (p ^ (rr & 7)) << 3;
        ldsoff[i] = (i * 512 + wid * 64) * 16;
    }

#define STAGE(buf, k0)                                                                     \
    {                                                                                      \
        _Pragma("unroll") for (int i = 0; i < 4; ++i) {                                    \
            load_lds16(A + (size_t)arow[i] * FDIM + (k0) + acol[i],                        \
                       (char*)&lds[buf][0][0] + ldsoff[i]);                                \
            load_lds16(Wt + (size_t)brow[i] * FDIM + (k0) + acol[i],                       \
                       (char*)&lds[buf][1][0] + ldsoff[i]);                                \
        }                                                                                  \
    }

    STAGE(0, 0);
    __syncthreads();

    int cur = 0;
    for (int kt = 0; kt < NKT; ++kt) {
        if (kt + 1 < NKT) STAGE(cur ^ 1, (kt + 1) * GBK);
        const short* Ab = &lds[cur][0][0];
        const short* Bb = &lds[cur][1][0];
#pragma unroll
        for (int kh = 0; kh < 2; ++kh) {
            bf16x8 av[8], bv[4];
            const int c = kh * 4 + lk;
#pragma unroll
            for (int i = 0; i < 8; ++i) {
                const int mm = wr * 128 + i * 16 + lr;
                av[i] = *(const bf16x8*)((const char*)Ab + mm * 128 + ((c ^ (mm & 7)) << 4));
            }
#pragma unroll
            for (int j = 0; j < 4; ++j) {
                const int nn = wc * 64 + j * 16 + lr;
                bv[j] = *(const bf16x8*)((const char*)Bb + nn * 128 + ((c ^ (nn & 7)) << 4));
            }
#pragma unroll
            for (int i = 0; i < 8; ++i)
#pragma unroll
                for (int j = 0; j < 4; ++j)
                    acc[i][j] = __builtin_amdgcn_mfma_f32_16x16x32_bf16(av[i], bv[j], acc[i][j], 0, 0, 0);
        }
        __syncthreads();
        cur ^= 1;
    }

    // Epilogue: D mapping col=lane&15, row=(lane>>4)*4+reg
#pragma unroll
    for (int j = 0; j < 4; ++j) {
        const int col = n0 + wc * 64 + j * 16 + lr;
        const float bj = (col < FDIM) ? bsrc[col] : bdst[col - FDIM];
#pragma unroll
        for (int i = 0; i < 8; ++i) {
            const int row0 = m0 + wr * 128 + i * 16 + lk * 4;
#pragma unroll
            for (int r = 0; r < 4; ++r) {
                const int row = row0 + r;
                if (row < M) C[(size_t)row * NFUSE + col] = __float2bfloat16(acc[i][j][r] + bj);
            }
        }
    }
#undef STAGE
}

// ---------------- CSR build ----------------
__global__ __launch_bounds__(256) void hist_kernel(const int* __restrict__ dst, int* __restrict__ deg) {
    const int e = blockIdx.x * 256 + threadIdx.x;
    if (e < NE) atomicAdd(&deg[dst[e]], 1);
}

__global__ __launch_bounds__(256) void scan_kernel(const int* __restrict__ deg,
                                                   int* __restrict__ rowp,
                                                   int* __restrict__ cursor) {
    __shared__ int pref[257];
    const int t = threadIdx.x;
    const int CH = (N_NODES + 255) / 256;
    const int b0 = t * CH;
    const int b1 = (b0 + CH < N_NODES) ? b0 + CH : N_NODES;
    int s = 0;
    for (int i = b0; i < b1; ++i) s += deg[i];
    __shared__ int part[256];
    part[t] = s;
    __syncthreads();
    if (t == 0) {
        int acc = 0;
        for (int i = 0; i < 256; ++i) { pref[i] = acc; acc += part[i]; }
        pref[256] = acc;
    }
    __syncthreads();
    int run = pref[t];
    for (int i = b0; i < b1; ++i) { rowp[i] = run; cursor[i] = run; run += deg[i]; }
    if (t == 255) rowp[N_NODES] = run;
}

__global__ __launch_bounds__(256) void scatter_kernel(const int* __restrict__ dst,
                                                      int* __restrict__ cursor,
                                                      int* __restrict__ eid) {
    const int e = blockIdx.x * 256 + threadIdx.x;
    if (e < NE) {
        const int p = atomicAdd(&cursor[dst[e]], 1);
        eid[p] = e;
    }
}

// ---------------- fused score+softmax+aggregate: wave per dst node, online softmax ----------------
// fsd: [N][1536] = [fs | fd].  mode 0: o[n]=bf16(agg);  mode 1: h[n]=bf16(h+o+agg).
__global__ __launch_bounds__(256) void agg_fused_kernel(const bf16* __restrict__ fsd,
                                                        const float* __restrict__ attn,
                                                        const int* __restrict__ rowp,
                                                        const int* __restrict__ eid,
                                                        const int* __restrict__ src,
                                                        bf16* __restrict__ o,
                                                        bf16* __restrict__ h,
                                                        int mode) {
    const int wid = threadIdx.x >> 6;
    const int lane = threadIdx.x & 63;
    const int n = blockIdx.x * 4 + wid;
    if (n >= N_NODES) return;

    // This lane's 12 dims of fd[n] and attn
    float fdv[12], atv[12];
    {
        const ushort4* pfd = (const ushort4*)(fsd + (size_t)n * NFUSE + FDIM + lane * 12);
        const ushort4 d0 = pfd[0], d1 = pfd[1], d2 = pfd[2];
        fdv[0] = u2f(d0.x); fdv[1] = u2f(d0.y); fdv[2] = u2f(d0.z); fdv[3] = u2f(d0.w);
        fdv[4] = u2f(d1.x); fdv[5] = u2f(d1.y); fdv[6] = u2f(d1.z); fdv[7] = u2f(d1.w);
        fdv[8] = u2f(d2.x); fdv[9] = u2f(d2.y); fdv[10] = u2f(d2.z); fdv[11] = u2f(d2.w);
        const float4* pat = (const float4*)(attn + lane * 12);
        const float4 a0 = pat[0], a1 = pat[1], a2 = pat[2];
        atv[0] = a0.x; atv[1] = a0.y; atv[2] = a0.z; atv[3] = a0.w;
        atv[4] = a1.x; atv[5] = a1.y; atv[6] = a1.z; atv[7] = a1.w;
        atv[8] = a2.x; atv[9] = a2.y; atv[10] = a2.z; atv[11] = a2.w;
    }

    const int beg = rowp[n], end = rowp[n + 1];
    float m = -INFINITY, den = 0.f;
    float acc[12];
#pragma unroll
    for (int j = 0; j < 12; ++j) acc[j] = 0.f;

    for (int i = beg; i < end; ++i) {
        const int e = eid[i];
        const int s = src[e];
        const ushort4* pf = (const ushort4*)(fsd + (size_t)s * NFUSE + lane * 12);
        const ushort4 a0 = pf[0], a1 = pf[1], a2 = pf[2];
        float fsv[12];
        fsv[0] = u2f(a0.x); fsv[1] = u2f(a0.y); fsv[2] = u2f(a0.z); fsv[3] = u2f(a0.w);
        fsv[4] = u2f(a1.x); fsv[5] = u2f(a1.y); fsv[6] = u2f(a1.z); fsv[7] = u2f(a1.w);
        fsv[8] = u2f(a2.x); fsv[9] = u2f(a2.y); fsv[10] = u2f(a2.z); fsv[11] = u2f(a2.w);
        float p = 0.f;
#pragma unroll
        for (int j = 0; j < 12; ++j) {
            float x = fsv[j] + fdv[j];
            x = (x > 0.f) ? x : 0.2f * x;
            p += x * atv[j];
        }
        p += __shfl_xor(p, 1);
        p += __shfl_xor(p, 2);
        p += __shfl_xor(p, 4);
        if (p > m) {
            const float sc = expf(m - p);  // exp(-inf)=0 on first edge
            den *= sc;
#pragma unroll
            for (int j = 0; j < 12; ++j) acc[j] *= sc;
            m = p;
        }
        const float w = expf(p - m);
        den += w;
#pragma unroll
        for (int j = 0; j < 12; ++j) acc[j] += w * fsv[j];
    }

    const float inv = (den > 0.f) ? 1.f / den : 0.f;
    const size_t base = (size_t)n * FDIM + lane * 12;
    if (mode == 0) {
        ushort4 r0, r1, r2;
        r0.x = __bfloat16_as_ushort(__float2bfloat16(acc[0] * inv));  r0.y = __bfloat16_as_ushort(__float2bfloat16(acc[1] * inv));
        r0.z = __bfloat16_as_ushort(__float2bfloat16(acc[2] * inv));  r0.w = __bfloat16_as_ushort(__float2bfloat16(acc[3] * inv));
        r1.x = __bfloat16_as_ushort(__float2bfloat16(acc[4] * inv));  r1.y = __bfloat16_as_ushort(__float2bfloat16(acc[5] * inv));
        r1.z = __bfloat16_as_ushort(__float2bfloat16(acc[6] * inv));  r1.w = __bfloat16_as_ushort(__float2bfloat16(acc[7] * inv));
        r2.x = __bfloat16_as_ushort(__float2bfloat16(acc[8] * inv));  r2.y = __bfloat16_as_ushort(__float2bfloat16(acc[9] * inv));
        r2.z = __bfloat16_as_ushort(__float2bfloat16(acc[10] * inv)); r2.w = __bfloat16_as_ushort(__float2bfloat16(acc[11] * inv));
        ((ushort4*)(o + base))[0] = r0; ((ushort4*)(o + base))[1] = r1; ((ushort4*)(o + base))[2] = r2;
    } else {
        const ushort4* ph = (const ushort4*)(h + base);
        const ushort4* po = (const ushort4*)(o + base);
        const ushort4 hv0 = ph[0], hv1 = ph[1], hv2 = ph[2];
        const ushort4 ov0 = po[0], ov1 = po[1], ov2 = po[2];
        float v[12];
        v[0] = u2f(hv0.x) + u2f(ov0.x) + acc[0] * inv;  v[1] = u2f(hv0.y) + u2f(ov0.y) + acc[1] * inv;
        v[2] = u2f(hv0.z) + u2f(ov0.z) + acc[2] * inv;  v[3] = u2f(hv0.w) + u2f(ov0.w) + acc[3] * inv;
        v[4] = u2f(hv1.x) + u2f(ov1.x) + acc[4] * inv;  v[5] = u2f(hv1.y) + u2f(ov1.y) + acc[5] * inv;
        v[6] = u2f(hv1.z) + u2f(ov1.z) + acc[6] * inv;  v[7] = u2f(hv1.w) + u2f(ov1.w) + acc[7] * inv;
        v[8] = u2f(hv2.x) + u2f(ov2.x) + acc[8] * inv;  v[9] = u2f(hv2.y) + u2f(ov2.y) + acc[9] * inv;
        v[10] = u2f(hv2.z) + u2f(ov2.z) + acc[10] * inv; v[11] = u2f(hv2.w) + u2f(ov2.w) + acc[11] * inv;
        ushort4 r0, r1, r2;
        r0.x = __bfloat16_as_ushort(__float2bfloat16(v[0]));  r0.y = __bfloat16_as_ushort(__float2bfloat16(v[1]));
        r0.z = __bfloat16_as_ushort(__float2bfloat16(v[2]));  r0.w = __bfloat16_as_ushort(__float2bfloat16(v[3]));
        r1.x = __bfloat16_as_ushort(__float2bfloat16(v[4]));  r1.y = __bfloat16_as_ushort(__float2bfloat16(v[5]));
        r1.z = __bfloat16_as_ushort(__float2bfloat16(v[6]));  r1.w = __bfloat16_as_ushort(__float2bfloat16(v[7]));
        r2.x = __bfloat16_as_ushort(__float2bfloat16(v[8]));  r2.y = __bfloat16_as_ushort(__float2bfloat16(v[9]));
        r2.z = __bfloat16_as_ushort(__float2bfloat16(v[10])); r2.w = __bfloat16_as_ushort(__float2bfloat16(v[11]));
        ((ushort4*)(h + base))[0] = r0; ((ushort4*)(h + base))[1] = r1; ((ushort4*)(h + base))[2] = r2;
    }
}

// ---------------- MLP head ----------------
__global__ __launch_bounds__(256) void head_kernel(const bf16* __restrict__ h,
                                                   const int* __restrict__ gsi,
                                                   const float* __restrict__ fc1w,
                                                   const float* __restrict__ fc1b,
                                                   const float* __restrict__ fc2w,
                                                   const float* __restrict__ fc2b,
                                                   float* __restrict__ out) {
    __shared__ float fe[FDIM];
    __shared__ float hid[256];
    const int b = blockIdx.x, t = threadIdx.x;
    const int node = gsi[b];
    for (int i = t; i < FDIM; i += 256) fe[i] = __bfloat162float(h[(size_t)node * FDIM + i]);
    __syncthreads();
    float acc = fc1b[t];
    for (int k = 0; k < FDIM; ++k) acc += fe[k] * fc1w[k * 256 + t];
    hid[t] = (acc > 0.f) ? acc : 0.f;
    __syncthreads();
    if (t < NC) {
        float acc2 = fc2b[t];
        for (int k = 0; k < 256; ++k) acc2 += hid[k] * fc2w[k * NC + t];
        out[1 + b * NC + t] = acc2;
    }
}

// ---------------- loss ----------------
__global__ __launch_bounds__(256) void loss_kernel(const float* __restrict__ logits,
                                                   const int* __restrict__ labels,
                                                   float* __restrict__ out) {
    __shared__ float red[256];
    const int b = threadIdx.x;
    float m = -INFINITY;
    for (int c = 0; c < NC; ++c) m = fmaxf(m, logits[b * NC + c]);
    float sum = 0.f;
    for (int c = 0; c < NC; ++c) sum += expf(logits[b * NC + c] - m);
    const float lse = m + logf(sum);
    const float ll = logits[b * NC + labels[b]];
    red[b] = lse - ll;
    __syncthreads();
    for (int s = 128; s > 0; s >>= 1) {
        if (b < s) red[b] += red[b + s];
        __syncthreads();
    }
    if (b == 0) out[0] = red[0] / (float)NB;
}

extern "C" void kernel_launch(void* const* d_in, const int* in_sizes, int n_in,
                              void* d_out, int out_size, void* d_ws, size_t ws_size,
                              hipStream_t stream) {
    const float* feats = (const float*)d_in[0];
    const float* fc1w  = (const float*)d_in[11];
    const float* fc1b  = (const float*)d_in[12];
    const float* fc2w  = (const float*)d_in[13];
    const float* fc2b  = (const float*)d_in[14];
    const int* gsi     = (const int*)d_in[19];
    const int* labels  = (const int*)d_in[20];

    const size_t NF = (size_t)N_NODES * FDIM;
    const size_t WSZ = (size_t)FDIM * FDIM;
    char* p = (char*)d_ws;
    bf16* h   = (bf16*)p;  p += NF * 2;
    bf16* fsd = (bf16*)p;  p += (size_t)N_NODES * NFUSE * 2;
    bf16* o   = (bf16*)p;  p += NF * 2;
    bf16* WtF = (bf16*)p;  p += 8 * WSZ * 2;  // 4 fused matrices of [1536][768]
    int* deg[2];  int* rowp[2];  int* cursor[2];  int* eid[2];
    for (int r = 0; r < 2; ++r) {
        deg[r]    = (int*)p; p += (size_t)N_NODES * 4 + 256;
        rowp[r]   = (int*)p; p += ((size_t)N_NODES + 1) * 4 + 256;
        cursor[r] = (int*)p; p += (size_t)N_NODES * 4 + 256;
        eid[r]    = (int*)p; p += (size_t)NE * 4 + 256;
    }

    cvt_kernel<<<2048, 256, 0, stream>>>(feats, h);

    // Transpose+convert 8 weight matrices into 4 fused [1536][768] blocks.
    dim3 tgrid(FDIM / 32, FDIM / 32);
    for (int r = 0; r < 2; ++r)
        for (int l = 0; l < 2; ++l)
            for (int sd = 0; sd < 2; ++sd) {
                const float* src = (const float*)d_in[r == 0 ? (sd == 0 ? 1 : 3) : (sd == 0 ? 6 : 8)] + (size_t)l * WSZ;
                twt_kernel<<<tgrid, 256, 0, stream>>>(src, WtF + ((size_t)(r * 2 + l) * 2 + sd) * WSZ);
            }

    // Build CSR per relation (dst is layer-invariant).
    for (int r = 0; r < 2; ++r) {
        const int* dst = (const int*)d_in[r == 0 ? 16 : 18];
        hipMemsetAsync(deg[r], 0, sizeof(int) * N_NODES, stream);
        hist_kernel<<<(NE + 255) / 256, 256, 0, stream>>>(dst, deg[r]);
        scan_kernel<<<1, 256, 0, stream>>>(deg[r], rowp[r], cursor[r]);
        scatter_kernel<<<(NE + 255) / 256, 256, 0, stream>>>(dst, cursor[r], eid[r]);
    }

    const int gemm_blocks = ((N_NODES + GBM - 1) / GBM) * (NFUSE / GBN);  // 196*6 = 1176
    const int node_blocks = (N_NODES + 3) / 4;

    for (int l = 0; l < 2; ++l) {
        for (int r = 0; r < 2; ++r) {
            const float* bsrc = (const float*)d_in[r == 0 ? 2 : 7] + (size_t)l * FDIM;
            const float* bdst = (const float*)d_in[r == 0 ? 4 : 9] + (size_t)l * FDIM;
            const float* attn = (const float*)d_in[r == 0 ? 5 : 10] + (size_t)l * FDIM;
            const int* src = (const int*)d_in[r == 0 ? 15 : 17];
            const bf16* W = WtF + (size_t)(r * 2 + l) * 2 * WSZ;

            gemm_fused<<<gemm_blocks, 512, 0, stream>>>(h, W, bsrc, bdst, fsd, N_NODES);
            agg_fused_kernel<<<node_blocks, 256, 0, stream>>>(fsd, attn, rowp[r], eid[r], src, o, h, r);
        }
    }

    head_kernel<<<NB, 256, 0, stream>>>(h, gsi, fc1w, fc1b, fc2w, fc2b, (float*)d_out);
    loss_kernel<<<1, 256, 0, stream>>>((float*)d_out + 1, labels, (float*)d_out);
}

// Round 5
// 1345.787 us; speedup vs baseline: 13.9831x; 1.0851x over previous
//
#include <hip/hip_runtime.h>
#include <hip/hip_bf16.h>
#include <math.h>

#define N_NODES 50000
#define NE      100000
#define NH      8
#define HD      96
#define FDIM    768
#define NFUSE   1536
#define NB      256
#define NC      31

typedef __hip_bfloat16 bf16;
typedef __attribute__((ext_vector_type(8))) short bf16x8;
typedef __attribute__((ext_vector_type(4))) float f32x4;

__device__ inline float u2f(unsigned short u) { return __uint_as_float(((unsigned int)u) << 16); }

__device__ inline void load_lds16(const void* g, void* l) {
    __builtin_amdgcn_global_load_lds(
        (const __attribute__((address_space(1))) void*)g,
        (__attribute__((address_space(3))) void*)l, 16, 0, 0);
}

// ---------------- convert f32 -> bf16 ----------------
__global__ __launch_bounds__(256) void cvt_kernel(const float* __restrict__ in,
                                                  bf16* __restrict__ out) {
    const size_t total = (size_t)N_NODES * FDIM;
    const size_t stride = (size_t)gridDim.x * blockDim.x;
    for (size_t i = blockIdx.x * (size_t)blockDim.x + threadIdx.x; i < total; i += stride)
        out[i] = __float2bfloat16(in[i]);
}

// ---------------- weight transpose+convert: dst[n][k] = bf16(src[k][n]) ----------------
__global__ __launch_bounds__(256) void twt_kernel(const float* __restrict__ src,
                                                  bf16* __restrict__ dst) {
    __shared__ float tile[32][33];
    const int tx = threadIdx.x & 31, ty = threadIdx.x >> 5;
    const int x0 = blockIdx.x * 32, y0 = blockIdx.y * 32;
#pragma unroll
    for (int q = 0; q < 4; ++q)
        tile[ty + q * 8][tx] = src[(size_t)(y0 + ty + q * 8) * FDIM + x0 + tx];
    __syncthreads();
#pragma unroll
    for (int q = 0; q < 4; ++q)
        dst[(size_t)(x0 + ty + q * 8) * FDIM + y0 + tx] = __float2bfloat16(tile[tx][ty + q * 8]);
}

// ---------------- fused MFMA GEMM: C[M,1536](bf16) = A[M,768](bf16) @ WtF^T + bias ----------------
// m97 structure: 128x128 tile, BK=64, 4 waves (2x2), single 32KB LDS buffer,
// 2 barriers/K-step, global_load_lds w=16, XOR k-chunk swizzle (round-3 verified).
// Swapped-operand MFMA (acc = C^T fragment) so each lane packs 4 consecutive
// cols of one row -> 8B stores (coalesced-ish, no write amplification).
#define GBM 128
#define GBN 128
#define GBK 64
#define NKT (FDIM / GBK)  // 12
#define TILES_M ((N_NODES + GBM - 1) / GBM)  // 391
#define TILES_N (NFUSE / GBN)                // 12
#define NWG (TILES_M * TILES_N)              // 4692 = 8*586 + 4

__global__ __launch_bounds__(256) void gemm_fused(const bf16* __restrict__ A,
                                                  const bf16* __restrict__ Wt,
                                                  const float* __restrict__ bsrc,
                                                  const float* __restrict__ bdst,
                                                  bf16* __restrict__ C, int M) {
    __shared__ __align__(16) short Abuf[GBM * GBK];  // 16 KB
    __shared__ __align__(16) short Bbuf[GBN * GBK];  // 16 KB
    const int t = threadIdx.x;
    const int wid = t >> 6, lane = t & 63;
    const int wr = wid >> 1, wc = wid & 1;
    const int lr = lane & 15, lk = lane >> 4;

    // Bijective XCD swizzle (m204): nwg=4692, q=586, r=4 -> chunks of 587/586.
    const int orig = blockIdx.x;
    const int xcd = orig & 7;
    const int pos = orig >> 3;
    const int wgid = (xcd < 4 ? xcd * 587 : 4 * 587 + (xcd - 4) * 586) + pos;
    const int tm = wgid / TILES_N, tn = wgid % TILES_N;  // n-fastest: A-panel L2 reuse
    const int m0 = tm * GBM, n0 = tn * GBN;

    const f32x4 zero4 = {0.f, 0.f, 0.f, 0.f};
    f32x4 acc[4][4];
#pragma unroll
    for (int i = 0; i < 4; ++i)
#pragma unroll
        for (int j = 0; j < 4; ++j) acc[i][j] = zero4;

    // Staging slots: s = i*256+t -> row rr=s>>3, chunk p=s&7.
    // LDS linear; global source chunk = p ^ (rr&7) (matches swizzled ds_read).
    int arow[4], brow[4], acol[4], ldsoff[4];
#pragma unroll
    for (int i = 0; i < 4; ++i) {
        const int s = i * 256 + t;
        const int rr = s >> 3, p = s & 7;
        int r = m0 + rr; if (r >= M) r = M - 1;
        arow[i] = r;
        brow[i] = n0 + rr;
        acol[i] = (p ^ (rr & 7)) << 3;
        ldsoff[i] = (i * 256 + wid * 64) * 16;  // wave-uniform base
    }

    for (int kt = 0; kt < NKT; ++kt) {
        const int k0 = kt * GBK;
#pragma unroll
        for (int i = 0; i < 4; ++i) {
            load_lds16(A + (size_t)arow[i] * FDIM + k0 + acol[i], (char*)Abuf + ldsoff[i]);
            load_lds16(Wt + (size_t)brow[i] * FDIM + k0 + acol[i], (char*)Bbuf + ldsoff[i]);
        }
        __syncthreads();
#pragma unroll
        for (int kh = 0; kh < 2; ++kh) {
            bf16x8 av[4], bv[4];
            const int c = kh * 4 + lk;
#pragma unroll
            for (int i = 0; i < 4; ++i) {
                const int mm = wr * 64 + i * 16 + lr;
                av[i] = *(const bf16x8*)((const char*)Abuf + mm * 128 + ((c ^ (mm & 7)) << 4));
            }
#pragma unroll
            for (int j = 0; j < 4; ++j) {
                const int nn = wc * 64 + j * 16 + lr;
                bv[j] = *(const bf16x8*)((const char*)Bbuf + nn * 128 + ((c ^ (nn & 7)) << 4));
            }
            // Swapped operands: acc = (A.B^T)^T fragment; lane owns row m=..+lr,
            // cols n=..+lk*4+reg (4 consecutive).
#pragma unroll
            for (int i = 0; i < 4; ++i)
#pragma unroll
                for (int j = 0; j < 4; ++j)
                    acc[i][j] = __builtin_amdgcn_mfma_f32_16x16x32_bf16(bv[j], av[i], acc[i][j], 0, 0, 0);
        }
        __syncthreads();
    }

    // Epilogue: row = m0+wr*64+i*16+lr; col = n0+wc*64+j*16+lk*4 (+reg).
#pragma unroll
    for (int i = 0; i < 4; ++i) {
        const int row = m0 + wr * 64 + i * 16 + lr;
        if (row < M) {
#pragma unroll
            for (int j = 0; j < 4; ++j) {
                const int col = n0 + wc * 64 + j * 16 + lk * 4;
                const float4 b4 = (col < FDIM) ? *(const float4*)(bsrc + col)
                                               : *(const float4*)(bdst + col - FDIM);
                ushort4 w;
                w.x = __bfloat16_as_ushort(__float2bfloat16(acc[i][j][0] + b4.x));
                w.y = __bfloat16_as_ushort(__float2bfloat16(acc[i][j][1] + b4.y));
                w.z = __bfloat16_as_ushort(__float2bfloat16(acc[i][j][2] + b4.z));
                w.w = __bfloat16_as_ushort(__float2bfloat16(acc[i][j][3] + b4.w));
                *(ushort4*)(C + (size_t)row * NFUSE + col) = w;
            }
        }
    }
}

// ---------------- CSR build ----------------
__global__ __launch_bounds__(256) void hist_kernel(const int* __restrict__ dst, int* __restrict__ deg) {
    const int e = blockIdx.x * 256 + threadIdx.x;
    if (e < NE) atomicAdd(&deg[dst[e]], 1);
}

__global__ __launch_bounds__(256) void scan_kernel(const int* __restrict__ deg,
                                                   int* __restrict__ rowp,
                                                   int* __restrict__ cursor) {
    __shared__ int pref[257];
    const int t = threadIdx.x;
    const int CH = (N_NODES + 255) / 256;
    const int b0 = t * CH;
    const int b1 = (b0 + CH < N_NODES) ? b0 + CH : N_NODES;
    int s = 0;
    for (int i = b0; i < b1; ++i) s += deg[i];
    __shared__ int part[256];
    part[t] = s;
    __syncthreads();
    if (t == 0) {
        int acc = 0;
        for (int i = 0; i < 256; ++i) { pref[i] = acc; acc += part[i]; }
        pref[256] = acc;
    }
    __syncthreads();
    int run = pref[t];
    for (int i = b0; i < b1; ++i) { rowp[i] = run; cursor[i] = run; run += deg[i]; }
    if (t == 255) rowp[N_NODES] = run;
}

__global__ __launch_bounds__(256) void scatter_kernel(const int* __restrict__ dst,
                                                      int* __restrict__ cursor,
                                                      int* __restrict__ eid) {
    const int e = blockIdx.x * 256 + threadIdx.x;
    if (e < NE) {
        const int p = atomicAdd(&cursor[dst[e]], 1);
        eid[p] = e;
    }
}

// ---------------- fused score+softmax+aggregate: wave per dst node, online softmax ----------------
// fsd: [N][1536] = [fs | fd].  mode 0: o[n]=bf16(agg);  mode 1: h[n]=bf16(h+o+agg).
__global__ __launch_bounds__(256) void agg_fused_kernel(const bf16* __restrict__ fsd,
                                                        const float* __restrict__ attn,
                                                        const int* __restrict__ rowp,
                                                        const int* __restrict__ eid,
                                                        const int* __restrict__ src,
                                                        bf16* __restrict__ o,
                                                        bf16* __restrict__ h,
                                                        int mode) {
    const int wid = threadIdx.x >> 6;
    const int lane = threadIdx.x & 63;
    const int n = blockIdx.x * 4 + wid;
    if (n >= N_NODES) return;

    float fdv[12], atv[12];
    {
        const ushort4* pfd = (const ushort4*)(fsd + (size_t)n * NFUSE + FDIM + lane * 12);
        const ushort4 d0 = pfd[0], d1 = pfd[1], d2 = pfd[2];
        fdv[0] = u2f(d0.x); fdv[1] = u2f(d0.y); fdv[2] = u2f(d0.z); fdv[3] = u2f(d0.w);
        fdv[4] = u2f(d1.x); fdv[5] = u2f(d1.y); fdv[6] = u2f(d1.z); fdv[7] = u2f(d1.w);
        fdv[8] = u2f(d2.x); fdv[9] = u2f(d2.y); fdv[10] = u2f(d2.z); fdv[11] = u2f(d2.w);
        const float4* pat = (const float4*)(attn + lane * 12);
        const float4 a0 = pat[0], a1 = pat[1], a2 = pat[2];
        atv[0] = a0.x; atv[1] = a0.y; atv[2] = a0.z; atv[3] = a0.w;
        atv[4] = a1.x; atv[5] = a1.y; atv[6] = a1.z; atv[7] = a1.w;
        atv[8] = a2.x; atv[9] = a2.y; atv[10] = a2.z; atv[11] = a2.w;
    }

    const int beg = rowp[n], end = rowp[n + 1];
    float m = -INFINITY, den = 0.f;
    float acc[12];
#pragma unroll
    for (int j = 0; j < 12; ++j) acc[j] = 0.f;

    for (int i = beg; i < end; ++i) {
        const int e = eid[i];
        const int s = src[e];
        const ushort4* pf = (const ushort4*)(fsd + (size_t)s * NFUSE + lane * 12);
        const ushort4 a0 = pf[0], a1 = pf[1], a2 = pf[2];
        float fsv[12];
        fsv[0] = u2f(a0.x); fsv[1] = u2f(a0.y); fsv[2] = u2f(a0.z); fsv[3] = u2f(a0.w);
        fsv[4] = u2f(a1.x); fsv[5] = u2f(a1.y); fsv[6] = u2f(a1.z); fsv[7] = u2f(a1.w);
        fsv[8] = u2f(a2.x); fsv[9] = u2f(a2.y); fsv[10] = u2f(a2.z); fsv[11] = u2f(a2.w);
        float p = 0.f;
#pragma unroll
        for (int j = 0; j < 12; ++j) {
            float x = fsv[j] + fdv[j];
            x = (x > 0.f) ? x : 0.2f * x;
            p += x * atv[j];
        }
        p += __shfl_xor(p, 1);
        p += __shfl_xor(p, 2);
        p += __shfl_xor(p, 4);
        if (p > m) {
            const float sc = expf(m - p);
            den *= sc;
#pragma unroll
            for (int j = 0; j < 12; ++j) acc[j] *= sc;
            m = p;
        }
        const float w = expf(p - m);
        den += w;
#pragma unroll
        for (int j = 0; j < 12; ++j) acc[j] += w * fsv[j];
    }

    const float inv = (den > 0.f) ? 1.f / den : 0.f;
    const size_t base = (size_t)n * FDIM + lane * 12;
    if (mode == 0) {
        ushort4 r0, r1, r2;
        r0.x = __bfloat16_as_ushort(__float2bfloat16(acc[0] * inv));  r0.y = __bfloat16_as_ushort(__float2bfloat16(acc[1] * inv));
        r0.z = __bfloat16_as_ushort(__float2bfloat16(acc[2] * inv));  r0.w = __bfloat16_as_ushort(__float2bfloat16(acc[3] * inv));
        r1.x = __bfloat16_as_ushort(__float2bfloat16(acc[4] * inv));  r1.y = __bfloat16_as_ushort(__float2bfloat16(acc[5] * inv));
        r1.z = __bfloat16_as_ushort(__float2bfloat16(acc[6] * inv));  r1.w = __bfloat16_as_ushort(__float2bfloat16(acc[7] * inv));
        r2.x = __bfloat16_as_ushort(__float2bfloat16(acc[8] * inv));  r2.y = __bfloat16_as_ushort(__float2bfloat16(acc[9] * inv));
        r2.z = __bfloat16_as_ushort(__float2bfloat16(acc[10] * inv)); r2.w = __bfloat16_as_ushort(__float2bfloat16(acc[11] * inv));
        ((ushort4*)(o + base))[0] = r0; ((ushort4*)(o + base))[1] = r1; ((ushort4*)(o + base))[2] = r2;
    } else {
        const ushort4* ph = (const ushort4*)(h + base);
        const ushort4* po = (const ushort4*)(o + base);
        const ushort4 hv0 = ph[0], hv1 = ph[1], hv2 = ph[2];
        const ushort4 ov0 = po[0], ov1 = po[1], ov2 = po[2];
        float v[12];
        v[0] = u2f(hv0.x) + u2f(ov0.x) + acc[0] * inv;  v[1] = u2f(hv0.y) + u2f(ov0.y) + acc[1] * inv;
        v[2] = u2f(hv0.z) + u2f(ov0.z) + acc[2] * inv;  v[3] = u2f(hv0.w) + u2f(ov0.w) + acc[3] * inv;
        v[4] = u2f(hv1.x) + u2f(ov1.x) + acc[4] * inv;  v[5] = u2f(hv1.y) + u2f(ov1.y) + acc[5] * inv;
        v[6] = u2f(hv1.z) + u2f(ov1.z) + acc[6] * inv;  v[7] = u2f(hv1.w) + u2f(ov1.w) + acc[7] * inv;
        v[8] = u2f(hv2.x) + u2f(ov2.x) + acc[8] * inv;  v[9] = u2f(hv2.y) + u2f(ov2.y) + acc[9] * inv;
        v[10] = u2f(hv2.z) + u2f(ov2.z) + acc[10] * inv; v[11] = u2f(hv2.w) + u2f(ov2.w) + acc[11] * inv;
        ushort4 r0, r1, r2;
        r0.x = __bfloat16_as_ushort(__float2bfloat16(v[0]));  r0.y = __bfloat16_as_ushort(__float2bfloat16(v[1]));
        r0.z = __bfloat16_as_ushort(__float2bfloat16(v[2]));  r0.w = __bfloat16_as_ushort(__float2bfloat16(v[3]));
        r1.x = __bfloat16_as_ushort(__float2bfloat16(v[4]));  r1.y = __bfloat16_as_ushort(__float2bfloat16(v[5]));
        r1.z = __bfloat16_as_ushort(__float2bfloat16(v[6]));  r1.w = __bfloat16_as_ushort(__float2bfloat16(v[7]));
        r2.x = __bfloat16_as_ushort(__float2bfloat16(v[8]));  r2.y = __bfloat16_as_ushort(__float2bfloat16(v[9]));
        r2.z = __bfloat16_as_ushort(__float2bfloat16(v[10])); r2.w = __bfloat16_as_ushort(__float2bfloat16(v[11]));
        ((ushort4*)(h + base))[0] = r0; ((ushort4*)(h + base))[1] = r1; ((ushort4*)(h + base))[2] = r2;
    }
}

// ---------------- MLP head ----------------
__global__ __launch_bounds__(256) void head_kernel(const bf16* __restrict__ h,
                                                   const int* __restrict__ gsi,
                                                   const float* __restrict__ fc1w,
                                                   const float* __restrict__ fc1b,
                                                   const float* __restrict__ fc2w,
                                                   const float* __restrict__ fc2b,
                                                   float* __restrict__ out) {
    __shared__ float fe[FDIM];
    __shared__ float hid[256];
    const int b = blockIdx.x, t = threadIdx.x;
    const int node = gsi[b];
    for (int i = t; i < FDIM; i += 256) fe[i] = __bfloat162float(h[(size_t)node * FDIM + i]);
    __syncthreads();
    float acc = fc1b[t];
    for (int k = 0; k < FDIM; ++k) acc += fe[k] * fc1w[k * 256 + t];
    hid[t] = (acc > 0.f) ? acc : 0.f;
    __syncthreads();
    if (t < NC) {
        float acc2 = fc2b[t];
        for (int k = 0; k < 256; ++k) acc2 += hid[k] * fc2w[k * NC + t];
        out[1 + b * NC + t] = acc2;
    }
}

// ---------------- loss ----------------
__global__ __launch_bounds__(256) void loss_kernel(const float* __restrict__ logits,
                                                   const int* __restrict__ labels,
                                                   float* __restrict__ out) {
    __shared__ float red[256];
    const int b = threadIdx.x;
    float m = -INFINITY;
    for (int c = 0; c < NC; ++c) m = fmaxf(m, logits[b * NC + c]);
    float sum = 0.f;
    for (int c = 0; c < NC; ++c) sum += expf(logits[b * NC + c] - m);
    const float lse = m + logf(sum);
    const float ll = logits[b * NC + labels[b]];
    red[b] = lse - ll;
    __syncthreads();
    for (int s = 128; s > 0; s >>= 1) {
        if (b < s) red[b] += red[b + s];
        __syncthreads();
    }
    if (b == 0) out[0] = red[0] / (float)NB;
}

extern "C" void kernel_launch(void* const* d_in, const int* in_sizes, int n_in,
                              void* d_out, int out_size, void* d_ws, size_t ws_size,
                              hipStream_t stream) {
    const float* feats = (const float*)d_in[0];
    const float* fc1w  = (const float*)d_in[11];
    const float* fc1b  = (const float*)d_in[12];
    const float* fc2w  = (const float*)d_in[13];
    const float* fc2b  = (const float*)d_in[14];
    const int* gsi     = (const int*)d_in[19];
    const int* labels  = (const int*)d_in[20];

    const size_t NF = (size_t)N_NODES * FDIM;
    const size_t WSZ = (size_t)FDIM * FDIM;
    char* p = (char*)d_ws;
    bf16* h   = (bf16*)p;  p += NF * 2;
    bf16* fsd = (bf16*)p;  p += (size_t)N_NODES * NFUSE * 2;
    bf16* o   = (bf16*)p;  p += NF * 2;
    bf16* WtF = (bf16*)p;  p += 8 * WSZ * 2;  // 4 fused matrices of [1536][768]
    int* deg[2];  int* rowp[2];  int* cursor[2];  int* eid[2];
    for (int r = 0; r < 2; ++r) {
        deg[r]    = (int*)p; p += (size_t)N_NODES * 4 + 256;
        rowp[r]   = (int*)p; p += ((size_t)N_NODES + 1) * 4 + 256;
        cursor[r] = (int*)p; p += (size_t)N_NODES * 4 + 256;
        eid[r]    = (int*)p; p += (size_t)NE * 4 + 256;
    }

    cvt_kernel<<<2048, 256, 0, stream>>>(feats, h);

    // Transpose+convert 8 weight matrices into 4 fused [1536][768] blocks.
    dim3 tgrid(FDIM / 32, FDIM / 32);
    for (int r = 0; r < 2; ++r)
        for (int l = 0; l < 2; ++l)
            for (int sd = 0; sd < 2; ++sd) {
                const float* src = (const float*)d_in[r == 0 ? (sd == 0 ? 1 : 3) : (sd == 0 ? 6 : 8)] + (size_t)l * WSZ;
                twt_kernel<<<tgrid, 256, 0, stream>>>(src, WtF + ((size_t)(r * 2 + l) * 2 + sd) * WSZ);
            }

    // Build CSR per relation (dst is layer-invariant).
    for (int r = 0; r < 2; ++r) {
        const int* dst = (const int*)d_in[r == 0 ? 16 : 18];
        hipMemsetAsync(deg[r], 0, sizeof(int) * N_NODES, stream);
        hist_kernel<<<(NE + 255) / 256, 256, 0, stream>>>(dst, deg[r]);
        scan_kernel<<<1, 256, 0, stream>>>(deg[r], rowp[r], cursor[r]);
        scatter_kernel<<<(NE + 255) / 256, 256, 0, stream>>>(dst, cursor[r], eid[r]);
    }

    const int node_blocks = (N_NODES + 3) / 4;

    for (int l = 0; l < 2; ++l) {
        for (int r = 0; r < 2; ++r) {
            const float* bsrc = (const float*)d_in[r == 0 ? 2 : 7] + (size_t)l * FDIM;
            const float* bdst = (const float*)d_in[r == 0 ? 4 : 9] + (size_t)l * FDIM;
            const float* attn = (const float*)d_in[r == 0 ? 5 : 10] + (size_t)l * FDIM;
            const int* src = (const int*)d_in[r == 0 ? 15 : 17];
            const bf16* W = WtF + (size_t)(r * 2 + l) * 2 * WSZ;

            gemm_fused<<<NWG, 256, 0, stream>>>(h, W, bsrc, bdst, fsd, N_NODES);
            agg_fused_kernel<<<node_blocks, 256, 0, stream>>>(fsd, attn, rowp[r], eid[r], src, o, h, r);
        }
    }

    head_kernel<<<NB, 256, 0, stream>>>(h, gsi, fc1w, fc1b, fc2w, fc2b, (float*)d_out);
    loss_kernel<<<1, 256, 0, stream>>>((float*)d_out + 1, labels, (float*)d_out);
}

// Round 6
// 1339.630 us; speedup vs baseline: 14.0474x; 1.0046x over previous
//
#include <hip/hip_runtime.h>
#include <hip/hip_bf16.h>
#include <math.h>

#define N_NODES 50000
#define NE      100000
#define NH      8
#define FDIM    768
#define NFUSE   3072
#define NB      256
#define NC      31

typedef __hip_bfloat16 bf16;
typedef __attribute__((ext_vector_type(8))) short bf16x8;
typedef __attribute__((ext_vector_type(4))) float f32x4;

__device__ inline float u2f(unsigned short u) { return __uint_as_float(((unsigned int)u) << 16); }
__device__ inline unsigned short f2u(float f) { return __bfloat16_as_ushort(__float2bfloat16(f)); }

__device__ inline void load_lds16(const void* g, void* l) {
    __builtin_amdgcn_global_load_lds(
        (const __attribute__((address_space(1))) void*)g,
        (__attribute__((address_space(3))) void*)l, 16, 0, 0);
}

// ---------------- convert f32 -> bf16 ----------------
__global__ __launch_bounds__(256) void cvt_kernel(const float* __restrict__ in,
                                                  bf16* __restrict__ out) {
    const size_t total = (size_t)N_NODES * FDIM;
    const size_t stride = (size_t)gridDim.x * blockDim.x;
    for (size_t i = blockIdx.x * (size_t)blockDim.x + threadIdx.x; i < total; i += stride)
        out[i] = __float2bfloat16(in[i]);
}

// ---------------- weight transpose+convert, 4 matrices of one layer ----------------
// dst block z (z = r*2+sd): WtFl[z*768 + n][k] = bf16(src_z[l][k][n])
__global__ __launch_bounds__(256) void twt4_kernel(const float* __restrict__ w_sc,
                                                   const float* __restrict__ w_dc,
                                                   const float* __restrict__ w_scb,
                                                   const float* __restrict__ w_dcb,
                                                   bf16* __restrict__ WtFl, int l) {
    const int z = blockIdx.z;
    const float* src;
    if (z == 0) src = w_sc; else if (z == 1) src = w_dc; else if (z == 2) src = w_scb; else src = w_dcb;
    src += (size_t)l * FDIM * FDIM;
    bf16* dst = WtFl + (size_t)z * FDIM * FDIM;

    __shared__ float tile[32][33];
    const int tx = threadIdx.x & 31, ty = threadIdx.x >> 5;
    const int x0 = blockIdx.x * 32, y0 = blockIdx.y * 32;
#pragma unroll
    for (int q = 0; q < 4; ++q)
        tile[ty + q * 8][tx] = src[(size_t)(y0 + ty + q * 8) * FDIM + x0 + tx];
    __syncthreads();
#pragma unroll
    for (int q = 0; q < 4; ++q)
        dst[(size_t)(x0 + ty + q * 8) * FDIM + y0 + tx] = __float2bfloat16(tile[tx][ty + q * 8]);
}

// ---------------- bias pack: pb[l][3072] ----------------
__global__ __launch_bounds__(256) void bias_pack_kernel(const float* __restrict__ b_sc,
                                                        const float* __restrict__ b_dc,
                                                        const float* __restrict__ b_scb,
                                                        const float* __restrict__ b_dcb,
                                                        float* __restrict__ pb) {
    const int idx = blockIdx.x * 256 + threadIdx.x;
    if (idx >= 2 * NFUSE) return;
    const int l = idx / NFUSE, c = idx % NFUSE;
    const int sel = c / FDIM, off = c % FDIM;
    const float* src;
    if (sel == 0) src = b_sc; else if (sel == 1) src = b_dc; else if (sel == 2) src = b_scb; else src = b_dcb;
    pb[idx] = src[l * FDIM + off];
}

// ---------------- deep-pipelined MFMA GEMM: C[M,3072] = A[M,768] @ WtFl^T + pb ----------------
// 256x256 tile, 8 waves (2x4), BK=32, 4-slot LDS ring (128 KB), prefetch distance 3,
// counted vmcnt(8) at K-tile boundaries (never 0 in steady state), setprio around MFMA.
#define GBM 256
#define GBN 256
#define NKT 24                               // 768/32
#define TILES_M ((N_NODES + GBM - 1) / GBM)  // 196
#define TILES_N (NFUSE / GBN)                // 12
#define NWG (TILES_M * TILES_N)              // 2352 = 8*294

__global__ __launch_bounds__(512, 1) void gemm_fused(const bf16* __restrict__ A,
                                                     const bf16* __restrict__ Wt,
                                                     const float* __restrict__ pb,
                                                     bf16* __restrict__ C, int M) {
    // slot = one K-tile: A 256x32 + B 256x32 (8192 shorts each) -> 4 slots = 128 KB
    __shared__ __align__(16) short lds[4][2][8192];
    const int t = threadIdx.x;
    const int wid = t >> 6, lane = t & 63;
    const int wr = wid >> 2, wc = wid & 3;       // 2 x 4 waves, per-wave 128x64
    const int lr = lane & 15, lk = lane >> 4;

    // bijective XCD swizzle (2352 = 8*294), n-fastest for A-panel L2 reuse
    const int orig = blockIdx.x;
    const int swz = (orig & 7) * (NWG / 8) + (orig >> 3);
    const int tm = swz / TILES_N, tn = swz % TILES_N;
    const int m0 = tm * GBM, n0 = tn * GBN;

    const f32x4 zero4 = {0.f, 0.f, 0.f, 0.f};
    f32x4 acc[8][4];
#pragma unroll
    for (int i = 0; i < 8; ++i)
#pragma unroll
        for (int j = 0; j < 4; ++j) acc[i][j] = zero4;

    // Staging: slot s = issue*512 + t -> row rr=s>>2, chunk p=s&3 (16B chunks).
    // LDS linear; global source chunk = p ^ ((rr>>1)&3). Same for both issues.
    const int rr0 = t >> 2;
    const int cswz = (((t & 3) ^ ((t >> 3) & 3)) << 3);  // element offset in row
    int ar0 = m0 + rr0;        if (ar0 >= M) ar0 = M - 1;
    int ar1 = m0 + 128 + rr0;  if (ar1 >= M) ar1 = M - 1;
    const int br0 = n0 + rr0, br1 = n0 + 128 + rr0;
    const int d0 = wid * 1024;           // byte offset, issue 0 (lane*16 added by HW)
    const int d1 = 8192 + wid * 1024;    // byte offset, issue 1

#define STAGE_A(sl, kt) {                                                          \
        const int k0_ = (kt) * 32;                                                 \
        load_lds16(A + (size_t)ar0 * FDIM + k0_ + cswz, (char*)&lds[sl][0][0] + d0); \
        load_lds16(A + (size_t)ar1 * FDIM + k0_ + cswz, (char*)&lds[sl][0][0] + d1); }
#define STAGE_B(sl, kt) {                                                          \
        const int k0_ = (kt) * 32;                                                 \
        load_lds16(Wt + (size_t)br0 * FDIM + k0_ + cswz, (char*)&lds[sl][1][0] + d0); \
        load_lds16(Wt + (size_t)br1 * FDIM + k0_ + cswz, (char*)&lds[sl][1][0] + d1); }

    // Read-side: global chunk lk at row r lives in slot chunk lk ^ ((r>>1)&3);
    // (r>>1)&3 == (lr>>1)&3 for all our frag rows -> per-lane constant.
    const int rsw = ((lk ^ ((lr >> 1) & 3)) << 3);  // element offset
    const int arow_base = wr * 128 + lr;
    const int brow_base = wc * 64 + lr;

    // Prologue: stage K0..K2 (12 loads), ensure K0 landed (8 newest = K1,K2 may fly).
    STAGE_A(0, 0); STAGE_B(0, 0);
    STAGE_A(1, 1); STAGE_B(1, 1);
    STAGE_A(2, 2); STAGE_B(2, 2);
    asm volatile("s_waitcnt vmcnt(8)" ::: "memory");
    asm volatile("s_barrier" ::: "memory");

    for (int j = 0; j < NKT; ++j) {
        const int cs = j & 3;
        const int ss = (j + 3) & 3;
        const bool st = (j + 3) < NKT;

        // ---- phase 0: A-frags 0..3 + all B-frags; stage A of K_{j+3} ----
        bf16x8 av[4], bv[4];
#pragma unroll
        for (int i = 0; i < 4; ++i)
            av[i] = *(const bf16x8*)&lds[cs][0][(arow_base + i * 16) * 32 + rsw];
#pragma unroll
        for (int jj = 0; jj < 4; ++jj)
            bv[jj] = *(const bf16x8*)&lds[cs][1][(brow_base + jj * 16) * 32 + rsw];
        if (st) STAGE_A(ss, j + 3);
        asm volatile("s_barrier" ::: "memory");
        __builtin_amdgcn_s_setprio(1);
#pragma unroll
        for (int i = 0; i < 4; ++i)
#pragma unroll
            for (int jj = 0; jj < 4; ++jj)
                acc[i][jj] = __builtin_amdgcn_mfma_f32_16x16x32_bf16(bv[jj], av[i], acc[i][jj], 0, 0, 0);
        __builtin_amdgcn_s_setprio(0);
        asm volatile("s_barrier" ::: "memory");

        // ---- phase 1: A-frags 4..7 (bv reused); stage B of K_{j+3} ----
        bf16x8 av2[4];
#pragma unroll
        for (int i = 0; i < 4; ++i)
            av2[i] = *(const bf16x8*)&lds[cs][0][(arow_base + (4 + i) * 16) * 32 + rsw];
        if (st) STAGE_B(ss, j + 3);
        asm volatile("s_barrier" ::: "memory");
        __builtin_amdgcn_s_setprio(1);
#pragma unroll
        for (int i = 0; i < 4; ++i)
#pragma unroll
            for (int jj = 0; jj < 4; ++jj)
                acc[4 + i][jj] = __builtin_amdgcn_mfma_f32_16x16x32_bf16(bv[jj], av2[i], acc[4 + i][jj], 0, 0, 0);
        __builtin_amdgcn_s_setprio(0);
        // K-tile boundary: ensure K_{j+1} resident; allow K_{j+2},K_{j+3} in flight.
        if (j <= NKT - 4)      { asm volatile("s_waitcnt vmcnt(8)" ::: "memory"); }
        else if (j == NKT - 3) { asm volatile("s_waitcnt vmcnt(4)" ::: "memory"); }
        else if (j == NKT - 2) { asm volatile("s_waitcnt vmcnt(0)" ::: "memory"); }
        asm volatile("s_barrier" ::: "memory");
    }
#undef STAGE_A
#undef STAGE_B

    // Epilogue (swapped-operand D): row = m0+wr*128+i*16+lr; col = n0+wc*64+jj*16+lk*4+reg.
#pragma unroll
    for (int i = 0; i < 8; ++i) {
        const int row = m0 + wr * 128 + i * 16 + lr;
        if (row < M) {
#pragma unroll
            for (int jj = 0; jj < 4; ++jj) {
                const int col = n0 + wc * 64 + jj * 16 + lk * 4;
                const float4 b4 = *(const float4*)(pb + col);
                ushort4 w;
                w.x = f2u(acc[i][jj][0] + b4.x);
                w.y = f2u(acc[i][jj][1] + b4.y);
                w.z = f2u(acc[i][jj][2] + b4.z);
                w.w = f2u(acc[i][jj][3] + b4.w);
                *(ushort4*)(C + (size_t)row * NFUSE + col) = w;
            }
        }
    }
}

// ---------------- CSR build ----------------
__global__ __launch_bounds__(256) void hist_kernel(const int* __restrict__ dst, int* __restrict__ deg) {
    const int e = blockIdx.x * 256 + threadIdx.x;
    if (e < NE) atomicAdd(&deg[dst[e]], 1);
}

__global__ __launch_bounds__(256) void scan_kernel(const int* __restrict__ deg,
                                                   int* __restrict__ rowp,
                                                   int* __restrict__ cursor) {
    __shared__ int pref[257];
    const int t = threadIdx.x;
    const int CH = (N_NODES + 255) / 256;
    const int b0 = t * CH;
    const int b1 = (b0 + CH < N_NODES) ? b0 + CH : N_NODES;
    int s = 0;
    for (int i = b0; i < b1; ++i) s += deg[i];
    __shared__ int part[256];
    part[t] = s;
    __syncthreads();
    if (t == 0) {
        int acc = 0;
        for (int i = 0; i < 256; ++i) { pref[i] = acc; acc += part[i]; }
        pref[256] = acc;
    }
    __syncthreads();
    int run = pref[t];
    for (int i = b0; i < b1; ++i) { rowp[i] = run; cursor[i] = run; run += deg[i]; }
    if (t == 255) rowp[N_NODES] = run;
}

__global__ __launch_bounds__(256) void scatter_kernel(const int* __restrict__ dst,
                                                      int* __restrict__ cursor,
                                                      int* __restrict__ eid) {
    const int e = blockIdx.x * 256 + threadIdx.x;
    if (e < NE) {
        const int p = atomicAdd(&cursor[dst[e]], 1);
        eid[p] = e;
    }
}

// ---------------- per-relation online-softmax attention accumulate ----------------
__device__ inline void att_accum(const bf16* __restrict__ fsd, int n, int lane,
                                 const float* __restrict__ attn,
                                 const int* __restrict__ rowp, const int* __restrict__ eid,
                                 const int* __restrict__ src, int fs_off, int fd_off,
                                 float* __restrict__ out) {
    float fdv[12], atv[12];
    {
        const ushort4* pfd = (const ushort4*)(fsd + (size_t)n * NFUSE + fd_off + lane * 12);
        const ushort4 d0 = pfd[0], d1 = pfd[1], d2 = pfd[2];
        fdv[0] = u2f(d0.x); fdv[1] = u2f(d0.y); fdv[2] = u2f(d0.z); fdv[3] = u2f(d0.w);
        fdv[4] = u2f(d1.x); fdv[5] = u2f(d1.y); fdv[6] = u2f(d1.z); fdv[7] = u2f(d1.w);
        fdv[8] = u2f(d2.x); fdv[9] = u2f(d2.y); fdv[10] = u2f(d2.z); fdv[11] = u2f(d2.w);
        const float4* pat = (const float4*)(attn + lane * 12);
        const float4 a0 = pat[0], a1 = pat[1], a2 = pat[2];
        atv[0] = a0.x; atv[1] = a0.y; atv[2] = a0.z; atv[3] = a0.w;
        atv[4] = a1.x; atv[5] = a1.y; atv[6] = a1.z; atv[7] = a1.w;
        atv[8] = a2.x; atv[9] = a2.y; atv[10] = a2.z; atv[11] = a2.w;
    }
    const int beg = rowp[n], end = rowp[n + 1];
    float m = -INFINITY, den = 0.f;
    float acc[12];
#pragma unroll
    for (int j = 0; j < 12; ++j) acc[j] = 0.f;

    for (int i = beg; i < end; ++i) {
        const int e = eid[i];
        const ushort4* pf = (const ushort4*)(fsd + (size_t)src[e] * NFUSE + fs_off + lane * 12);
        const ushort4 a0 = pf[0], a1 = pf[1], a2 = pf[2];
        float fsv[12];
        fsv[0] = u2f(a0.x); fsv[1] = u2f(a0.y); fsv[2] = u2f(a0.z); fsv[3] = u2f(a0.w);
        fsv[4] = u2f(a1.x); fsv[5] = u2f(a1.y); fsv[6] = u2f(a1.z); fsv[7] = u2f(a1.w);
        fsv[8] = u2f(a2.x); fsv[9] = u2f(a2.y); fsv[10] = u2f(a2.z); fsv[11] = u2f(a2.w);
        float p = 0.f;
#pragma unroll
        for (int j = 0; j < 12; ++j) {
            float x = fsv[j] + fdv[j];
            x = (x > 0.f) ? x : 0.2f * x;
            p += x * atv[j];
        }
        p += __shfl_xor(p, 1);
        p += __shfl_xor(p, 2);
        p += __shfl_xor(p, 4);
        if (p > m) {
            const float sc = expf(m - p);
            den *= sc;
#pragma unroll
            for (int j = 0; j < 12; ++j) acc[j] *= sc;
            m = p;
        }
        const float w = expf(p - m);
        den += w;
#pragma unroll
        for (int j = 0; j < 12; ++j) acc[j] += w * fsv[j];
    }
    const float inv = (den > 0.f) ? 1.f / den : 0.f;
#pragma unroll
    for (int j = 0; j < 12; ++j) out[j] = acc[j] * inv;
}

// ---------------- merged agg: h[n] = bf16(h + att_r0 + att_r1), wave per node ----------------
__global__ __launch_bounds__(256) void agg2_kernel(const bf16* __restrict__ fsd,
                                                   const float* __restrict__ attn0,
                                                   const float* __restrict__ attn1,
                                                   const int* __restrict__ rowp0,
                                                   const int* __restrict__ eid0,
                                                   const int* __restrict__ src0,
                                                   const int* __restrict__ rowp1,
                                                   const int* __restrict__ eid1,
                                                   const int* __restrict__ src1,
                                                   bf16* __restrict__ h) {
    const int wid = threadIdx.x >> 6;
    const int lane = threadIdx.x & 63;
    const int n = blockIdx.x * 4 + wid;
    if (n >= N_NODES) return;

    float a0[12], a1[12];
    att_accum(fsd, n, lane, attn0, rowp0, eid0, src0, 0, 768, a0);
    att_accum(fsd, n, lane, attn1, rowp1, eid1, src1, 1536, 2304, a1);

    const size_t base = (size_t)n * FDIM + lane * 12;
    const ushort4* ph = (const ushort4*)(h + base);
    const ushort4 h0 = ph[0], h1 = ph[1], h2 = ph[2];
    ushort4 r0, r1, r2;
    r0.x = f2u(u2f(h0.x) + a0[0] + a1[0]);  r0.y = f2u(u2f(h0.y) + a0[1] + a1[1]);
    r0.z = f2u(u2f(h0.z) + a0[2] + a1[2]);  r0.w = f2u(u2f(h0.w) + a0[3] + a1[3]);
    r1.x = f2u(u2f(h1.x) + a0[4] + a1[4]);  r1.y = f2u(u2f(h1.y) + a0[5] + a1[5]);
    r1.z = f2u(u2f(h1.z) + a0[6] + a1[6]);  r1.w = f2u(u2f(h1.w) + a0[7] + a1[7]);
    r2.x = f2u(u2f(h2.x) + a0[8] + a1[8]);  r2.y = f2u(u2f(h2.y) + a0[9] + a1[9]);
    r2.z = f2u(u2f(h2.z) + a0[10] + a1[10]); r2.w = f2u(u2f(h2.w) + a0[11] + a1[11]);
    ((ushort4*)(h + base))[0] = r0; ((ushort4*)(h + base))[1] = r1; ((ushort4*)(h + base))[2] = r2;
}

// ---------------- MLP head ----------------
__global__ __launch_bounds__(256) void head_kernel(const bf16* __restrict__ h,
                                                   const int* __restrict__ gsi,
                                                   const float* __restrict__ fc1w,
                                                   const float* __restrict__ fc1b,
                                                   const float* __restrict__ fc2w,
                                                   const float* __restrict__ fc2b,
                                                   float* __restrict__ out) {
    __shared__ float fe[FDIM];
    __shared__ float hid[256];
    const int b = blockIdx.x, t = threadIdx.x;
    const int node = gsi[b];
    for (int i = t; i < FDIM; i += 256) fe[i] = __bfloat162float(h[(size_t)node * FDIM + i]);
    __syncthreads();
    float acc = fc1b[t];
    for (int k = 0; k < FDIM; ++k) acc += fe[k] * fc1w[k * 256 + t];
    hid[t] = (acc > 0.f) ? acc : 0.f;
    __syncthreads();
    if (t < NC) {
        float acc2 = fc2b[t];
        for (int k = 0; k < 256; ++k) acc2 += hid[k] * fc2w[k * NC + t];
        out[1 + b * NC + t] = acc2;
    }
}

// ---------------- loss ----------------
__global__ __launch_bounds__(256) void loss_kernel(const float* __restrict__ logits,
                                                   const int* __restrict__ labels,
                                                   float* __restrict__ out) {
    __shared__ float red[256];
    const int b = threadIdx.x;
    float m = -INFINITY;
    for (int c = 0; c < NC; ++c) m = fmaxf(m, logits[b * NC + c]);
    float sum = 0.f;
    for (int c = 0; c < NC; ++c) sum += expf(logits[b * NC + c] - m);
    const float lse = m + logf(sum);
    const float ll = logits[b * NC + labels[b]];
    red[b] = lse - ll;
    __syncthreads();
    for (int s = 128; s > 0; s >>= 1) {
        if (b < s) red[b] += red[b + s];
        __syncthreads();
    }
    if (b == 0) out[0] = red[0] / (float)NB;
}

extern "C" void kernel_launch(void* const* d_in, const int* in_sizes, int n_in,
                              void* d_out, int out_size, void* d_ws, size_t ws_size,
                              hipStream_t stream) {
    const float* feats = (const float*)d_in[0];
    const float* fc1w  = (const float*)d_in[11];
    const float* fc1b  = (const float*)d_in[12];
    const float* fc2w  = (const float*)d_in[13];
    const float* fc2b  = (const float*)d_in[14];
    const int* gsi     = (const int*)d_in[19];
    const int* labels  = (const int*)d_in[20];

    const size_t NF = (size_t)N_NODES * FDIM;
    const size_t WSZ = (size_t)FDIM * FDIM;
    char* p = (char*)d_ws;
    bf16* h    = (bf16*)p;  p += NF * 2;
    bf16* fsd  = (bf16*)p;  p += (size_t)N_NODES * NFUSE * 2;
    bf16* WtFl = (bf16*)p;  p += 4 * WSZ * 2;   // one layer's 4 matrices [3072][768]
    float* pb  = (float*)p; p += 2 * NFUSE * 4; // packed bias, both layers
    int* deg[2];  int* rowp[2];  int* cursor[2];  int* eid[2];
    for (int r = 0; r < 2; ++r) {
        deg[r]    = (int*)p; p += (size_t)N_NODES * 4 + 256;
        rowp[r]   = (int*)p; p += ((size_t)N_NODES + 1) * 4 + 256;
        cursor[r] = (int*)p; p += (size_t)N_NODES * 4 + 256;
        eid[r]    = (int*)p; p += (size_t)NE * 4 + 256;
    }

    cvt_kernel<<<2048, 256, 0, stream>>>(feats, h);
    bias_pack_kernel<<<(2 * NFUSE + 255) / 256, 256, 0, stream>>>(
        (const float*)d_in[2], (const float*)d_in[4], (const float*)d_in[7], (const float*)d_in[9], pb);

    // Build CSR per relation (dst is layer-invariant).
    for (int r = 0; r < 2; ++r) {
        const int* dst = (const int*)d_in[r == 0 ? 16 : 18];
        hipMemsetAsync(deg[r], 0, sizeof(int) * N_NODES, stream);
        hist_kernel<<<(NE + 255) / 256, 256, 0, stream>>>(dst, deg[r]);
        scan_kernel<<<1, 256, 0, stream>>>(deg[r], rowp[r], cursor[r]);
        scatter_kernel<<<(NE + 255) / 256, 256, 0, stream>>>(dst, cursor[r], eid[r]);
    }

    const int node_blocks = (N_NODES + 3) / 4;
    dim3 tgrid(FDIM / 32, FDIM / 32, 4);

    for (int l = 0; l < 2; ++l) {
        twt4_kernel<<<tgrid, 256, 0, stream>>>(
            (const float*)d_in[1], (const float*)d_in[3],
            (const float*)d_in[6], (const float*)d_in[8], WtFl, l);
        gemm_fused<<<NWG, 512, 0, stream>>>(h, WtFl, pb + (size_t)l * NFUSE, fsd, N_NODES);
        agg2_kernel<<<node_blocks, 256, 0, stream>>>(
            fsd, (const float*)d_in[5] + (size_t)l * FDIM, (const float*)d_in[10] + (size_t)l * FDIM,
            rowp[0], eid[0], (const int*)d_in[15],
            rowp[1], eid[1], (const int*)d_in[17], h);
    }

    head_kernel<<<NB, 256, 0, stream>>>(h, gsi, fc1w, fc1b, fc2w, fc2b, (float*)d_out);
    loss_kernel<<<1, 256, 0, stream>>>((float*)d_out + 1, labels, (float*)d_out);
}

// Round 7
// 1318.979 us; speedup vs baseline: 14.2673x; 1.0157x over previous
//
#include <hip/hip_runtime.h>
#include <hip/hip_bf16.h>
#include <math.h>

#define N_NODES 50000
#define NE      100000
#define NH      8
#define FDIM    768
#define NFUSE   3072
#define NB      256
#define NC      31

typedef __hip_bfloat16 bf16;
typedef __attribute__((ext_vector_type(8))) short bf16x8;
typedef __attribute__((ext_vector_type(4))) float f32x4;

__device__ inline float u2f(unsigned short u) { return __uint_as_float(((unsigned int)u) << 16); }
__device__ inline unsigned short f2u(float f) { return __bfloat16_as_ushort(__float2bfloat16(f)); }

__device__ inline void load_lds16(const void* g, void* l) {
    __builtin_amdgcn_global_load_lds(
        (const __attribute__((address_space(1))) void*)g,
        (__attribute__((address_space(3))) void*)l, 16, 0, 0);
}

// ---------------- convert f32 -> bf16 ----------------
__global__ __launch_bounds__(256) void cvt_kernel(const float* __restrict__ in,
                                                  bf16* __restrict__ out) {
    const size_t total = (size_t)N_NODES * FDIM;
    const size_t stride = (size_t)gridDim.x * blockDim.x;
    for (size_t i = blockIdx.x * (size_t)blockDim.x + threadIdx.x; i < total; i += stride)
        out[i] = __float2bfloat16(in[i]);
}

// ---------------- weight transpose+convert, 4 matrices of one layer ----------------
__global__ __launch_bounds__(256) void twt4_kernel(const float* __restrict__ w_sc,
                                                   const float* __restrict__ w_dc,
                                                   const float* __restrict__ w_scb,
                                                   const float* __restrict__ w_dcb,
                                                   bf16* __restrict__ WtFl, int l) {
    const int z = blockIdx.z;
    const float* src;
    if (z == 0) src = w_sc; else if (z == 1) src = w_dc; else if (z == 2) src = w_scb; else src = w_dcb;
    src += (size_t)l * FDIM * FDIM;
    bf16* dst = WtFl + (size_t)z * FDIM * FDIM;

    __shared__ float tile[32][33];
    const int tx = threadIdx.x & 31, ty = threadIdx.x >> 5;
    const int x0 = blockIdx.x * 32, y0 = blockIdx.y * 32;
#pragma unroll
    for (int q = 0; q < 4; ++q)
        tile[ty + q * 8][tx] = src[(size_t)(y0 + ty + q * 8) * FDIM + x0 + tx];
    __syncthreads();
#pragma unroll
    for (int q = 0; q < 4; ++q)
        dst[(size_t)(x0 + ty + q * 8) * FDIM + y0 + tx] = __float2bfloat16(tile[tx][ty + q * 8]);
}

// ---------------- bias pack: pb[l][3072] ----------------
__global__ __launch_bounds__(256) void bias_pack_kernel(const float* __restrict__ b_sc,
                                                        const float* __restrict__ b_dc,
                                                        const float* __restrict__ b_scb,
                                                        const float* __restrict__ b_dcb,
                                                        float* __restrict__ pb) {
    const int idx = blockIdx.x * 256 + threadIdx.x;
    if (idx >= 2 * NFUSE) return;
    const int l = idx / NFUSE, c = idx % NFUSE;
    const int sel = c / FDIM, off = c % FDIM;
    const float* src;
    if (sel == 0) src = b_sc; else if (sel == 1) src = b_dc; else if (sel == 2) src = b_scb; else src = b_dcb;
    pb[idx] = src[l * FDIM + off];
}

// ---------------- 8-phase MFMA GEMM: C[M,3072] = A[M,768] @ WtFl^T + pb ----------------
// 256x256 tile, 8 waves (2x4), BK=64 as 2 kh-slabs of 32, double-buffered LDS (128 KB).
// Per K-tile: 4 phases {ds_read subtile | stage 1 unit (2 gload) | barrier | lgkmcnt(0)
// | setprio 16xMFMA | barrier}; counted vmcnt(4) at ends of P2 and P4 (never drains
// mid-loop). Stage order: A-kh0, B-kh0, A-kh1, B-kh1 of tile j+1.
// Ledger (per-thread, 2 loads/phase): P4(j)-end vmcnt(4) retires {A-kh0,B-kh0}(j+1)
// needed at P1(j+1), leaving kh1(j+1) in flight; P2(j)-end vmcnt(4) retires kh1(j)
// needed at P3(j), leaving kh0(j+1) in flight.
#define GBM 256
#define GBN 256
#define NKT 12                               // 768/64
#define TILES_M ((N_NODES + GBM - 1) / GBM)  // 196
#define TILES_N (NFUSE / GBN)                // 12
#define NWG (TILES_M * TILES_N)              // 2352 = 8*294

__global__ __launch_bounds__(512, 1) void gemm_fused(const bf16* __restrict__ A,
                                                     const bf16* __restrict__ Wt,
                                                     const float* __restrict__ pb,
                                                     bf16* __restrict__ C, int M) {
    // [dbuf][op A=0/B=1][kh][256 rows x 32 cols] ; slab row = 64 B
    __shared__ __align__(16) short lds[2][2][2][8192];
    const int t = threadIdx.x;
    const int wid = t >> 6, lane = t & 63;
    const int wr = wid >> 2, wc = wid & 3;       // 2M x 4N waves, per-wave 128x64 output
    const int lr = lane & 15, lk = lane >> 4;

    // bijective XCD swizzle (2352 = 8*294), n-fastest for A-panel L2 reuse
    const int orig = blockIdx.x;
    const int swz = (orig & 7) * (NWG / 8) + (orig >> 3);
    const int tm = swz / TILES_N, tn = swz % TILES_N;
    const int m0 = tm * GBM, n0 = tn * GBN;

    const f32x4 zero4 = {0.f, 0.f, 0.f, 0.f};
    f32x4 acc[8][4];
#pragma unroll
    for (int i = 0; i < 8; ++i)
#pragma unroll
        for (int j = 0; j < 4; ++j) acc[i][j] = zero4;

    // ---- staging precompute ----
    // Unit = one (op, kh) slab of 256 rows x 32 cols = 16 KB = 2 loads/thread.
    // load q: lds bytes [wid*2048 + q*1024 + lane*16] -> row wid*32+q*16+(lane>>2),
    // slot lane&3; source chunk = slot ^ ((row>>1)&3) = (lane&3)^((lane>>3)&3).
    const int scol_sw = (((lane & 3) ^ ((lane >> 3) & 3)) << 3);  // elements
    int arow[2], brow[2], dstq[2];
#pragma unroll
    for (int q = 0; q < 2; ++q) {
        const int r = wid * 32 + q * 16 + (lane >> 2);
        int ra = m0 + r; if (ra >= M) ra = M - 1;
        arow[q] = ra;
        brow[q] = n0 + r;
        dstq[q] = wid * 2048 + q * 1024;  // wave-uniform byte base within slab
    }
    // read-side swizzled element offset within a 32-elem row (constant per lane)
    const int rsw = ((lk ^ ((lr >> 1) & 3)) << 3);
    const int abase = wr * 128 + lr;
    const int bbase = wc * 64 + lr;

#define STG_A(d, kh, kt) {                                                                  \
        load_lds16(A + (size_t)arow[0] * FDIM + (kt) * 64 + (kh) * 32 + scol_sw,            \
                   (char*)&lds[d][0][kh][0] + dstq[0]);                                     \
        load_lds16(A + (size_t)arow[1] * FDIM + (kt) * 64 + (kh) * 32 + scol_sw,            \
                   (char*)&lds[d][0][kh][0] + dstq[1]); }
#define STG_B(d, kh, kt) {                                                                  \
        load_lds16(Wt + (size_t)brow[0] * FDIM + (kt) * 64 + (kh) * 32 + scol_sw,           \
                   (char*)&lds[d][1][kh][0] + dstq[0]);                                     \
        load_lds16(Wt + (size_t)brow[1] * FDIM + (kt) * 64 + (kh) * 32 + scol_sw,           \
                   (char*)&lds[d][1][kh][0] + dstq[1]); }

    // Prologue: tile 0 -> dbuf 0 (order A-kh0, B-kh0, A-kh1, B-kh1 = 8 loads),
    // vmcnt(4): kh0 landed, kh1 in flight.
    STG_A(0, 0, 0); STG_B(0, 0, 0); STG_A(0, 1, 0); STG_B(0, 1, 0);
    asm volatile("s_waitcnt vmcnt(4)");
    __builtin_amdgcn_s_barrier();
    __builtin_amdgcn_sched_barrier(0);

    int db = 0;
    for (int j = 0; j < NKT; ++j) {
        const int nd = db ^ 1;
        const bool st = (j + 1) < NKT;
        const short* Ak0 = &lds[db][0][0][0];
        const short* Bk0 = &lds[db][1][0][0];
        const short* Ak1 = &lds[db][0][1][0];
        const short* Bk1 = &lds[db][1][1][0];
        bf16x8 av[4], bv[4], av2[4];

        // ---- P1: quadrant (kh0, i0-3); stage A-kh0(j+1) ----
#pragma unroll
        for (int i = 0; i < 4; ++i) av[i] = *(const bf16x8*)&Ak0[(abase + i * 16) * 32 + rsw];
#pragma unroll
        for (int jj = 0; jj < 4; ++jj) bv[jj] = *(const bf16x8*)&Bk0[(bbase + jj * 16) * 32 + rsw];
        if (st) STG_A(nd, 0, j + 1);
        __builtin_amdgcn_s_barrier();
        asm volatile("s_waitcnt lgkmcnt(0)");
        __builtin_amdgcn_sched_barrier(0);
        __builtin_amdgcn_s_setprio(1);
#pragma unroll
        for (int i = 0; i < 4; ++i)
#pragma unroll
            for (int jj = 0; jj < 4; ++jj)
                acc[i][jj] = __builtin_amdgcn_mfma_f32_16x16x32_bf16(bv[jj], av[i], acc[i][jj], 0, 0, 0);
        __builtin_amdgcn_s_setprio(0);
        __builtin_amdgcn_s_barrier();
        __builtin_amdgcn_sched_barrier(0);

        // ---- P2: quadrant (kh0, i4-7); stage B-kh0(j+1); vmcnt(4) ----
#pragma unroll
        for (int i = 0; i < 4; ++i) av2[i] = *(const bf16x8*)&Ak0[(abase + (4 + i) * 16) * 32 + rsw];
        if (st) STG_B(nd, 0, j + 1);
        __builtin_amdgcn_s_barrier();
        asm volatile("s_waitcnt lgkmcnt(0)");
        __builtin_amdgcn_sched_barrier(0);
        __builtin_amdgcn_s_setprio(1);
#pragma unroll
        for (int i = 0; i < 4; ++i)
#pragma unroll
            for (int jj = 0; jj < 4; ++jj)
                acc[4 + i][jj] = __builtin_amdgcn_mfma_f32_16x16x32_bf16(bv[jj], av2[i], acc[4 + i][jj], 0, 0, 0);
        __builtin_amdgcn_s_setprio(0);
        if (st) { asm volatile("s_waitcnt vmcnt(4)"); }
        else    { asm volatile("s_waitcnt vmcnt(0)"); }
        __builtin_amdgcn_s_barrier();
        __builtin_amdgcn_sched_barrier(0);

        // ---- P3: quadrant (kh1, i0-3); stage A-kh1(j+1) ----
#pragma unroll
        for (int i = 0; i < 4; ++i) av[i] = *(const bf16x8*)&Ak1[(abase + i * 16) * 32 + rsw];
#pragma unroll
        for (int jj = 0; jj < 4; ++jj) bv[jj] = *(const bf16x8*)&Bk1[(bbase + jj * 16) * 32 + rsw];
        if (st) STG_A(nd, 1, j + 1);
        __builtin_amdgcn_s_barrier();
        asm volatile("s_waitcnt lgkmcnt(0)");
        __builtin_amdgcn_sched_barrier(0);
        __builtin_amdgcn_s_setprio(1);
#pragma unroll
        for (int i = 0; i < 4; ++i)
#pragma unroll
            for (int jj = 0; jj < 4; ++jj)
                acc[i][jj] = __builtin_amdgcn_mfma_f32_16x16x32_bf16(bv[jj], av[i], acc[i][jj], 0, 0, 0);
        __builtin_amdgcn_s_setprio(0);
        __builtin_amdgcn_s_barrier();
        __builtin_amdgcn_sched_barrier(0);

        // ---- P4: quadrant (kh1, i4-7); stage B-kh1(j+1); vmcnt(4) ----
#pragma unroll
        for (int i = 0; i < 4; ++i) av2[i] = *(const bf16x8*)&Ak1[(abase + (4 + i) * 16) * 32 + rsw];
        if (st) STG_B(nd, 1, j + 1);
        __builtin_amdgcn_s_barrier();
        asm volatile("s_waitcnt lgkmcnt(0)");
        __builtin_amdgcn_sched_barrier(0);
        __builtin_amdgcn_s_setprio(1);
#pragma unroll
        for (int i = 0; i < 4; ++i)
#pragma unroll
            for (int jj = 0; jj < 4; ++jj)
                acc[4 + i][jj] = __builtin_amdgcn_mfma_f32_16x16x32_bf16(bv[jj], av2[i], acc[4 + i][jj], 0, 0, 0);
        __builtin_amdgcn_s_setprio(0);
        if (st) { asm volatile("s_waitcnt vmcnt(4)"); }
        __builtin_amdgcn_s_barrier();
        __builtin_amdgcn_sched_barrier(0);

        db = nd;
    }
#undef STG_A
#undef STG_B

    // Epilogue (swapped-operand D): row = m0+wr*128+i*16+lr; col = n0+wc*64+jj*16+lk*4.
#pragma unroll
    for (int i = 0; i < 8; ++i) {
        const int row = m0 + wr * 128 + i * 16 + lr;
        if (row < M) {
#pragma unroll
            for (int jj = 0; jj < 4; ++jj) {
                const int col = n0 + wc * 64 + jj * 16 + lk * 4;
                const float4 b4 = *(const float4*)(pb + col);
                ushort4 w;
                w.x = f2u(acc[i][jj][0] + b4.x);
                w.y = f2u(acc[i][jj][1] + b4.y);
                w.z = f2u(acc[i][jj][2] + b4.z);
                w.w = f2u(acc[i][jj][3] + b4.w);
                *(ushort4*)(C + (size_t)row * NFUSE + col) = w;
            }
        }
    }
}

// ---------------- CSR build ----------------
__global__ __launch_bounds__(256) void hist_kernel(const int* __restrict__ dst, int* __restrict__ deg) {
    const int e = blockIdx.x * 256 + threadIdx.x;
    if (e < NE) atomicAdd(&deg[dst[e]], 1);
}

__global__ __launch_bounds__(256) void scan_kernel(const int* __restrict__ deg,
                                                   int* __restrict__ rowp,
                                                   int* __restrict__ cursor) {
    __shared__ int pref[257];
    const int t = threadIdx.x;
    const int CH = (N_NODES + 255) / 256;
    const int b0 = t * CH;
    const int b1 = (b0 + CH < N_NODES) ? b0 + CH : N_NODES;
    int s = 0;
    for (int i = b0; i < b1; ++i) s += deg[i];
    __shared__ int part[256];
    part[t] = s;
    __syncthreads();
    if (t == 0) {
        int acc = 0;
        for (int i = 0; i < 256; ++i) { pref[i] = acc; acc += part[i]; }
        pref[256] = acc;
    }
    __syncthreads();
    int run = pref[t];
    for (int i = b0; i < b1; ++i) { rowp[i] = run; cursor[i] = run; run += deg[i]; }
    if (t == 255) rowp[N_NODES] = run;
}

__global__ __launch_bounds__(256) void scatter_kernel(const int* __restrict__ dst,
                                                      int* __restrict__ cursor,
                                                      int* __restrict__ eid) {
    const int e = blockIdx.x * 256 + threadIdx.x;
    if (e < NE) {
        const int p = atomicAdd(&cursor[dst[e]], 1);
        eid[p] = e;
    }
}

// ---------------- per-relation online-softmax attention accumulate ----------------
__device__ inline void att_accum(const bf16* __restrict__ fsd, int n, int lane,
                                 const float* __restrict__ attn,
                                 const int* __restrict__ rowp, const int* __restrict__ eid,
                                 const int* __restrict__ src, int fs_off, int fd_off,
                                 float* __restrict__ out) {
    float fdv[12], atv[12];
    {
        const ushort4* pfd = (const ushort4*)(fsd + (size_t)n * NFUSE + fd_off + lane * 12);
        const ushort4 d0 = pfd[0], d1 = pfd[1], d2 = pfd[2];
        fdv[0] = u2f(d0.x); fdv[1] = u2f(d0.y); fdv[2] = u2f(d0.z); fdv[3] = u2f(d0.w);
        fdv[4] = u2f(d1.x); fdv[5] = u2f(d1.y); fdv[6] = u2f(d1.z); fdv[7] = u2f(d1.w);
        fdv[8] = u2f(d2.x); fdv[9] = u2f(d2.y); fdv[10] = u2f(d2.z); fdv[11] = u2f(d2.w);
        const float4* pat = (const float4*)(attn + lane * 12);
        const float4 a0 = pat[0], a1 = pat[1], a2 = pat[2];
        atv[0] = a0.x; atv[1] = a0.y; atv[2] = a0.z; atv[3] = a0.w;
        atv[4] = a1.x; atv[5] = a1.y; atv[6] = a1.z; atv[7] = a1.w;
        atv[8] = a2.x; atv[9] = a2.y; atv[10] = a2.z; atv[11] = a2.w;
    }
    const int beg = rowp[n], end = rowp[n + 1];
    float m = -INFINITY, den = 0.f;
    float acc[12];
#pragma unroll
    for (int j = 0; j < 12; ++j) acc[j] = 0.f;

    for (int i = beg; i < end; ++i) {
        const int e = eid[i];
        const ushort4* pf = (const ushort4*)(fsd + (size_t)src[e] * NFUSE + fs_off + lane * 12);
        const ushort4 a0 = pf[0], a1 = pf[1], a2 = pf[2];
        float fsv[12];
        fsv[0] = u2f(a0.x); fsv[1] = u2f(a0.y); fsv[2] = u2f(a0.z); fsv[3] = u2f(a0.w);
        fsv[4] = u2f(a1.x); fsv[5] = u2f(a1.y); fsv[6] = u2f(a1.z); fsv[7] = u2f(a1.w);
        fsv[8] = u2f(a2.x); fsv[9] = u2f(a2.y); fsv[10] = u2f(a2.z); fsv[11] = u2f(a2.w);
        float p = 0.f;
#pragma unroll
        for (int j = 0; j < 12; ++j) {
            float x = fsv[j] + fdv[j];
            x = (x > 0.f) ? x : 0.2f * x;
            p += x * atv[j];
        }
        p += __shfl_xor(p, 1);
        p += __shfl_xor(p, 2);
        p += __shfl_xor(p, 4);
        if (p > m) {
            const float sc = expf(m - p);
            den *= sc;
#pragma unroll
            for (int j = 0; j < 12; ++j) acc[j] *= sc;
            m = p;
        }
        const float w = expf(p - m);
        den += w;
#pragma unroll
        for (int j = 0; j < 12; ++j) acc[j] += w * fsv[j];
    }
    const float inv = (den > 0.f) ? 1.f / den : 0.f;
#pragma unroll
    for (int j = 0; j < 12; ++j) out[j] = acc[j] * inv;
}

// ---------------- merged agg: h[n] = bf16(h + att_r0 + att_r1), wave per node ----------------
__global__ __launch_bounds__(256) void agg2_kernel(const bf16* __restrict__ fsd,
                                                   const float* __restrict__ attn0,
                                                   const float* __restrict__ attn1,
                                                   const int* __restrict__ rowp0,
                                                   const int* __restrict__ eid0,
                                                   const int* __restrict__ src0,
                                                   const int* __restrict__ rowp1,
                                                   const int* __restrict__ eid1,
                                                   const int* __restrict__ src1,
                                                   bf16* __restrict__ h) {
    const int wid = threadIdx.x >> 6;
    const int lane = threadIdx.x & 63;
    const int n = blockIdx.x * 4 + wid;
    if (n >= N_NODES) return;

    float a0[12], a1[12];
    att_accum(fsd, n, lane, attn0, rowp0, eid0, src0, 0, 768, a0);
    att_accum(fsd, n, lane, attn1, rowp1, eid1, src1, 1536, 2304, a1);

    const size_t base = (size_t)n * FDIM + lane * 12;
    const ushort4* ph = (const ushort4*)(h + base);
    const ushort4 h0 = ph[0], h1 = ph[1], h2 = ph[2];
    ushort4 r0, r1, r2;
    r0.x = f2u(u2f(h0.x) + a0[0] + a1[0]);  r0.y = f2u(u2f(h0.y) + a0[1] + a1[1]);
    r0.z = f2u(u2f(h0.z) + a0[2] + a1[2]);  r0.w = f2u(u2f(h0.w) + a0[3] + a1[3]);
    r1.x = f2u(u2f(h1.x) + a0[4] + a1[4]);  r1.y = f2u(u2f(h1.y) + a0[5] + a1[5]);
    r1.z = f2u(u2f(h1.z) + a0[6] + a1[6]);  r1.w = f2u(u2f(h1.w) + a0[7] + a1[7]);
    r2.x = f2u(u2f(h2.x) + a0[8] + a1[8]);  r2.y = f2u(u2f(h2.y) + a0[9] + a1[9]);
    r2.z = f2u(u2f(h2.z) + a0[10] + a1[10]); r2.w = f2u(u2f(h2.w) + a0[11] + a1[11]);
    ((ushort4*)(h + base))[0] = r0; ((ushort4*)(h + base))[1] = r1; ((ushort4*)(h + base))[2] = r2;
}

// ---------------- MLP head ----------------
__global__ __launch_bounds__(256) void head_kernel(const bf16* __restrict__ h,
                                                   const int* __restrict__ gsi,
                                                   const float* __restrict__ fc1w,
                                                   const float* __restrict__ fc1b,
                                                   const float* __restrict__ fc2w,
                                                   const float* __restrict__ fc2b,
                                                   float* __restrict__ out) {
    __shared__ float fe[FDIM];
    __shared__ float hid[256];
    const int b = blockIdx.x, t = threadIdx.x;
    const int node = gsi[b];
    for (int i = t; i < FDIM; i += 256) fe[i] = __bfloat162float(h[(size_t)node * FDIM + i]);
    __syncthreads();
    float acc = fc1b[t];
    for (int k = 0; k < FDIM; ++k) acc += fe[k] * fc1w[k * 256 + t];
    hid[t] = (acc > 0.f) ? acc : 0.f;
    __syncthreads();
    if (t < NC) {
        float acc2 = fc2b[t];
        for (int k = 0; k < 256; ++k) acc2 += hid[k] * fc2w[k * NC + t];
        out[1 + b * NC + t] = acc2;
    }
}

// ---------------- loss ----------------
__global__ __launch_bounds__(256) void loss_kernel(const float* __restrict__ logits,
                                                   const int* __restrict__ labels,
                                                   float* __restrict__ out) {
    __shared__ float red[256];
    const int b = threadIdx.x;
    float m = -INFINITY;
    for (int c = 0; c < NC; ++c) m = fmaxf(m, logits[b * NC + c]);
    float sum = 0.f;
    for (int c = 0; c < NC; ++c) sum += expf(logits[b * NC + c] - m);
    const float lse = m + logf(sum);
    const float ll = logits[b * NC + labels[b]];
    red[b] = lse - ll;
    __syncthreads();
    for (int s = 128; s > 0; s >>= 1) {
        if (b < s) red[b] += red[b + s];
        __syncthreads();
    }
    if (b == 0) out[0] = red[0] / (float)NB;
}

extern "C" void kernel_launch(void* const* d_in, const int* in_sizes, int n_in,
                              void* d_out, int out_size, void* d_ws, size_t ws_size,
                              hipStream_t stream) {
    const float* feats = (const float*)d_in[0];
    const float* fc1w  = (const float*)d_in[11];
    const float* fc1b  = (const float*)d_in[12];
    const float* fc2w  = (const float*)d_in[13];
    const float* fc2b  = (const float*)d_in[14];
    const int* gsi     = (const int*)d_in[19];
    const int* labels  = (const int*)d_in[20];

    const size_t NF = (size_t)N_NODES * FDIM;
    const size_t WSZ = (size_t)FDIM * FDIM;
    char* p = (char*)d_ws;
    bf16* h    = (bf16*)p;  p += NF * 2;
    bf16* fsd  = (bf16*)p;  p += (size_t)N_NODES * NFUSE * 2;
    bf16* WtFl = (bf16*)p;  p += 4 * WSZ * 2;   // one layer's 4 matrices [3072][768]
    float* pb  = (float*)p; p += 2 * NFUSE * 4; // packed bias, both layers
    int* deg[2];  int* rowp[2];  int* cursor[2];  int* eid[2];
    for (int r = 0; r < 2; ++r) {
        deg[r]    = (int*)p; p += (size_t)N_NODES * 4 + 256;
        rowp[r]   = (int*)p; p += ((size_t)N_NODES + 1) * 4 + 256;
        cursor[r] = (int*)p; p += (size_t)N_NODES * 4 + 256;
        eid[r]    = (int*)p; p += (size_t)NE * 4 + 256;
    }

    cvt_kernel<<<2048, 256, 0, stream>>>(feats, h);
    bias_pack_kernel<<<(2 * NFUSE + 255) / 256, 256, 0, stream>>>(
        (const float*)d_in[2], (const float*)d_in[4], (const float*)d_in[7], (const float*)d_in[9], pb);

    // Build CSR per relation (dst is layer-invariant).
    for (int r = 0; r < 2; ++r) {
        const int* dst = (const int*)d_in[r == 0 ? 16 : 18];
        hipMemsetAsync(deg[r], 0, sizeof(int) * N_NODES, stream);
        hist_kernel<<<(NE + 255) / 256, 256, 0, stream>>>(dst, deg[r]);
        scan_kernel<<<1, 256, 0, stream>>>(deg[r], rowp[r], cursor[r]);
        scatter_kernel<<<(NE + 255) / 256, 256, 0, stream>>>(dst, cursor[r], eid[r]);
    }

    const int node_blocks = (N_NODES + 3) / 4;
    dim3 tgrid(FDIM / 32, FDIM / 32, 4);

    for (int l = 0; l < 2; ++l) {
        twt4_kernel<<<tgrid, 256, 0, stream>>>(
            (const float*)d_in[1], (const float*)d_in[3],
            (const float*)d_in[6], (const float*)d_in[8], WtFl, l);
        gemm_fused<<<NWG, 512, 0, stream>>>(h, WtFl, pb + (size_t)l * NFUSE, fsd, N_NODES);
        agg2_kernel<<<node_blocks, 256, 0, stream>>>(
            fsd, (const float*)d_in[5] + (size_t)l * FDIM, (const float*)d_in[10] + (size_t)l * FDIM,
            rowp[0], eid[0], (const int*)d_in[15],
            rowp[1], eid[1], (const int*)d_in[17], h);
    }

    head_kernel<<<NB, 256, 0, stream>>>(h, gsi, fc1w, fc1b, fc2w, fc2b, (float*)d_out);
    loss_kernel<<<1, 256, 0, stream>>>((float*)d_out + 1, labels, (float*)d_out);
}

// Round 8
// 1301.982 us; speedup vs baseline: 14.4536x; 1.0131x over previous
//
#include <hip/hip_runtime.h>
#include <hip/hip_bf16.h>
#include <math.h>

#define N_NODES 50000
#define NE      100000
#define NH      8
#define FDIM    768
#define NFUSE   3072
#define NB      256
#define NC      31

typedef __hip_bfloat16 bf16;
typedef __attribute__((ext_vector_type(8))) short bf16x8;
typedef __attribute__((ext_vector_type(4))) float f32x4;

__device__ inline float u2f(unsigned short u) { return __uint_as_float(((unsigned int)u) << 16); }
__device__ inline unsigned short f2u(float f) { return __bfloat16_as_ushort(__float2bfloat16(f)); }

__device__ inline void load_lds16(const void* g, void* l) {
    __builtin_amdgcn_global_load_lds(
        (const __attribute__((address_space(1))) void*)g,
        (__attribute__((address_space(3))) void*)l, 16, 0, 0);
}

// ---------------- convert f32 -> bf16 ----------------
__global__ __launch_bounds__(256) void cvt_kernel(const float* __restrict__ in,
                                                  bf16* __restrict__ out) {
    const size_t total = (size_t)N_NODES * FDIM;
    const size_t stride = (size_t)gridDim.x * blockDim.x;
    for (size_t i = blockIdx.x * (size_t)blockDim.x + threadIdx.x; i < total; i += stride)
        out[i] = __float2bfloat16(in[i]);
}

// ---------------- weight transpose+convert, 4 matrices of one layer ----------------
__global__ __launch_bounds__(256) void twt4_kernel(const float* __restrict__ w_sc,
                                                   const float* __restrict__ w_dc,
                                                   const float* __restrict__ w_scb,
                                                   const float* __restrict__ w_dcb,
                                                   bf16* __restrict__ WtFl, int l) {
    const int z = blockIdx.z;
    const float* src;
    if (z == 0) src = w_sc; else if (z == 1) src = w_dc; else if (z == 2) src = w_scb; else src = w_dcb;
    src += (size_t)l * FDIM * FDIM;
    bf16* dst = WtFl + (size_t)z * FDIM * FDIM;

    __shared__ float tile[32][33];
    const int tx = threadIdx.x & 31, ty = threadIdx.x >> 5;
    const int x0 = blockIdx.x * 32, y0 = blockIdx.y * 32;
#pragma unroll
    for (int q = 0; q < 4; ++q)
        tile[ty + q * 8][tx] = src[(size_t)(y0 + ty + q * 8) * FDIM + x0 + tx];
    __syncthreads();
#pragma unroll
    for (int q = 0; q < 4; ++q)
        dst[(size_t)(x0 + ty + q * 8) * FDIM + y0 + tx] = __float2bfloat16(tile[tx][ty + q * 8]);
}

// ---------------- bias pack: pb[l][3072] ----------------
__global__ __launch_bounds__(256) void bias_pack_kernel(const float* __restrict__ b_sc,
                                                        const float* __restrict__ b_dc,
                                                        const float* __restrict__ b_scb,
                                                        const float* __restrict__ b_dcb,
                                                        float* __restrict__ pb) {
    const int idx = blockIdx.x * 256 + threadIdx.x;
    if (idx >= 2 * NFUSE) return;
    const int l = idx / NFUSE, c = idx % NFUSE;
    const int sel = c / FDIM, off = c % FDIM;
    const float* src;
    if (sel == 0) src = b_sc; else if (sel == 1) src = b_dc; else if (sel == 2) src = b_scb; else src = b_dcb;
    pb[idx] = src[l * FDIM + off];
}

// ---------------- 8-phase MFMA GEMM: C[M,3072] = A[M,768] @ WtFl^T + pb ----------------
// Same compute/schedule as round 7; ONLY the block->tile mapping changed:
// L2-cluster order (ng, mt, nn): n-groups of 4 tiles, XCD-contiguous ranges.
// Resident set per XCD ~ 8 m-tiles x 4 n-tiles = A 3.1 MB + B 1.5 MB < 4 MB L2.
#define GBM 256
#define GBN 256
#define NKT 12                               // 768/64
#define TILES_M ((N_NODES + GBM - 1) / GBM)  // 196
#define TILES_N (NFUSE / GBN)                // 12
#define NWG (TILES_M * TILES_N)              // 2352 = 8*294

__global__ __launch_bounds__(512, 1) void gemm_fused(const bf16* __restrict__ A,
                                                     const bf16* __restrict__ Wt,
                                                     const float* __restrict__ pb,
                                                     bf16* __restrict__ C, int M) {
    __shared__ __align__(16) short lds[2][2][2][8192];
    const int t = threadIdx.x;
    const int wid = t >> 6, lane = t & 63;
    const int wr = wid >> 2, wc = wid & 3;       // 2M x 4N waves, per-wave 128x64 output
    const int lr = lane & 15, lk = lane >> 4;

    // L2-cluster swizzle: gidx = xcd-contiguous; decode (ng, mt, nn), n-group of 4.
    const int orig = blockIdx.x;
    const int gidx = (orig & 7) * (NWG / 8) + (orig >> 3);
    const int ng  = gidx / (TILES_M * 4);    // 0..2
    const int rem = gidx % (TILES_M * 4);
    const int tm  = rem >> 2;
    const int tn  = ng * 4 + (rem & 3);
    const int m0 = tm * GBM, n0 = tn * GBN;

    const f32x4 zero4 = {0.f, 0.f, 0.f, 0.f};
    f32x4 acc[8][4];
#pragma unroll
    for (int i = 0; i < 8; ++i)
#pragma unroll
        for (int j = 0; j < 4; ++j) acc[i][j] = zero4;

    const int scol_sw = (((lane & 3) ^ ((lane >> 3) & 3)) << 3);  // elements
    int arow[2], brow[2], dstq[2];
#pragma unroll
    for (int q = 0; q < 2; ++q) {
        const int r = wid * 32 + q * 16 + (lane >> 2);
        int ra = m0 + r; if (ra >= M) ra = M - 1;
        arow[q] = ra;
        brow[q] = n0 + r;
        dstq[q] = wid * 2048 + q * 1024;
    }
    const int rsw = ((lk ^ ((lr >> 1) & 3)) << 3);
    const int abase = wr * 128 + lr;
    const int bbase = wc * 64 + lr;

#define STG_A(d, kh, kt) {                                                                  \
        load_lds16(A + (size_t)arow[0] * FDIM + (kt) * 64 + (kh) * 32 + scol_sw,            \
                   (char*)&lds[d][0][kh][0] + dstq[0]);                                     \
        load_lds16(A + (size_t)arow[1] * FDIM + (kt) * 64 + (kh) * 32 + scol_sw,            \
                   (char*)&lds[d][0][kh][0] + dstq[1]); }
#define STG_B(d, kh, kt) {                                                                  \
        load_lds16(Wt + (size_t)brow[0] * FDIM + (kt) * 64 + (kh) * 32 + scol_sw,           \
                   (char*)&lds[d][1][kh][0] + dstq[0]);                                     \
        load_lds16(Wt + (size_t)brow[1] * FDIM + (kt) * 64 + (kh) * 32 + scol_sw,           \
                   (char*)&lds[d][1][kh][0] + dstq[1]); }

    STG_A(0, 0, 0); STG_B(0, 0, 0); STG_A(0, 1, 0); STG_B(0, 1, 0);
    asm volatile("s_waitcnt vmcnt(4)");
    __builtin_amdgcn_s_barrier();
    __builtin_amdgcn_sched_barrier(0);

    int db = 0;
    for (int j = 0; j < NKT; ++j) {
        const int nd = db ^ 1;
        const bool st = (j + 1) < NKT;
        const short* Ak0 = &lds[db][0][0][0];
        const short* Bk0 = &lds[db][1][0][0];
        const short* Ak1 = &lds[db][0][1][0];
        const short* Bk1 = &lds[db][1][1][0];
        bf16x8 av[4], bv[4], av2[4];

        // ---- P1: (kh0, i0-3); stage A-kh0(j+1) ----
#pragma unroll
        for (int i = 0; i < 4; ++i) av[i] = *(const bf16x8*)&Ak0[(abase + i * 16) * 32 + rsw];
#pragma unroll
        for (int jj = 0; jj < 4; ++jj) bv[jj] = *(const bf16x8*)&Bk0[(bbase + jj * 16) * 32 + rsw];
        if (st) STG_A(nd, 0, j + 1);
        __builtin_amdgcn_s_barrier();
        asm volatile("s_waitcnt lgkmcnt(0)");
        __builtin_amdgcn_sched_barrier(0);
        __builtin_amdgcn_s_setprio(1);
#pragma unroll
        for (int i = 0; i < 4; ++i)
#pragma unroll
            for (int jj = 0; jj < 4; ++jj)
                acc[i][jj] = __builtin_amdgcn_mfma_f32_16x16x32_bf16(bv[jj], av[i], acc[i][jj], 0, 0, 0);
        __builtin_amdgcn_s_setprio(0);
        __builtin_amdgcn_s_barrier();
        __builtin_amdgcn_sched_barrier(0);

        // ---- P2: (kh0, i4-7); stage B-kh0(j+1); vmcnt(4) ----
#pragma unroll
        for (int i = 0; i < 4; ++i) av2[i] = *(const bf16x8*)&Ak0[(abase + (4 + i) * 16) * 32 + rsw];
        if (st) STG_B(nd, 0, j + 1);
        __builtin_amdgcn_s_barrier();
        asm volatile("s_waitcnt lgkmcnt(0)");
        __builtin_amdgcn_sched_barrier(0);
        __builtin_amdgcn_s_setprio(1);
#pragma unroll
        for (int i = 0; i < 4; ++i)
#pragma unroll
            for (int jj = 0; jj < 4; ++jj)
                acc[4 + i][jj] = __builtin_amdgcn_mfma_f32_16x16x32_bf16(bv[jj], av2[i], acc[4 + i][jj], 0, 0, 0);
        __builtin_amdgcn_s_setprio(0);
        if (st) { asm volatile("s_waitcnt vmcnt(4)"); }
        else    { asm volatile("s_waitcnt vmcnt(0)"); }
        __builtin_amdgcn_s_barrier();
        __builtin_amdgcn_sched_barrier(0);

        // ---- P3: (kh1, i0-3); stage A-kh1(j+1) ----
#pragma unroll
        for (int i = 0; i < 4; ++i) av[i] = *(const bf16x8*)&Ak1[(abase + i * 16) * 32 + rsw];
#pragma unroll
        for (int jj = 0; jj < 4; ++jj) bv[jj] = *(const bf16x8*)&Bk1[(bbase + jj * 16) * 32 + rsw];
        if (st) STG_A(nd, 1, j + 1);
        __builtin_amdgcn_s_barrier();
        asm volatile("s_waitcnt lgkmcnt(0)");
        __builtin_amdgcn_sched_barrier(0);
        __builtin_amdgcn_s_setprio(1);
#pragma unroll
        for (int i = 0; i < 4; ++i)
#pragma unroll
            for (int jj = 0; jj < 4; ++jj)
                acc[i][jj] = __builtin_amdgcn_mfma_f32_16x16x32_bf16(bv[jj], av[i], acc[i][jj], 0, 0, 0);
        __builtin_amdgcn_s_setprio(0);
        __builtin_amdgcn_s_barrier();
        __builtin_amdgcn_sched_barrier(0);

        // ---- P4: (kh1, i4-7); stage B-kh1(j+1); vmcnt(4) ----
#pragma unroll
        for (int i = 0; i < 4; ++i) av2[i] = *(const bf16x8*)&Ak1[(abase + (4 + i) * 16) * 32 + rsw];
        if (st) STG_B(nd, 1, j + 1);
        __builtin_amdgcn_s_barrier();
        asm volatile("s_waitcnt lgkmcnt(0)");
        __builtin_amdgcn_sched_barrier(0);
        __builtin_amdgcn_s_setprio(1);
#pragma unroll
        for (int i = 0; i < 4; ++i)
#pragma unroll
            for (int jj = 0; jj < 4; ++jj)
                acc[4 + i][jj] = __builtin_amdgcn_mfma_f32_16x16x32_bf16(bv[jj], av2[i], acc[4 + i][jj], 0, 0, 0);
        __builtin_amdgcn_s_setprio(0);
        if (st) { asm volatile("s_waitcnt vmcnt(4)"); }
        __builtin_amdgcn_s_barrier();
        __builtin_amdgcn_sched_barrier(0);

        db = nd;
    }
#undef STG_A
#undef STG_B

    // Epilogue (swapped-operand D): row = m0+wr*128+i*16+lr; col = n0+wc*64+jj*16+lk*4.
#pragma unroll
    for (int i = 0; i < 8; ++i) {
        const int row = m0 + wr * 128 + i * 16 + lr;
        if (row < M) {
#pragma unroll
            for (int jj = 0; jj < 4; ++jj) {
                const int col = n0 + wc * 64 + jj * 16 + lk * 4;
                const float4 b4 = *(const float4*)(pb + col);
                ushort4 w;
                w.x = f2u(acc[i][jj][0] + b4.x);
                w.y = f2u(acc[i][jj][1] + b4.y);
                w.z = f2u(acc[i][jj][2] + b4.z);
                w.w = f2u(acc[i][jj][3] + b4.w);
                *(ushort4*)(C + (size_t)row * NFUSE + col) = w;
            }
        }
    }
}

// ---------------- CSR build ----------------
__global__ __launch_bounds__(256) void hist_kernel(const int* __restrict__ dst, int* __restrict__ deg) {
    const int e = blockIdx.x * 256 + threadIdx.x;
    if (e < NE) atomicAdd(&deg[dst[e]], 1);
}

__global__ __launch_bounds__(256) void scan_kernel(const int* __restrict__ deg,
                                                   int* __restrict__ rowp,
                                                   int* __restrict__ cursor) {
    __shared__ int pref[257];
    const int t = threadIdx.x;
    const int CH = (N_NODES + 255) / 256;
    const int b0 = t * CH;
    const int b1 = (b0 + CH < N_NODES) ? b0 + CH : N_NODES;
    int s = 0;
    for (int i = b0; i < b1; ++i) s += deg[i];
    __shared__ int part[256];
    part[t] = s;
    __syncthreads();
    if (t == 0) {
        int acc = 0;
        for (int i = 0; i < 256; ++i) { pref[i] = acc; acc += part[i]; }
        pref[256] = acc;
    }
    __syncthreads();
    int run = pref[t];
    for (int i = b0; i < b1; ++i) { rowp[i] = run; cursor[i] = run; run += deg[i]; }
    if (t == 255) rowp[N_NODES] = run;
}

__global__ __launch_bounds__(256) void scatter_kernel(const int* __restrict__ dst,
                                                      int* __restrict__ cursor,
                                                      int* __restrict__ eid) {
    const int e = blockIdx.x * 256 + threadIdx.x;
    if (e < NE) {
        const int p = atomicAdd(&cursor[dst[e]], 1);
        eid[p] = e;
    }
}

// ---------------- per-relation online-softmax attention accumulate ----------------
__device__ inline void att_accum(const bf16* __restrict__ fsd, int n, int lane,
                                 const float* __restrict__ attn,
                                 const int* __restrict__ rowp, const int* __restrict__ eid,
                                 const int* __restrict__ src, int fs_off, int fd_off,
                                 float* __restrict__ out) {
    float fdv[12], atv[12];
    {
        const ushort4* pfd = (const ushort4*)(fsd + (size_t)n * NFUSE + fd_off + lane * 12);
        const ushort4 d0 = pfd[0], d1 = pfd[1], d2 = pfd[2];
        fdv[0] = u2f(d0.x); fdv[1] = u2f(d0.y); fdv[2] = u2f(d0.z); fdv[3] = u2f(d0.w);
        fdv[4] = u2f(d1.x); fdv[5] = u2f(d1.y); fdv[6] = u2f(d1.z); fdv[7] = u2f(d1.w);
        fdv[8] = u2f(d2.x); fdv[9] = u2f(d2.y); fdv[10] = u2f(d2.z); fdv[11] = u2f(d2.w);
        const float4* pat = (const float4*)(attn + lane * 12);
        const float4 a0 = pat[0], a1 = pat[1], a2 = pat[2];
        atv[0] = a0.x; atv[1] = a0.y; atv[2] = a0.z; atv[3] = a0.w;
        atv[4] = a1.x; atv[5] = a1.y; atv[6] = a1.z; atv[7] = a1.w;
        atv[8] = a2.x; atv[9] = a2.y; atv[10] = a2.z; atv[11] = a2.w;
    }
    const int beg = rowp[n], end = rowp[n + 1];
    float m = -INFINITY, den = 0.f;
    float acc[12];
#pragma unroll
    for (int j = 0; j < 12; ++j) acc[j] = 0.f;

    for (int i = beg; i < end; ++i) {
        const int e = eid[i];
        const ushort4* pf = (const ushort4*)(fsd + (size_t)src[e] * NFUSE + fs_off + lane * 12);
        const ushort4 a0 = pf[0], a1 = pf[1], a2 = pf[2];
        float fsv[12];
        fsv[0] = u2f(a0.x); fsv[1] = u2f(a0.y); fsv[2] = u2f(a0.z); fsv[3] = u2f(a0.w);
        fsv[4] = u2f(a1.x); fsv[5] = u2f(a1.y); fsv[6] = u2f(a1.z); fsv[7] = u2f(a1.w);
        fsv[8] = u2f(a2.x); fsv[9] = u2f(a2.y); fsv[10] = u2f(a2.z); fsv[11] = u2f(a2.w);
        float p = 0.f;
#pragma unroll
        for (int j = 0; j < 12; ++j) {
            float x = fsv[j] + fdv[j];
            x = (x > 0.f) ? x : 0.2f * x;
            p += x * atv[j];
        }
        p += __shfl_xor(p, 1);
        p += __shfl_xor(p, 2);
        p += __shfl_xor(p, 4);
        if (p > m) {
            const float sc = expf(m - p);
            den *= sc;
#pragma unroll
            for (int j = 0; j < 12; ++j) acc[j] *= sc;
            m = p;
        }
        const float w = expf(p - m);
        den += w;
#pragma unroll
        for (int j = 0; j < 12; ++j) acc[j] += w * fsv[j];
    }
    const float inv = (den > 0.f) ? 1.f / den : 0.f;
#pragma unroll
    for (int j = 0; j < 12; ++j) out[j] = acc[j] * inv;
}

// ---------------- merged agg: h[n] = bf16(h + att_r0 + att_r1), wave per node ----------------
__global__ __launch_bounds__(256) void agg2_kernel(const bf16* __restrict__ fsd,
                                                   const float* __restrict__ attn0,
                                                   const float* __restrict__ attn1,
                                                   const int* __restrict__ rowp0,
                                                   const int* __restrict__ eid0,
                                                   const int* __restrict__ src0,
                                                   const int* __restrict__ rowp1,
                                                   const int* __restrict__ eid1,
                                                   const int* __restrict__ src1,
                                                   bf16* __restrict__ h) {
    const int wid = threadIdx.x >> 6;
    const int lane = threadIdx.x & 63;
    const int n = blockIdx.x * 4 + wid;
    if (n >= N_NODES) return;

    float a0[12], a1[12];
    att_accum(fsd, n, lane, attn0, rowp0, eid0, src0, 0, 768, a0);
    att_accum(fsd, n, lane, attn1, rowp1, eid1, src1, 1536, 2304, a1);

    const size_t base = (size_t)n * FDIM + lane * 12;
    const ushort4* ph = (const ushort4*)(h + base);
    const ushort4 h0 = ph[0], h1 = ph[1], h2 = ph[2];
    ushort4 r0, r1, r2;
    r0.x = f2u(u2f(h0.x) + a0[0] + a1[0]);  r0.y = f2u(u2f(h0.y) + a0[1] + a1[1]);
    r0.z = f2u(u2f(h0.z) + a0[2] + a1[2]);  r0.w = f2u(u2f(h0.w) + a0[3] + a1[3]);
    r1.x = f2u(u2f(h1.x) + a0[4] + a1[4]);  r1.y = f2u(u2f(h1.y) + a0[5] + a1[5]);
    r1.z = f2u(u2f(h1.z) + a0[6] + a1[6]);  r1.w = f2u(u2f(h1.w) + a0[7] + a1[7]);
    r2.x = f2u(u2f(h2.x) + a0[8] + a1[8]);  r2.y = f2u(u2f(h2.y) + a0[9] + a1[9]);
    r2.z = f2u(u2f(h2.z) + a0[10] + a1[10]); r2.w = f2u(u2f(h2.w) + a0[11] + a1[11]);
    ((ushort4*)(h + base))[0] = r0; ((ushort4*)(h + base))[1] = r1; ((ushort4*)(h + base))[2] = r2;
}

// ---------------- MLP head ----------------
__global__ __launch_bounds__(256) void head_kernel(const bf16* __restrict__ h,
                                                   const int* __restrict__ gsi,
                                                   const float* __restrict__ fc1w,
                                                   const float* __restrict__ fc1b,
                                                   const float* __restrict__ fc2w,
                                                   const float* __restrict__ fc2b,
                                                   float* __restrict__ out) {
    __shared__ float fe[FDIM];
    __shared__ float hid[256];
    const int b = blockIdx.x, t = threadIdx.x;
    const int node = gsi[b];
    for (int i = t; i < FDIM; i += 256) fe[i] = __bfloat162float(h[(size_t)node * FDIM + i]);
    __syncthreads();
    float acc = fc1b[t];
    for (int k = 0; k < FDIM; ++k) acc += fe[k] * fc1w[k * 256 + t];
    hid[t] = (acc > 0.f) ? acc : 0.f;
    __syncthreads();
    if (t < NC) {
        float acc2 = fc2b[t];
        for (int k = 0; k < 256; ++k) acc2 += hid[k] * fc2w[k * NC + t];
        out[1 + b * NC + t] = acc2;
    }
}

// ---------------- loss ----------------
__global__ __launch_bounds__(256) void loss_kernel(const float* __restrict__ logits,
                                                   const int* __restrict__ labels,
                                                   float* __restrict__ out) {
    __shared__ float red[256];
    const int b = threadIdx.x;
    float m = -INFINITY;
    for (int c = 0; c < NC; ++c) m = fmaxf(m, logits[b * NC + c]);
    float sum = 0.f;
    for (int c = 0; c < NC; ++c) sum += expf(logits[b * NC + c] - m);
    const float lse = m + logf(sum);
    const float ll = logits[b * NC + labels[b]];
    red[b] = lse - ll;
    __syncthreads();
    for (int s = 128; s > 0; s >>= 1) {
        if (b < s) red[b] += red[b + s];
        __syncthreads();
    }
    if (b == 0) out[0] = red[0] / (float)NB;
}

extern "C" void kernel_launch(void* const* d_in, const int* in_sizes, int n_in,
                              void* d_out, int out_size, void* d_ws, size_t ws_size,
                              hipStream_t stream) {
    const float* feats = (const float*)d_in[0];
    const float* fc1w  = (const float*)d_in[11];
    const float* fc1b  = (const float*)d_in[12];
    const float* fc2w  = (const float*)d_in[13];
    const float* fc2b  = (const float*)d_in[14];
    const int* gsi     = (const int*)d_in[19];
    const int* labels  = (const int*)d_in[20];

    const size_t NF = (size_t)N_NODES * FDIM;
    const size_t WSZ = (size_t)FDIM * FDIM;
    char* p = (char*)d_ws;
    bf16* h    = (bf16*)p;  p += NF * 2;
    bf16* fsd  = (bf16*)p;  p += (size_t)N_NODES * NFUSE * 2;
    bf16* WtFl = (bf16*)p;  p += 4 * WSZ * 2;   // one layer's 4 matrices [3072][768]
    float* pb  = (float*)p; p += 2 * NFUSE * 4; // packed bias, both layers
    int* deg[2];  int* rowp[2];  int* cursor[2];  int* eid[2];
    for (int r = 0; r < 2; ++r) {
        deg[r]    = (int*)p; p += (size_t)N_NODES * 4 + 256;
        rowp[r]   = (int*)p; p += ((size_t)N_NODES + 1) * 4 + 256;
        cursor[r] = (int*)p; p += (size_t)N_NODES * 4 + 256;
        eid[r]    = (int*)p; p += (size_t)NE * 4 + 256;
    }

    cvt_kernel<<<2048, 256, 0, stream>>>(feats, h);
    bias_pack_kernel<<<(2 * NFUSE + 255) / 256, 256, 0, stream>>>(
        (const float*)d_in[2], (const float*)d_in[4], (const float*)d_in[7], (const float*)d_in[9], pb);

    // Build CSR per relation (dst is layer-invariant).
    for (int r = 0; r < 2; ++r) {
        const int* dst = (const int*)d_in[r == 0 ? 16 : 18];
        hipMemsetAsync(deg[r], 0, sizeof(int) * N_NODES, stream);
        hist_kernel<<<(NE + 255) / 256, 256, 0, stream>>>(dst, deg[r]);
        scan_kernel<<<1, 256, 0, stream>>>(deg[r], rowp[r], cursor[r]);
        scatter_kernel<<<(NE + 255) / 256, 256, 0, stream>>>(dst, cursor[r], eid[r]);
    }

    const int node_blocks = (N_NODES + 3) / 4;
    dim3 tgrid(FDIM / 32, FDIM / 32, 4);

    for (int l = 0; l < 2; ++l) {
        twt4_kernel<<<tgrid, 256, 0, stream>>>(
            (const float*)d_in[1], (const float*)d_in[3],
            (const float*)d_in[6], (const float*)d_in[8], WtFl, l);
        gemm_fused<<<NWG, 512, 0, stream>>>(h, WtFl, pb + (size_t)l * NFUSE, fsd, N_NODES);
        agg2_kernel<<<node_blocks, 256, 0, stream>>>(
            fsd, (const float*)d_in[5] + (size_t)l * FDIM, (const float*)d_in[10] + (size_t)l * FDIM,
            rowp[0], eid[0], (const int*)d_in[15],
            rowp[1], eid[1], (const int*)d_in[17], h);
    }

    head_kernel<<<NB, 256, 0, stream>>>(h, gsi, fc1w, fc1b, fc2w, fc2b, (float*)d_out);
    loss_kernel<<<1, 256, 0, stream>>>((float*)d_out + 1, labels, (float*)d_out);
}

// Round 9
// 467.956 us; speedup vs baseline: 40.2139x; 2.7823x over previous
//
#include <hip/hip_runtime.h>
#include <hip/hip_bf16.h>
#include <math.h>

#define N_NODES 50000
#define NE      100000
#define NH      8
#define FDIM    768
#define NFUSE   3072
#define NB      256
#define NC      31

#define A1_CAP  16384   // nodes needing fsd in layer 0 (expect ~6.4k)
#define N1_CAP  4096    // nodes needing h1 / fsd in layer 1 (expect ~1.3k)
#define TILES_N 12      // 3072/256

typedef __hip_bfloat16 bf16;
typedef __attribute__((ext_vector_type(8))) short bf16x8;
typedef __attribute__((ext_vector_type(4))) float f32x4;

__device__ inline float u2f(unsigned short u) { return __uint_as_float(((unsigned int)u) << 16); }
__device__ inline unsigned short f2u(float f) { return __bfloat16_as_ushort(__float2bfloat16(f)); }

__device__ inline void load_lds16(const void* g, void* l) {
    __builtin_amdgcn_global_load_lds(
        (const __attribute__((address_space(1))) void*)g,
        (__attribute__((address_space(3))) void*)l, 16, 0, 0);
}

// ---------------- receptive-field construction ----------------
__global__ __launch_bounds__(256) void mark_gsi_kernel(const int* __restrict__ gsi,
                                                       int* __restrict__ fL2,
                                                       int* __restrict__ fL1,
                                                       int* __restrict__ fA1) {
    const int n = gsi[threadIdx.x];
    fL2[n] = 1; fL1[n] = 1; fA1[n] = 1;
}

// if dflag[dst[e]]: mark src[e] in f1 (and f2 if given)
__global__ __launch_bounds__(256) void mark_src_kernel(const int* __restrict__ src,
                                                       const int* __restrict__ dst,
                                                       const int* __restrict__ dflag,
                                                       int* __restrict__ f1,
                                                       int* __restrict__ f2) {
    const int e = blockIdx.x * 256 + threadIdx.x;
    if (e >= NE) return;
    if (dflag[dst[e]]) {
        const int s = src[e];
        f1[s] = 1;
        if (f2) f2[s] = 1;
    }
}

__global__ __launch_bounds__(256) void compact_kernel(const int* __restrict__ fA1,
                                                      const int* __restrict__ fL1,
                                                      const int* __restrict__ fL2,
                                                      int* __restrict__ list1, int* __restrict__ idx1,
                                                      int* __restrict__ list2, int* __restrict__ idx2,
                                                      int* __restrict__ list0,
                                                      int* __restrict__ cnts) {
    const int n = blockIdx.x * 256 + threadIdx.x;
    if (n >= N_NODES) return;
    if (fA1[n]) {
        const int p = atomicAdd(&cnts[0], 1);
        if (p < A1_CAP) { list1[p] = n; idx1[n] = p; } else idx1[n] = 0;
    }
    if (fL1[n]) {
        const int p = atomicAdd(&cnts[1], 1);
        if (p < N1_CAP) { list2[p] = n; idx2[n] = p; } else idx2[n] = 0;
    }
    if (fL2[n]) {
        const int p = atomicAdd(&cnts[2], 1);
        if (p < 256) list0[p] = n;
    }
}

// ---------------- gathered convert f32 -> bf16 (active rows only) ----------------
__global__ __launch_bounds__(256) void cvt_gather_kernel(const float* __restrict__ feats,
                                                         const int* __restrict__ list,
                                                         const int* __restrict__ pcnt,
                                                         bf16* __restrict__ h) {
    int c = *pcnt; if (c > A1_CAP) c = A1_CAP;
    for (int b = blockIdx.x; b < c; b += gridDim.x) {
        const int n = list[b];
        const float* s = feats + (size_t)n * FDIM;
        bf16* d = h + (size_t)n * FDIM;
        for (int i = threadIdx.x; i < FDIM; i += 256) d[i] = __float2bfloat16(s[i]);
    }
}

// ---------------- weight transpose+convert, 4 matrices of one layer ----------------
__global__ __launch_bounds__(256) void twt4_kernel(const float* __restrict__ w_sc,
                                                   const float* __restrict__ w_dc,
                                                   const float* __restrict__ w_scb,
                                                   const float* __restrict__ w_dcb,
                                                   bf16* __restrict__ WtFl, int l) {
    const int z = blockIdx.z;
    const float* src;
    if (z == 0) src = w_sc; else if (z == 1) src = w_dc; else if (z == 2) src = w_scb; else src = w_dcb;
    src += (size_t)l * FDIM * FDIM;
    bf16* dst = WtFl + (size_t)z * FDIM * FDIM;

    __shared__ float tile[32][33];
    const int tx = threadIdx.x & 31, ty = threadIdx.x >> 5;
    const int x0 = blockIdx.x * 32, y0 = blockIdx.y * 32;
#pragma unroll
    for (int q = 0; q < 4; ++q)
        tile[ty + q * 8][tx] = src[(size_t)(y0 + ty + q * 8) * FDIM + x0 + tx];
    __syncthreads();
#pragma unroll
    for (int q = 0; q < 4; ++q)
        dst[(size_t)(x0 + ty + q * 8) * FDIM + y0 + tx] = __float2bfloat16(tile[tx][ty + q * 8]);
}

// ---------------- bias pack: pb[l][3072] ----------------
__global__ __launch_bounds__(256) void bias_pack_kernel(const float* __restrict__ b_sc,
                                                        const float* __restrict__ b_dc,
                                                        const float* __restrict__ b_scb,
                                                        const float* __restrict__ b_dcb,
                                                        float* __restrict__ pb) {
    const int idx = blockIdx.x * 256 + threadIdx.x;
    if (idx >= 2 * NFUSE) return;
    const int l = idx / NFUSE, c = idx % NFUSE;
    const int sel = c / FDIM, off = c % FDIM;
    const float* src;
    if (sel == 0) src = b_sc; else if (sel == 1) src = b_dc; else if (sel == 2) src = b_scb; else src = b_dcb;
    pb[idx] = src[l * FDIM + off];
}

// ---------------- pipelined MFMA GEMM over compacted row list ----------------
// C[m,3072] = A[rowlist[m],768] @ WtFl^T + pb  for m < *pcnt (C rows compact).
// 256x256 tile, 8 waves, BK=64 as 2 kh-slabs, double-buffered LDS, counted vmcnt.
#define GBM 256
#define GBN 256
#define NKT 12  // 768/64

__global__ __launch_bounds__(512, 1) void gemm_fused(const bf16* __restrict__ A,
                                                     const bf16* __restrict__ Wt,
                                                     const float* __restrict__ pb,
                                                     bf16* __restrict__ C,
                                                     const int* __restrict__ rowlist,
                                                     const int* __restrict__ pcnt,
                                                     int mcap) {
    int cnt = *pcnt; if (cnt > mcap) cnt = mcap;
    const int bid = blockIdx.x;
    const int tm = bid / TILES_N, tn = bid % TILES_N;
    const int m0 = tm * GBM, n0 = tn * GBN;
    if (m0 >= cnt) return;

    __shared__ __align__(16) short lds[2][2][2][8192];
    const int t = threadIdx.x;
    const int wid = t >> 6, lane = t & 63;
    const int wr = wid >> 2, wc = wid & 3;
    const int lr = lane & 15, lk = lane >> 4;

    const f32x4 zero4 = {0.f, 0.f, 0.f, 0.f};
    f32x4 acc[8][4];
#pragma unroll
    for (int i = 0; i < 8; ++i)
#pragma unroll
        for (int j = 0; j < 4; ++j) acc[i][j] = zero4;

    const int scol_sw = (((lane & 3) ^ ((lane >> 3) & 3)) << 3);
    int arow[2], brow[2], dstq[2];
#pragma unroll
    for (int q = 0; q < 2; ++q) {
        int rr = m0 + wid * 32 + q * 16 + (lane >> 2);
        if (rr >= cnt) rr = cnt - 1;
        arow[q] = rowlist[rr];
        brow[q] = n0 + wid * 32 + q * 16 + (lane >> 2);
        dstq[q] = wid * 2048 + q * 1024;
    }
    const int rsw = ((lk ^ ((lr >> 1) & 3)) << 3);
    const int abase = wr * 128 + lr;
    const int bbase = wc * 64 + lr;

#define STG_A(d, kh, kt) {                                                                  \
        load_lds16(A + (size_t)arow[0] * FDIM + (kt) * 64 + (kh) * 32 + scol_sw,            \
                   (char*)&lds[d][0][kh][0] + dstq[0]);                                     \
        load_lds16(A + (size_t)arow[1] * FDIM + (kt) * 64 + (kh) * 32 + scol_sw,            \
                   (char*)&lds[d][0][kh][0] + dstq[1]); }
#define STG_B(d, kh, kt) {                                                                  \
        load_lds16(Wt + (size_t)brow[0] * FDIM + (kt) * 64 + (kh) * 32 + scol_sw,           \
                   (char*)&lds[d][1][kh][0] + dstq[0]);                                     \
        load_lds16(Wt + (size_t)brow[1] * FDIM + (kt) * 64 + (kh) * 32 + scol_sw,           \
                   (char*)&lds[d][1][kh][0] + dstq[1]); }

    STG_A(0, 0, 0); STG_B(0, 0, 0); STG_A(0, 1, 0); STG_B(0, 1, 0);
    asm volatile("s_waitcnt vmcnt(4)");
    __builtin_amdgcn_s_barrier();
    __builtin_amdgcn_sched_barrier(0);

    int db = 0;
    for (int j = 0; j < NKT; ++j) {
        const int nd = db ^ 1;
        const bool st = (j + 1) < NKT;
        const short* Ak0 = &lds[db][0][0][0];
        const short* Bk0 = &lds[db][1][0][0];
        const short* Ak1 = &lds[db][0][1][0];
        const short* Bk1 = &lds[db][1][1][0];
        bf16x8 av[4], bv[4], av2[4];

        // P1: (kh0, i0-3); stage A-kh0(j+1)
#pragma unroll
        for (int i = 0; i < 4; ++i) av[i] = *(const bf16x8*)&Ak0[(abase + i * 16) * 32 + rsw];
#pragma unroll
        for (int jj = 0; jj < 4; ++jj) bv[jj] = *(const bf16x8*)&Bk0[(bbase + jj * 16) * 32 + rsw];
        if (st) STG_A(nd, 0, j + 1);
        __builtin_amdgcn_s_barrier();
        asm volatile("s_waitcnt lgkmcnt(0)");
        __builtin_amdgcn_sched_barrier(0);
        __builtin_amdgcn_s_setprio(1);
#pragma unroll
        for (int i = 0; i < 4; ++i)
#pragma unroll
            for (int jj = 0; jj < 4; ++jj)
                acc[i][jj] = __builtin_amdgcn_mfma_f32_16x16x32_bf16(bv[jj], av[i], acc[i][jj], 0, 0, 0);
        __builtin_amdgcn_s_setprio(0);
        __builtin_amdgcn_s_barrier();
        __builtin_amdgcn_sched_barrier(0);

        // P2: (kh0, i4-7); stage B-kh0(j+1); vmcnt(4)
#pragma unroll
        for (int i = 0; i < 4; ++i) av2[i] = *(const bf16x8*)&Ak0[(abase + (4 + i) * 16) * 32 + rsw];
        if (st) STG_B(nd, 0, j + 1);
        __builtin_amdgcn_s_barrier();
        asm volatile("s_waitcnt lgkmcnt(0)");
        __builtin_amdgcn_sched_barrier(0);
        __builtin_amdgcn_s_setprio(1);
#pragma unroll
        for (int i = 0; i < 4; ++i)
#pragma unroll
            for (int jj = 0; jj < 4; ++jj)
                acc[4 + i][jj] = __builtin_amdgcn_mfma_f32_16x16x32_bf16(bv[jj], av2[i], acc[4 + i][jj], 0, 0, 0);
        __builtin_amdgcn_s_setprio(0);
        if (st) { asm volatile("s_waitcnt vmcnt(4)"); }
        else    { asm volatile("s_waitcnt vmcnt(0)"); }
        __builtin_amdgcn_s_barrier();
        __builtin_amdgcn_sched_barrier(0);

        // P3: (kh1, i0-3); stage A-kh1(j+1)
#pragma unroll
        for (int i = 0; i < 4; ++i) av[i] = *(const bf16x8*)&Ak1[(abase + i * 16) * 32 + rsw];
#pragma unroll
        for (int jj = 0; jj < 4; ++jj) bv[jj] = *(const bf16x8*)&Bk1[(bbase + jj * 16) * 32 + rsw];
        if (st) STG_A(nd, 1, j + 1);
        __builtin_amdgcn_s_barrier();
        asm volatile("s_waitcnt lgkmcnt(0)");
        __builtin_amdgcn_sched_barrier(0);
        __builtin_amdgcn_s_setprio(1);
#pragma unroll
        for (int i = 0; i < 4; ++i)
#pragma unroll
            for (int jj = 0; jj < 4; ++jj)
                acc[i][jj] = __builtin_amdgcn_mfma_f32_16x16x32_bf16(bv[jj], av[i], acc[i][jj], 0, 0, 0);
        __builtin_amdgcn_s_setprio(0);
        __builtin_amdgcn_s_barrier();
        __builtin_amdgcn_sched_barrier(0);

        // P4: (kh1, i4-7); stage B-kh1(j+1); vmcnt(4)
#pragma unroll
        for (int i = 0; i < 4; ++i) av2[i] = *(const bf16x8*)&Ak1[(abase + (4 + i) * 16) * 32 + rsw];
        if (st) STG_B(nd, 1, j + 1);
        __builtin_amdgcn_s_barrier();
        asm volatile("s_waitcnt lgkmcnt(0)");
        __builtin_amdgcn_sched_barrier(0);
        __builtin_amdgcn_s_setprio(1);
#pragma unroll
        for (int i = 0; i < 4; ++i)
#pragma unroll
            for (int jj = 0; jj < 4; ++jj)
                acc[4 + i][jj] = __builtin_amdgcn_mfma_f32_16x16x32_bf16(bv[jj], av2[i], acc[4 + i][jj], 0, 0, 0);
        __builtin_amdgcn_s_setprio(0);
        if (st) { asm volatile("s_waitcnt vmcnt(4)"); }
        __builtin_amdgcn_s_barrier();
        __builtin_amdgcn_sched_barrier(0);

        db = nd;
    }
#undef STG_A
#undef STG_B

    // Epilogue: compact C row = m; col = n0+wc*64+jj*16+lk*4.
#pragma unroll
    for (int i = 0; i < 8; ++i) {
        const int row = m0 + wr * 128 + i * 16 + lr;
        if (row < cnt) {
#pragma unroll
            for (int jj = 0; jj < 4; ++jj) {
                const int col = n0 + wc * 64 + jj * 16 + lk * 4;
                const float4 b4 = *(const float4*)(pb + col);
                ushort4 w;
                w.x = f2u(acc[i][jj][0] + b4.x);
                w.y = f2u(acc[i][jj][1] + b4.y);
                w.z = f2u(acc[i][jj][2] + b4.z);
                w.w = f2u(acc[i][jj][3] + b4.w);
                *(ushort4*)(C + (size_t)row * NFUSE + col) = w;
            }
        }
    }
}

// ---------------- CSR build (full graph, per relation) ----------------
__global__ __launch_bounds__(256) void hist_kernel(const int* __restrict__ dst, int* __restrict__ deg) {
    const int e = blockIdx.x * 256 + threadIdx.x;
    if (e < NE) atomicAdd(&deg[dst[e]], 1);
}

__global__ __launch_bounds__(256) void scan_kernel(const int* __restrict__ deg,
                                                   int* __restrict__ rowp,
                                                   int* __restrict__ cursor) {
    __shared__ int pref[257];
    const int t = threadIdx.x;
    const int CH = (N_NODES + 255) / 256;
    const int b0 = t * CH;
    const int b1 = (b0 + CH < N_NODES) ? b0 + CH : N_NODES;
    int s = 0;
    for (int i = b0; i < b1; ++i) s += deg[i];
    __shared__ int part[256];
    part[t] = s;
    __syncthreads();
    if (t == 0) {
        int acc = 0;
        for (int i = 0; i < 256; ++i) { pref[i] = acc; acc += part[i]; }
        pref[256] = acc;
    }
    __syncthreads();
    int run = pref[t];
    for (int i = b0; i < b1; ++i) { rowp[i] = run; cursor[i] = run; run += deg[i]; }
    if (t == 255) rowp[N_NODES] = run;
}

__global__ __launch_bounds__(256) void scatter_kernel(const int* __restrict__ dst,
                                                      int* __restrict__ cursor,
                                                      int* __restrict__ eid) {
    const int e = blockIdx.x * 256 + threadIdx.x;
    if (e < NE) {
        const int p = atomicAdd(&cursor[dst[e]], 1);
        eid[p] = e;
    }
}

// ---------------- per-relation online-softmax attention (compact fsd via idx) ----------------
__device__ inline void att_accum(const bf16* __restrict__ fsd, const int* __restrict__ idx,
                                 int n, int lane, const float* __restrict__ attn,
                                 const int* __restrict__ rowp, const int* __restrict__ eid,
                                 const int* __restrict__ src, int fs_off, int fd_off,
                                 float* __restrict__ out) {
    float fdv[12], atv[12];
    {
        const ushort4* pfd = (const ushort4*)(fsd + (size_t)idx[n] * NFUSE + fd_off + lane * 12);
        const ushort4 d0 = pfd[0], d1 = pfd[1], d2 = pfd[2];
        fdv[0] = u2f(d0.x); fdv[1] = u2f(d0.y); fdv[2] = u2f(d0.z); fdv[3] = u2f(d0.w);
        fdv[4] = u2f(d1.x); fdv[5] = u2f(d1.y); fdv[6] = u2f(d1.z); fdv[7] = u2f(d1.w);
        fdv[8] = u2f(d2.x); fdv[9] = u2f(d2.y); fdv[10] = u2f(d2.z); fdv[11] = u2f(d2.w);
        const float4* pat = (const float4*)(attn + lane * 12);
        const float4 a0 = pat[0], a1 = pat[1], a2 = pat[2];
        atv[0] = a0.x; atv[1] = a0.y; atv[2] = a0.z; atv[3] = a0.w;
        atv[4] = a1.x; atv[5] = a1.y; atv[6] = a1.z; atv[7] = a1.w;
        atv[8] = a2.x; atv[9] = a2.y; atv[10] = a2.z; atv[11] = a2.w;
    }
    const int beg = rowp[n], end = rowp[n + 1];
    float m = -INFINITY, den = 0.f;
    float acc[12];
#pragma unroll
    for (int j = 0; j < 12; ++j) acc[j] = 0.f;

    for (int i = beg; i < end; ++i) {
        const int e = eid[i];
        const ushort4* pf = (const ushort4*)(fsd + (size_t)idx[src[e]] * NFUSE + fs_off + lane * 12);
        const ushort4 a0 = pf[0], a1 = pf[1], a2 = pf[2];
        float fsv[12];
        fsv[0] = u2f(a0.x); fsv[1] = u2f(a0.y); fsv[2] = u2f(a0.z); fsv[3] = u2f(a0.w);
        fsv[4] = u2f(a1.x); fsv[5] = u2f(a1.y); fsv[6] = u2f(a1.z); fsv[7] = u2f(a1.w);
        fsv[8] = u2f(a2.x); fsv[9] = u2f(a2.y); fsv[10] = u2f(a2.z); fsv[11] = u2f(a2.w);
        float p = 0.f;
#pragma unroll
        for (int j = 0; j < 12; ++j) {
            float x = fsv[j] + fdv[j];
            x = (x > 0.f) ? x : 0.2f * x;
            p += x * atv[j];
        }
        p += __shfl_xor(p, 1);
        p += __shfl_xor(p, 2);
        p += __shfl_xor(p, 4);
        if (p > m) {
            const float sc = expf(m - p);
            den *= sc;
#pragma unroll
            for (int j = 0; j < 12; ++j) acc[j] *= sc;
            m = p;
        }
        const float w = expf(p - m);
        den += w;
#pragma unroll
        for (int j = 0; j < 12; ++j) acc[j] += w * fsv[j];
    }
    const float inv = (den > 0.f) ? 1.f / den : 0.f;
#pragma unroll
    for (int j = 0; j < 12; ++j) out[j] = acc[j] * inv;
}

// ---------------- agg over node list: h[n] = bf16(h + att_r0 + att_r1) ----------------
__global__ __launch_bounds__(256) void aggL_kernel(const bf16* __restrict__ fsd,
                                                   const int* __restrict__ idx,
                                                   const float* __restrict__ attn0,
                                                   const float* __restrict__ attn1,
                                                   const int* __restrict__ rowp0,
                                                   const int* __restrict__ eid0,
                                                   const int* __restrict__ src0,
                                                   const int* __restrict__ rowp1,
                                                   const int* __restrict__ eid1,
                                                   const int* __restrict__ src1,
                                                   bf16* __restrict__ h,
                                                   const int* __restrict__ list,
                                                   const int* __restrict__ pcnt,
                                                   int cap) {
    const int wid = threadIdx.x >> 6;
    const int lane = threadIdx.x & 63;
    int cnt = *pcnt; if (cnt > cap) cnt = cap;
    const int i = blockIdx.x * 4 + wid;
    if (i >= cnt) return;
    const int n = list[i];

    float a0[12], a1[12];
    att_accum(fsd, idx, n, lane, attn0, rowp0, eid0, src0, 0, 768, a0);
    att_accum(fsd, idx, n, lane, attn1, rowp1, eid1, src1, 1536, 2304, a1);

    const size_t base = (size_t)n * FDIM + lane * 12;
    const ushort4* ph = (const ushort4*)(h + base);
    const ushort4 h0 = ph[0], h1 = ph[1], h2 = ph[2];
    ushort4 r0, r1, r2;
    r0.x = f2u(u2f(h0.x) + a0[0] + a1[0]);  r0.y = f2u(u2f(h0.y) + a0[1] + a1[1]);
    r0.z = f2u(u2f(h0.z) + a0[2] + a1[2]);  r0.w = f2u(u2f(h0.w) + a0[3] + a1[3]);
    r1.x = f2u(u2f(h1.x) + a0[4] + a1[4]);  r1.y = f2u(u2f(h1.y) + a0[5] + a1[5]);
    r1.z = f2u(u2f(h1.z) + a0[6] + a1[6]);  r1.w = f2u(u2f(h1.w) + a0[7] + a1[7]);
    r2.x = f2u(u2f(h2.x) + a0[8] + a1[8]);  r2.y = f2u(u2f(h2.y) + a0[9] + a1[9]);
    r2.z = f2u(u2f(h2.z) + a0[10] + a1[10]); r2.w = f2u(u2f(h2.w) + a0[11] + a1[11]);
    ((ushort4*)(h + base))[0] = r0; ((ushort4*)(h + base))[1] = r1; ((ushort4*)(h + base))[2] = r2;
}

// ---------------- MLP head ----------------
__global__ __launch_bounds__(256) void head_kernel(const bf16* __restrict__ h,
                                                   const int* __restrict__ gsi,
                                                   const float* __restrict__ fc1w,
                                                   const float* __restrict__ fc1b,
                                                   const float* __restrict__ fc2w,
                                                   const float* __restrict__ fc2b,
                                                   float* __restrict__ out) {
    __shared__ float fe[FDIM];
    __shared__ float hid[256];
    const int b = blockIdx.x, t = threadIdx.x;
    const int node = gsi[b];
    for (int i = t; i < FDIM; i += 256) fe[i] = __bfloat162float(h[(size_t)node * FDIM + i]);
    __syncthreads();
    float acc = fc1b[t];
    for (int k = 0; k < FDIM; ++k) acc += fe[k] * fc1w[k * 256 + t];
    hid[t] = (acc > 0.f) ? acc : 0.f;
    __syncthreads();
    if (t < NC) {
        float acc2 = fc2b[t];
        for (int k = 0; k < 256; ++k) acc2 += hid[k] * fc2w[k * NC + t];
        out[1 + b * NC + t] = acc2;
    }
}

// ---------------- loss ----------------
__global__ __launch_bounds__(256) void loss_kernel(const float* __restrict__ logits,
                                                   const int* __restrict__ labels,
                                                   float* __restrict__ out) {
    __shared__ float red[256];
    const int b = threadIdx.x;
    float m = -INFINITY;
    for (int c = 0; c < NC; ++c) m = fmaxf(m, logits[b * NC + c]);
    float sum = 0.f;
    for (int c = 0; c < NC; ++c) sum += expf(logits[b * NC + c] - m);
    const float lse = m + logf(sum);
    const float ll = logits[b * NC + labels[b]];
    red[b] = lse - ll;
    __syncthreads();
    for (int s = 128; s > 0; s >>= 1) {
        if (b < s) red[b] += red[b + s];
        __syncthreads();
    }
    if (b == 0) out[0] = red[0] / (float)NB;
}

extern "C" void kernel_launch(void* const* d_in, const int* in_sizes, int n_in,
                              void* d_out, int out_size, void* d_ws, size_t ws_size,
                              hipStream_t stream) {
    const float* feats = (const float*)d_in[0];
    const float* fc1w  = (const float*)d_in[11];
    const float* fc1b  = (const float*)d_in[12];
    const float* fc2w  = (const float*)d_in[13];
    const float* fc2b  = (const float*)d_in[14];
    const int* src0    = (const int*)d_in[15];
    const int* dst0    = (const int*)d_in[16];
    const int* src1    = (const int*)d_in[17];
    const int* dst1    = (const int*)d_in[18];
    const int* gsi     = (const int*)d_in[19];
    const int* labels  = (const int*)d_in[20];

    const size_t NF = (size_t)N_NODES * FDIM;
    const size_t WSZ = (size_t)FDIM * FDIM;
    char* p = (char*)d_ws;
    bf16* h    = (bf16*)p;  p += NF * 2;
    bf16* fsd  = (bf16*)p;  p += (size_t)A1_CAP * NFUSE * 2;
    bf16* WtFl = (bf16*)p;  p += 4 * WSZ * 2;
    float* pb  = (float*)p; p += 2 * NFUSE * 4;
    int* flagL2 = (int*)p;  p += (size_t)N_NODES * 4;
    int* flagL1 = (int*)p;  p += (size_t)N_NODES * 4;
    int* flagA1 = (int*)p;  p += (size_t)N_NODES * 4;
    int* cnts   = (int*)p;  p += 64;
    const size_t flag_bytes = 3 * (size_t)N_NODES * 4 + 64;
    int* idx1  = (int*)p;   p += (size_t)N_NODES * 4;
    int* idx2  = (int*)p;   p += (size_t)N_NODES * 4;
    int* list1 = (int*)p;   p += (size_t)A1_CAP * 4;
    int* list2 = (int*)p;   p += (size_t)N1_CAP * 4;
    int* list0 = (int*)p;   p += 256 * 4;
    int* deg[2];  int* rowp[2];  int* cursor[2];  int* eid[2];
    for (int r = 0; r < 2; ++r) {
        deg[r]    = (int*)p; p += (size_t)N_NODES * 4 + 256;
        rowp[r]   = (int*)p; p += ((size_t)N_NODES + 1) * 4 + 256;
        cursor[r] = (int*)p; p += (size_t)N_NODES * 4 + 256;
        eid[r]    = (int*)p; p += (size_t)NE * 4 + 256;
    }

    const int eb = (NE + 255) / 256;

    // --- receptive-field sets ---
    hipMemsetAsync(flagL2, 0, flag_bytes, stream);
    mark_gsi_kernel<<<1, 256, 0, stream>>>(gsi, flagL2, flagL1, flagA1);
    mark_src_kernel<<<eb, 256, 0, stream>>>(src0, dst0, flagL2, flagL1, flagA1);
    mark_src_kernel<<<eb, 256, 0, stream>>>(src1, dst1, flagL2, flagL1, flagA1);
    mark_src_kernel<<<eb, 256, 0, stream>>>(src0, dst0, flagL1, flagA1, (int*)nullptr);
    mark_src_kernel<<<eb, 256, 0, stream>>>(src1, dst1, flagL1, flagA1, (int*)nullptr);
    compact_kernel<<<(N_NODES + 255) / 256, 256, 0, stream>>>(
        flagA1, flagL1, flagL2, list1, idx1, list2, idx2, list0, cnts);

    // --- CSR (full graph, per relation) ---
    for (int r = 0; r < 2; ++r) {
        const int* dst = r == 0 ? dst0 : dst1;
        hipMemsetAsync(deg[r], 0, sizeof(int) * N_NODES, stream);
        hist_kernel<<<eb, 256, 0, stream>>>(dst, deg[r]);
        scan_kernel<<<1, 256, 0, stream>>>(deg[r], rowp[r], cursor[r]);
        scatter_kernel<<<eb, 256, 0, stream>>>(dst, cursor[r], eid[r]);
    }

    cvt_gather_kernel<<<512, 256, 0, stream>>>(feats, list1, &cnts[0], h);
    bias_pack_kernel<<<(2 * NFUSE + 255) / 256, 256, 0, stream>>>(
        (const float*)d_in[2], (const float*)d_in[4], (const float*)d_in[7], (const float*)d_in[9], pb);

    dim3 tgrid(FDIM / 32, FDIM / 32, 4);

    // --- layer 0: rows = A1 (list1), agg at N1 (list2) ---
    twt4_kernel<<<tgrid, 256, 0, stream>>>(
        (const float*)d_in[1], (const float*)d_in[3],
        (const float*)d_in[6], (const float*)d_in[8], WtFl, 0);
    gemm_fused<<<(A1_CAP / GBM) * TILES_N, 512, 0, stream>>>(
        h, WtFl, pb, fsd, list1, &cnts[0], A1_CAP);
    aggL_kernel<<<(N1_CAP + 3) / 4, 256, 0, stream>>>(
        fsd, idx1, (const float*)d_in[5], (const float*)d_in[10],
        rowp[0], eid[0], src0, rowp[1], eid[1], src1, h, list2, &cnts[1], N1_CAP);

    // --- layer 1: rows = N1 (list2), agg at S0 (list0) ---
    twt4_kernel<<<tgrid, 256, 0, stream>>>(
        (const float*)d_in[1], (const float*)d_in[3],
        (const float*)d_in[6], (const float*)d_in[8], WtFl, 1);
    gemm_fused<<<(N1_CAP / GBM) * TILES_N, 512, 0, stream>>>(
        h, WtFl, pb + NFUSE, fsd, list2, &cnts[1], N1_CAP);
    aggL_kernel<<<64, 256, 0, stream>>>(
        fsd, idx2, (const float*)d_in[5] + FDIM, (const float*)d_in[10] + FDIM,
        rowp[0], eid[0], src0, rowp[1], eid[1], src1, h, list0, &cnts[2], 256);

    head_kernel<<<NB, 256, 0, stream>>>(h, gsi, fc1w, fc1b, fc2w, fc2b, (float*)d_out);
    loss_kernel<<<1, 256, 0, stream>>>((float*)d_out + 1, labels, (float*)d_out);
}

// Round 10
// 228.895 us; speedup vs baseline: 82.2137x; 2.0444x over previous
//
#include <hip/hip_runtime.h>
#include <hip/hip_bf16.h>
#include <math.h>

#define N_NODES 50000
#define NE      100000
#define NH      8
#define FDIM    768
#define NFUSE   3072
#define NB      256
#define NC      31

#define A1_CAP  16384   // nodes needing fsd in layer 0 (expect ~6.4k)
#define N1_CAP  4096    // nodes needing h1 / fsd in layer 1 (expect ~1.3k)
#define TILES_N 12      // 3072/256
#define NBLK    ((N_NODES + 255) / 256)   // 196

typedef __hip_bfloat16 bf16;
typedef __attribute__((ext_vector_type(8))) short bf16x8;
typedef __attribute__((ext_vector_type(4))) float f32x4;

__device__ inline float u2f(unsigned short u) { return __uint_as_float(((unsigned int)u) << 16); }
__device__ inline unsigned short f2u(float f) { return __bfloat16_as_ushort(__float2bfloat16(f)); }

__device__ inline void load_lds16(const void* g, void* l) {
    __builtin_amdgcn_global_load_lds(
        (const __attribute__((address_space(1))) void*)g,
        (__attribute__((address_space(3))) void*)l, 16, 0, 0);
}

// ---------------- receptive-field construction ----------------
__global__ __launch_bounds__(256) void mark_gsi_kernel(const int* __restrict__ gsi,
                                                       int* __restrict__ fL2,
                                                       int* __restrict__ fL1,
                                                       int* __restrict__ fA1) {
    const int n = gsi[threadIdx.x];
    fL2[n] = 1; fL1[n] = 1; fA1[n] = 1;
}

__global__ __launch_bounds__(256) void mark_src_kernel(const int* __restrict__ src,
                                                       const int* __restrict__ dst,
                                                       const int* __restrict__ dflag,
                                                       int* __restrict__ f1,
                                                       int* __restrict__ f2) {
    const int e = blockIdx.x * 256 + threadIdx.x;
    if (e >= NE) return;
    if (dflag[dst[e]]) {
        const int s = src[e];
        f1[s] = 1;
        if (f2) f2[s] = 1;
    }
}

__global__ __launch_bounds__(256) void compact_kernel(const int* __restrict__ fA1,
                                                      const int* __restrict__ fL1,
                                                      const int* __restrict__ fL2,
                                                      int* __restrict__ list1, int* __restrict__ idx1,
                                                      int* __restrict__ list2, int* __restrict__ idx2,
                                                      int* __restrict__ list0,
                                                      int* __restrict__ cnts) {
    const int n = blockIdx.x * 256 + threadIdx.x;
    if (n >= N_NODES) return;
    if (fA1[n]) {
        const int p = atomicAdd(&cnts[0], 1);
        if (p < A1_CAP) { list1[p] = n; idx1[n] = p; } else idx1[n] = 0;
    }
    if (fL1[n]) {
        const int p = atomicAdd(&cnts[1], 1);
        if (p < N1_CAP) { list2[p] = n; idx2[n] = p; } else idx2[n] = 0;
    }
    if (fL2[n]) {
        const int p = atomicAdd(&cnts[2], 1);
        if (p < 256) list0[p] = n;
    }
}

// ---------------- gathered convert f32 -> bf16 ----------------
__global__ __launch_bounds__(256) void cvt_gather_kernel(const float* __restrict__ feats,
                                                         const int* __restrict__ list,
                                                         const int* __restrict__ pcnt,
                                                         bf16* __restrict__ h) {
    int c = *pcnt; if (c > A1_CAP) c = A1_CAP;
    for (int b = blockIdx.x; b < c; b += gridDim.x) {
        const int n = list[b];
        const float* s = feats + (size_t)n * FDIM;
        bf16* d = h + (size_t)n * FDIM;
        for (int i = threadIdx.x; i < FDIM; i += 256) d[i] = __float2bfloat16(s[i]);
    }
}

// ---------------- weight transpose+convert, all 8 matrices (both layers) ----------------
// z = l*4 + sel; dst block: WtFl[(l*4+sel)*768 + n][k] = bf16(src_sel[l][k][n])
__global__ __launch_bounds__(256) void twt8_kernel(const float* __restrict__ w_sc,
                                                   const float* __restrict__ w_dc,
                                                   const float* __restrict__ w_scb,
                                                   const float* __restrict__ w_dcb,
                                                   bf16* __restrict__ WtFl) {
    const int z = blockIdx.z;
    const int l = z >> 2, sel = z & 3;
    const float* src;
    if (sel == 0) src = w_sc; else if (sel == 1) src = w_dc; else if (sel == 2) src = w_scb; else src = w_dcb;
    src += (size_t)l * FDIM * FDIM;
    bf16* dst = WtFl + (size_t)z * FDIM * FDIM;

    __shared__ float tile[32][33];
    const int tx = threadIdx.x & 31, ty = threadIdx.x >> 5;
    const int x0 = blockIdx.x * 32, y0 = blockIdx.y * 32;
#pragma unroll
    for (int q = 0; q < 4; ++q)
        tile[ty + q * 8][tx] = src[(size_t)(y0 + ty + q * 8) * FDIM + x0 + tx];
    __syncthreads();
#pragma unroll
    for (int q = 0; q < 4; ++q)
        dst[(size_t)(x0 + ty + q * 8) * FDIM + y0 + tx] = __float2bfloat16(tile[tx][ty + q * 8]);
}

// ---------------- bias pack: pb[l][3072] ----------------
__global__ __launch_bounds__(256) void bias_pack_kernel(const float* __restrict__ b_sc,
                                                        const float* __restrict__ b_dc,
                                                        const float* __restrict__ b_scb,
                                                        const float* __restrict__ b_dcb,
                                                        float* __restrict__ pb) {
    const int idx = blockIdx.x * 256 + threadIdx.x;
    if (idx >= 2 * NFUSE) return;
    const int l = idx / NFUSE, c = idx % NFUSE;
    const int sel = c / FDIM, off = c % FDIM;
    const float* src;
    if (sel == 0) src = b_sc; else if (sel == 1) src = b_dc; else if (sel == 2) src = b_scb; else src = b_dcb;
    pb[idx] = src[l * FDIM + off];
}

// ---------------- pipelined MFMA GEMM over compacted row list ----------------
#define GBM 256
#define GBN 256
#define NKT 12  // 768/64

__global__ __launch_bounds__(512, 1) void gemm_fused(const bf16* __restrict__ A,
                                                     const bf16* __restrict__ Wt,
                                                     const float* __restrict__ pb,
                                                     bf16* __restrict__ C,
                                                     const int* __restrict__ rowlist,
                                                     const int* __restrict__ pcnt,
                                                     int mcap) {
    int cnt = *pcnt; if (cnt > mcap) cnt = mcap;
    const int bid = blockIdx.x;
    const int tm = bid / TILES_N, tn = bid % TILES_N;
    const int m0 = tm * GBM, n0 = tn * GBN;
    if (m0 >= cnt) return;

    __shared__ __align__(16) short lds[2][2][2][8192];
    const int t = threadIdx.x;
    const int wid = t >> 6, lane = t & 63;
    const int wr = wid >> 2, wc = wid & 3;
    const int lr = lane & 15, lk = lane >> 4;

    const f32x4 zero4 = {0.f, 0.f, 0.f, 0.f};
    f32x4 acc[8][4];
#pragma unroll
    for (int i = 0; i < 8; ++i)
#pragma unroll
        for (int j = 0; j < 4; ++j) acc[i][j] = zero4;

    const int scol_sw = (((lane & 3) ^ ((lane >> 3) & 3)) << 3);
    int arow[2], brow[2], dstq[2];
#pragma unroll
    for (int q = 0; q < 2; ++q) {
        int rr = m0 + wid * 32 + q * 16 + (lane >> 2);
        if (rr >= cnt) rr = cnt - 1;
        arow[q] = rowlist[rr];
        brow[q] = n0 + wid * 32 + q * 16 + (lane >> 2);
        dstq[q] = wid * 2048 + q * 1024;
    }
    const int rsw = ((lk ^ ((lr >> 1) & 3)) << 3);
    const int abase = wr * 128 + lr;
    const int bbase = wc * 64 + lr;

#define STG_A(d, kh, kt) {                                                                  \
        load_lds16(A + (size_t)arow[0] * FDIM + (kt) * 64 + (kh) * 32 + scol_sw,            \
                   (char*)&lds[d][0][kh][0] + dstq[0]);                                     \
        load_lds16(A + (size_t)arow[1] * FDIM + (kt) * 64 + (kh) * 32 + scol_sw,            \
                   (char*)&lds[d][0][kh][0] + dstq[1]); }
#define STG_B(d, kh, kt) {                                                                  \
        load_lds16(Wt + (size_t)brow[0] * FDIM + (kt) * 64 + (kh) * 32 + scol_sw,           \
                   (char*)&lds[d][1][kh][0] + dstq[0]);                                     \
        load_lds16(Wt + (size_t)brow[1] * FDIM + (kt) * 64 + (kh) * 32 + scol_sw,           \
                   (char*)&lds[d][1][kh][0] + dstq[1]); }

    STG_A(0, 0, 0); STG_B(0, 0, 0); STG_A(0, 1, 0); STG_B(0, 1, 0);
    asm volatile("s_waitcnt vmcnt(4)");
    __builtin_amdgcn_s_barrier();
    __builtin_amdgcn_sched_barrier(0);

    int db = 0;
    for (int j = 0; j < NKT; ++j) {
        const int nd = db ^ 1;
        const bool st = (j + 1) < NKT;
        const short* Ak0 = &lds[db][0][0][0];
        const short* Bk0 = &lds[db][1][0][0];
        const short* Ak1 = &lds[db][0][1][0];
        const short* Bk1 = &lds[db][1][1][0];
        bf16x8 av[4], bv[4], av2[4];

        // P1
#pragma unroll
        for (int i = 0; i < 4; ++i) av[i] = *(const bf16x8*)&Ak0[(abase + i * 16) * 32 + rsw];
#pragma unroll
        for (int jj = 0; jj < 4; ++jj) bv[jj] = *(const bf16x8*)&Bk0[(bbase + jj * 16) * 32 + rsw];
        if (st) STG_A(nd, 0, j + 1);
        __builtin_amdgcn_s_barrier();
        asm volatile("s_waitcnt lgkmcnt(0)");
        __builtin_amdgcn_sched_barrier(0);
        __builtin_amdgcn_s_setprio(1);
#pragma unroll
        for (int i = 0; i < 4; ++i)
#pragma unroll
            for (int jj = 0; jj < 4; ++jj)
                acc[i][jj] = __builtin_amdgcn_mfma_f32_16x16x32_bf16(bv[jj], av[i], acc[i][jj], 0, 0, 0);
        __builtin_amdgcn_s_setprio(0);
        __builtin_amdgcn_s_barrier();
        __builtin_amdgcn_sched_barrier(0);

        // P2
#pragma unroll
        for (int i = 0; i < 4; ++i) av2[i] = *(const bf16x8*)&Ak0[(abase + (4 + i) * 16) * 32 + rsw];
        if (st) STG_B(nd, 0, j + 1);
        __builtin_amdgcn_s_barrier();
        asm volatile("s_waitcnt lgkmcnt(0)");
        __builtin_amdgcn_sched_barrier(0);
        __builtin_amdgcn_s_setprio(1);
#pragma unroll
        for (int i = 0; i < 4; ++i)
#pragma unroll
            for (int jj = 0; jj < 4; ++jj)
                acc[4 + i][jj] = __builtin_amdgcn_mfma_f32_16x16x32_bf16(bv[jj], av2[i], acc[4 + i][jj], 0, 0, 0);
        __builtin_amdgcn_s_setprio(0);
        if (st) { asm volatile("s_waitcnt vmcnt(4)"); }
        else    { asm volatile("s_waitcnt vmcnt(0)"); }
        __builtin_amdgcn_s_barrier();
        __builtin_amdgcn_sched_barrier(0);

        // P3
#pragma unroll
        for (int i = 0; i < 4; ++i) av[i] = *(const bf16x8*)&Ak1[(abase + i * 16) * 32 + rsw];
#pragma unroll
        for (int jj = 0; jj < 4; ++jj) bv[jj] = *(const bf16x8*)&Bk1[(bbase + jj * 16) * 32 + rsw];
        if (st) STG_A(nd, 1, j + 1);
        __builtin_amdgcn_s_barrier();
        asm volatile("s_waitcnt lgkmcnt(0)");
        __builtin_amdgcn_sched_barrier(0);
        __builtin_amdgcn_s_setprio(1);
#pragma unroll
        for (int i = 0; i < 4; ++i)
#pragma unroll
            for (int jj = 0; jj < 4; ++jj)
                acc[i][jj] = __builtin_amdgcn_mfma_f32_16x16x32_bf16(bv[jj], av[i], acc[i][jj], 0, 0, 0);
        __builtin_amdgcn_s_setprio(0);
        __builtin_amdgcn_s_barrier();
        __builtin_amdgcn_sched_barrier(0);

        // P4
#pragma unroll
        for (int i = 0; i < 4; ++i) av2[i] = *(const bf16x8*)&Ak1[(abase + (4 + i) * 16) * 32 + rsw];
        if (st) STG_B(nd, 1, j + 1);
        __builtin_amdgcn_s_barrier();
        asm volatile("s_waitcnt lgkmcnt(0)");
        __builtin_amdgcn_sched_barrier(0);
        __builtin_amdgcn_s_setprio(1);
#pragma unroll
        for (int i = 0; i < 4; ++i)
#pragma unroll
            for (int jj = 0; jj < 4; ++jj)
                acc[4 + i][jj] = __builtin_amdgcn_mfma_f32_16x16x32_bf16(bv[jj], av2[i], acc[4 + i][jj], 0, 0, 0);
        __builtin_amdgcn_s_setprio(0);
        if (st) { asm volatile("s_waitcnt vmcnt(4)"); }
        __builtin_amdgcn_s_barrier();
        __builtin_amdgcn_sched_barrier(0);

        db = nd;
    }
#undef STG_A
#undef STG_B

#pragma unroll
    for (int i = 0; i < 8; ++i) {
        const int row = m0 + wr * 128 + i * 16 + lr;
        if (row < cnt) {
#pragma unroll
            for (int jj = 0; jj < 4; ++jj) {
                const int col = n0 + wc * 64 + jj * 16 + lk * 4;
                const float4 b4 = *(const float4*)(pb + col);
                ushort4 w;
                w.x = f2u(acc[i][jj][0] + b4.x);
                w.y = f2u(acc[i][jj][1] + b4.y);
                w.z = f2u(acc[i][jj][2] + b4.z);
                w.w = f2u(acc[i][jj][3] + b4.w);
                *(ushort4*)(C + (size_t)row * NFUSE + col) = w;
            }
        }
    }
}

// ---------------- CSR build (both relations, parallel scan) ----------------
__global__ __launch_bounds__(256) void hist2_kernel(const int* __restrict__ dst0,
                                                    const int* __restrict__ dst1,
                                                    int* __restrict__ deg) {  // deg[2][N]
    const int e = blockIdx.x * 256 + threadIdx.x;
    const int r = blockIdx.y;
    if (e < NE) atomicAdd(&deg[(size_t)r * N_NODES + (r ? dst1 : dst0)[e]], 1);
}

// per-chunk sums: bsum[r][b]
__global__ __launch_bounds__(256) void scan1_kernel(const int* __restrict__ deg,
                                                    int* __restrict__ bsum) {
    const int r = blockIdx.y, b = blockIdx.x, t = threadIdx.x;
    const int i = b * 256 + t;
    __shared__ int s[256];
    s[t] = (i < N_NODES) ? deg[(size_t)r * N_NODES + i] : 0;
    __syncthreads();
    for (int o = 128; o > 0; o >>= 1) {
        if (t < o) s[t] += s[t + o];
        __syncthreads();
    }
    if (t == 0) bsum[r * NBLK + b] = s[0];
}

// exclusive scan of chunk sums; also rowp[N]=NE for both
__global__ __launch_bounds__(256) void scan2_kernel(int* __restrict__ bsum,
                                                    int* __restrict__ boff,
                                                    int* __restrict__ rowp0,
                                                    int* __restrict__ rowp1) {
    const int t = threadIdx.x;
    if (t < 2) {
        int run = 0;
        for (int b = 0; b < NBLK; ++b) {
            boff[t * NBLK + b] = run;
            run += bsum[t * NBLK + b];
        }
    }
    if (t == 0) rowp0[N_NODES] = NE;
    if (t == 1) rowp1[N_NODES] = NE;
}

// per-chunk Hillis-Steele; write rowp + cursor
__global__ __launch_bounds__(256) void scan3_kernel(const int* __restrict__ deg,
                                                    const int* __restrict__ boff,
                                                    int* __restrict__ rowp0, int* __restrict__ cursor0,
                                                    int* __restrict__ rowp1, int* __restrict__ cursor1) {
    const int r = blockIdx.y, b = blockIdx.x, t = threadIdx.x;
    const int i = b * 256 + t;
    int* rowp = r ? rowp1 : rowp0;
    int* cursor = r ? cursor1 : cursor0;
    __shared__ int s[256];
    const int v = (i < N_NODES) ? deg[(size_t)r * N_NODES + i] : 0;
    s[t] = v;
    __syncthreads();
    for (int o = 1; o < 256; o <<= 1) {
        int x = 0;
        if (t >= o) x = s[t - o];
        __syncthreads();
        if (t >= o) s[t] += x;
        __syncthreads();
    }
    if (i < N_NODES) {
        const int p = boff[r * NBLK + b] + s[t] - v;  // exclusive
        rowp[i] = p;
        cursor[i] = p;
    }
}

__global__ __launch_bounds__(256) void scatter2_kernel(const int* __restrict__ dst0,
                                                       const int* __restrict__ dst1,
                                                       int* __restrict__ cursor0,
                                                       int* __restrict__ cursor1,
                                                       int* __restrict__ eid0,
                                                       int* __restrict__ eid1) {
    const int e = blockIdx.x * 256 + threadIdx.x;
    const int r = blockIdx.y;
    if (e < NE) {
        if (r == 0) { const int p = atomicAdd(&cursor0[dst0[e]], 1); eid0[p] = e; }
        else        { const int p = atomicAdd(&cursor1[dst1[e]], 1); eid1[p] = e; }
    }
}

// ---------------- per-relation online-softmax attention (compact fsd via idx) ----------------
__device__ inline void att_accum(const bf16* __restrict__ fsd, const int* __restrict__ idx,
                                 int n, int lane, const float* __restrict__ attn,
                                 const int* __restrict__ rowp, const int* __restrict__ eid,
                                 const int* __restrict__ src, int fs_off, int fd_off,
                                 float* __restrict__ out) {
    float fdv[12], atv[12];
    {
        const ushort4* pfd = (const ushort4*)(fsd + (size_t)idx[n] * NFUSE + fd_off + lane * 12);
        const ushort4 d0 = pfd[0], d1 = pfd[1], d2 = pfd[2];
        fdv[0] = u2f(d0.x); fdv[1] = u2f(d0.y); fdv[2] = u2f(d0.z); fdv[3] = u2f(d0.w);
        fdv[4] = u2f(d1.x); fdv[5] = u2f(d1.y); fdv[6] = u2f(d1.z); fdv[7] = u2f(d1.w);
        fdv[8] = u2f(d2.x); fdv[9] = u2f(d2.y); fdv[10] = u2f(d2.z); fdv[11] = u2f(d2.w);
        const float4* pat = (const float4*)(attn + lane * 12);
        const float4 a0 = pat[0], a1 = pat[1], a2 = pat[2];
        atv[0] = a0.x; atv[1] = a0.y; atv[2] = a0.z; atv[3] = a0.w;
        atv[4] = a1.x; atv[5] = a1.y; atv[6] = a1.z; atv[7] = a1.w;
        atv[8] = a2.x; atv[9] = a2.y; atv[10] = a2.z; atv[11] = a2.w;
    }
    const int beg = rowp[n], end = rowp[n + 1];
    float m = -INFINITY, den = 0.f;
    float acc[12];
#pragma unroll
    for (int j = 0; j < 12; ++j) acc[j] = 0.f;

    for (int i = beg; i < end; ++i) {
        const int e = eid[i];
        const ushort4* pf = (const ushort4*)(fsd + (size_t)idx[src[e]] * NFUSE + fs_off + lane * 12);
        const ushort4 a0 = pf[0], a1 = pf[1], a2 = pf[2];
        float fsv[12];
        fsv[0] = u2f(a0.x); fsv[1] = u2f(a0.y); fsv[2] = u2f(a0.z); fsv[3] = u2f(a0.w);
        fsv[4] = u2f(a1.x); fsv[5] = u2f(a1.y); fsv[6] = u2f(a1.z); fsv[7] = u2f(a1.w);
        fsv[8] = u2f(a2.x); fsv[9] = u2f(a2.y); fsv[10] = u2f(a2.z); fsv[11] = u2f(a2.w);
        float p = 0.f;
#pragma unroll
        for (int j = 0; j < 12; ++j) {
            float x = fsv[j] + fdv[j];
            x = (x > 0.f) ? x : 0.2f * x;
            p += x * atv[j];
        }
        p += __shfl_xor(p, 1);
        p += __shfl_xor(p, 2);
        p += __shfl_xor(p, 4);
        if (p > m) {
            const float sc = expf(m - p);
            den *= sc;
#pragma unroll
            for (int j = 0; j < 12; ++j) acc[j] *= sc;
            m = p;
        }
        const float w = expf(p - m);
        den += w;
#pragma unroll
        for (int j = 0; j < 12; ++j) acc[j] += w * fsv[j];
    }
    const float inv = (den > 0.f) ? 1.f / den : 0.f;
#pragma unroll
    for (int j = 0; j < 12; ++j) out[j] = acc[j] * inv;
}

// ---------------- agg over node list: h[n] = bf16(h + att_r0 + att_r1) ----------------
__global__ __launch_bounds__(256) void aggL_kernel(const bf16* __restrict__ fsd,
                                                   const int* __restrict__ idx,
                                                   const float* __restrict__ attn0,
                                                   const float* __restrict__ attn1,
                                                   const int* __restrict__ rowp0,
                                                   const int* __restrict__ eid0,
                                                   const int* __restrict__ src0,
                                                   const int* __restrict__ rowp1,
                                                   const int* __restrict__ eid1,
                                                   const int* __restrict__ src1,
                                                   bf16* __restrict__ h,
                                                   const int* __restrict__ list,
                                                   const int* __restrict__ pcnt,
                                                   int cap) {
    const int wid = threadIdx.x >> 6;
    const int lane = threadIdx.x & 63;
    int cnt = *pcnt; if (cnt > cap) cnt = cap;
    const int i = blockIdx.x * 4 + wid;
    if (i >= cnt) return;
    const int n = list[i];

    float a0[12], a1[12];
    att_accum(fsd, idx, n, lane, attn0, rowp0, eid0, src0, 0, 768, a0);
    att_accum(fsd, idx, n, lane, attn1, rowp1, eid1, src1, 1536, 2304, a1);

    const size_t base = (size_t)n * FDIM + lane * 12;
    const ushort4* ph = (const ushort4*)(h + base);
    const ushort4 h0 = ph[0], h1 = ph[1], h2 = ph[2];
    ushort4 r0, r1, r2;
    r0.x = f2u(u2f(h0.x) + a0[0] + a1[0]);  r0.y = f2u(u2f(h0.y) + a0[1] + a1[1]);
    r0.z = f2u(u2f(h0.z) + a0[2] + a1[2]);  r0.w = f2u(u2f(h0.w) + a0[3] + a1[3]);
    r1.x = f2u(u2f(h1.x) + a0[4] + a1[4]);  r1.y = f2u(u2f(h1.y) + a0[5] + a1[5]);
    r1.z = f2u(u2f(h1.z) + a0[6] + a1[6]);  r1.w = f2u(u2f(h1.w) + a0[7] + a1[7]);
    r2.x = f2u(u2f(h2.x) + a0[8] + a1[8]);  r2.y = f2u(u2f(h2.y) + a0[9] + a1[9]);
    r2.z = f2u(u2f(h2.z) + a0[10] + a1[10]); r2.w = f2u(u2f(h2.w) + a0[11] + a1[11]);
    ((ushort4*)(h + base))[0] = r0; ((ushort4*)(h + base))[1] = r1; ((ushort4*)(h + base))[2] = r2;
}

// ---------------- MLP head ----------------
__global__ __launch_bounds__(256) void head_kernel(const bf16* __restrict__ h,
                                                   const int* __restrict__ gsi,
                                                   const float* __restrict__ fc1w,
                                                   const float* __restrict__ fc1b,
                                                   const float* __restrict__ fc2w,
                                                   const float* __restrict__ fc2b,
                                                   float* __restrict__ out) {
    __shared__ float fe[FDIM];
    __shared__ float hid[256];
    const int b = blockIdx.x, t = threadIdx.x;
    const int node = gsi[b];
    for (int i = t; i < FDIM; i += 256) fe[i] = __bfloat162float(h[(size_t)node * FDIM + i]);
    __syncthreads();
    float acc = fc1b[t];
    for (int k = 0; k < FDIM; ++k) acc += fe[k] * fc1w[k * 256 + t];
    hid[t] = (acc > 0.f) ? acc : 0.f;
    __syncthreads();
    if (t < NC) {
        float acc2 = fc2b[t];
        for (int k = 0; k < 256; ++k) acc2 += hid[k] * fc2w[k * NC + t];
        out[1 + b * NC + t] = acc2;
    }
}

// ---------------- loss ----------------
__global__ __launch_bounds__(256) void loss_kernel(const float* __restrict__ logits,
                                                   const int* __restrict__ labels,
                                                   float* __restrict__ out) {
    __shared__ float red[256];
    const int b = threadIdx.x;
    float m = -INFINITY;
    for (int c = 0; c < NC; ++c) m = fmaxf(m, logits[b * NC + c]);
    float sum = 0.f;
    for (int c = 0; c < NC; ++c) sum += expf(logits[b * NC + c] - m);
    const float lse = m + logf(sum);
    const float ll = logits[b * NC + labels[b]];
    red[b] = lse - ll;
    __syncthreads();
    for (int s = 128; s > 0; s >>= 1) {
        if (b < s) red[b] += red[b + s];
        __syncthreads();
    }
    if (b == 0) out[0] = red[0] / (float)NB;
}

extern "C" void kernel_launch(void* const* d_in, const int* in_sizes, int n_in,
                              void* d_out, int out_size, void* d_ws, size_t ws_size,
                              hipStream_t stream) {
    const float* feats = (const float*)d_in[0];
    const float* fc1w  = (const float*)d_in[11];
    const float* fc1b  = (const float*)d_in[12];
    const float* fc2w  = (const float*)d_in[13];
    const float* fc2b  = (const float*)d_in[14];
    const int* src0    = (const int*)d_in[15];
    const int* dst0    = (const int*)d_in[16];
    const int* src1    = (const int*)d_in[17];
    const int* dst1    = (const int*)d_in[18];
    const int* gsi     = (const int*)d_in[19];
    const int* labels  = (const int*)d_in[20];

    const size_t NF = (size_t)N_NODES * FDIM;
    const size_t WSZ = (size_t)FDIM * FDIM;
    char* p = (char*)d_ws;
    bf16* h    = (bf16*)p;  p += NF * 2;
    bf16* fsd  = (bf16*)p;  p += (size_t)A1_CAP * NFUSE * 2;
    bf16* WtFl = (bf16*)p;  p += 8 * WSZ * 2;     // both layers
    float* pb  = (float*)p; p += 2 * NFUSE * 4;
    int* flagL2 = (int*)p;  p += (size_t)N_NODES * 4;
    int* flagL1 = (int*)p;  p += (size_t)N_NODES * 4;
    int* flagA1 = (int*)p;  p += (size_t)N_NODES * 4;
    int* cnts   = (int*)p;  p += 64;
    const size_t flag_bytes = 3 * (size_t)N_NODES * 4 + 64;
    int* idx1  = (int*)p;   p += (size_t)N_NODES * 4;
    int* idx2  = (int*)p;   p += (size_t)N_NODES * 4;
    int* list1 = (int*)p;   p += (size_t)A1_CAP * 4;
    int* list2 = (int*)p;   p += (size_t)N1_CAP * 4;
    int* list0 = (int*)p;   p += 256 * 4;
    int* deg   = (int*)p;   p += 2 * (size_t)N_NODES * 4;   // deg[2][N]
    int* bsum  = (int*)p;   p += 2 * NBLK * 4;
    int* boff  = (int*)p;   p += 2 * NBLK * 4;
    int* rowp0 = (int*)p;   p += ((size_t)N_NODES + 1) * 4 + 252;
    int* rowp1 = (int*)p;   p += ((size_t)N_NODES + 1) * 4 + 252;
    int* cursor0 = (int*)p; p += (size_t)N_NODES * 4;
    int* cursor1 = (int*)p; p += (size_t)N_NODES * 4;
    int* eid0  = (int*)p;   p += (size_t)NE * 4;
    int* eid1  = (int*)p;   p += (size_t)NE * 4;

    const int eb = (NE + 255) / 256;

    // --- receptive-field sets ---
    hipMemsetAsync(flagL2, 0, flag_bytes, stream);
    mark_gsi_kernel<<<1, 256, 0, stream>>>(gsi, flagL2, flagL1, flagA1);
    mark_src_kernel<<<eb, 256, 0, stream>>>(src0, dst0, flagL2, flagL1, flagA1);
    mark_src_kernel<<<eb, 256, 0, stream>>>(src1, dst1, flagL2, flagL1, flagA1);
    mark_src_kernel<<<eb, 256, 0, stream>>>(src0, dst0, flagL1, flagA1, (int*)nullptr);
    mark_src_kernel<<<eb, 256, 0, stream>>>(src1, dst1, flagL1, flagA1, (int*)nullptr);
    compact_kernel<<<(N_NODES + 255) / 256, 256, 0, stream>>>(
        flagA1, flagL1, flagL2, list1, idx1, list2, idx2, list0, cnts);

    // --- CSR (both relations, parallel scan) ---
    hipMemsetAsync(deg, 0, 2 * sizeof(int) * N_NODES, stream);
    hist2_kernel<<<dim3(eb, 2), 256, 0, stream>>>(dst0, dst1, deg);
    scan1_kernel<<<dim3(NBLK, 2), 256, 0, stream>>>(deg, bsum);
    scan2_kernel<<<1, 256, 0, stream>>>(bsum, boff, rowp0, rowp1);
    scan3_kernel<<<dim3(NBLK, 2), 256, 0, stream>>>(deg, boff, rowp0, cursor0, rowp1, cursor1);
    scatter2_kernel<<<dim3(eb, 2), 256, 0, stream>>>(dst0, dst1, cursor0, cursor1, eid0, eid1);

    cvt_gather_kernel<<<512, 256, 0, stream>>>(feats, list1, &cnts[0], h);
    bias_pack_kernel<<<(2 * NFUSE + 255) / 256, 256, 0, stream>>>(
        (const float*)d_in[2], (const float*)d_in[4], (const float*)d_in[7], (const float*)d_in[9], pb);
    twt8_kernel<<<dim3(FDIM / 32, FDIM / 32, 8), 256, 0, stream>>>(
        (const float*)d_in[1], (const float*)d_in[3],
        (const float*)d_in[6], (const float*)d_in[8], WtFl);

    // --- layer 0 ---
    gemm_fused<<<(A1_CAP / GBM) * TILES_N, 512, 0, stream>>>(
        h, WtFl, pb, fsd, list1, &cnts[0], A1_CAP);
    aggL_kernel<<<(N1_CAP + 3) / 4, 256, 0, stream>>>(
        fsd, idx1, (const float*)d_in[5], (const float*)d_in[10],
        rowp0, eid0, src0, rowp1, eid1, src1, h, list2, &cnts[1], N1_CAP);

    // --- layer 1 ---
    gemm_fused<<<(N1_CAP / GBM) * TILES_N, 512, 0, stream>>>(
        h, WtFl + 4 * WSZ, pb + NFUSE, fsd, list2, &cnts[1], N1_CAP);
    aggL_kernel<<<64, 256, 0, stream>>>(
        fsd, idx2, (const float*)d_in[5] + FDIM, (const float*)d_in[10] + FDIM,
        rowp0, eid0, src0, rowp1, eid1, src1, h, list0, &cnts[2], 256);

    head_kernel<<<NB, 256, 0, stream>>>(h, gsi, fc1w, fc1b, fc2w, fc2b, (float*)d_out);
    loss_kernel<<<1, 256, 0, stream>>>((float*)d_out + 1, labels, (float*)d_out);
}

// Round 11
// 221.847 us; speedup vs baseline: 84.8257x; 1.0318x over previous
//
#include <hip/hip_runtime.h>
#include <hip/hip_bf16.h>
#include <math.h>

#define N_NODES 50000
#define NE      100000
#define FDIM    768
#define NFUSE   3072
#define NB      256
#define NC      31

#define A1_CAP  16384
#define N1_CAP  4096
#define NBLK    ((N_NODES + 255) / 256)   // 196

// setup kernel partition
#define TWT_BLOCKS  (8 * 576)   // 8 matrices x (24x24) 32-tiles
#define BIAS_BLOCKS 24          // 2*3072/256
#define CVT_BLOCKS  512
#define SETUP_BLOCKS (TWT_BLOCKS + BIAS_BLOCKS + CVT_BLOCKS)

typedef __hip_bfloat16 bf16;
typedef __attribute__((ext_vector_type(8))) short bf16x8;
typedef __attribute__((ext_vector_type(4))) float f32x4;

__device__ inline float u2f(unsigned short u) { return __uint_as_float(((unsigned int)u) << 16); }
__device__ inline unsigned short f2u(float f) { return __bfloat16_as_ushort(__float2bfloat16(f)); }

__device__ inline void load_lds16(const void* g, void* l) {
    __builtin_amdgcn_global_load_lds(
        (const __attribute__((address_space(1))) void*)g,
        (__attribute__((address_space(3))) void*)l, 16, 0, 0);
}

// ---------------- receptive-field construction ----------------
__global__ __launch_bounds__(256) void mark_gsi_kernel(const int* __restrict__ gsi,
                                                       int* __restrict__ fL2,
                                                       int* __restrict__ fL1,
                                                       int* __restrict__ fA1) {
    const int n = gsi[threadIdx.x];
    fL2[n] = 1; fL1[n] = 1; fA1[n] = 1;
}

// both relations in one dispatch: if dflag[dst[e]] mark src[e] into f1 (and f2)
__global__ __launch_bounds__(256) void mark2_kernel(const int* __restrict__ src0,
                                                    const int* __restrict__ dst0,
                                                    const int* __restrict__ src1,
                                                    const int* __restrict__ dst1,
                                                    const int* __restrict__ dflag,
                                                    int* __restrict__ f1,
                                                    int* __restrict__ f2) {
    const int e = blockIdx.x * 256 + threadIdx.x;
    if (e >= NE) return;
    const int* src = blockIdx.y ? src1 : src0;
    const int* dst = blockIdx.y ? dst1 : dst0;
    if (dflag[dst[e]]) {
        const int s = src[e];
        f1[s] = 1;
        if (f2) f2[s] = 1;
    }
}

__global__ __launch_bounds__(256) void compact_kernel(const int* __restrict__ fA1,
                                                      const int* __restrict__ fL1,
                                                      const int* __restrict__ fL2,
                                                      int* __restrict__ list1, int* __restrict__ idx1,
                                                      int* __restrict__ list2, int* __restrict__ idx2,
                                                      int* __restrict__ list0,
                                                      int* __restrict__ cnts) {
    const int n = blockIdx.x * 256 + threadIdx.x;
    if (n >= N_NODES) return;
    if (fA1[n]) {
        const int p = atomicAdd(&cnts[0], 1);
        if (p < A1_CAP) { list1[p] = n; idx1[n] = p; } else idx1[n] = 0;
    }
    if (fL1[n]) {
        const int p = atomicAdd(&cnts[1], 1);
        if (p < N1_CAP) { list2[p] = n; idx2[n] = p; } else idx2[n] = 0;
    }
    if (fL2[n]) {
        const int p = atomicAdd(&cnts[2], 1);
        if (p < 256) list0[p] = n;
    }
}

// ---------------- fused setup: weight transpose (8) + bias pack + gathered cvt ----------------
// WtFl block z = l*4 + sel2; sel2: 0=w_src_calls 1=w_src_cb 2=w_dst_calls 3=w_dst_cb
// pb[l][c]: c/768 = same sel2 order.
__global__ __launch_bounds__(256) void setup_kernel(const float* __restrict__ w_sc,
                                                    const float* __restrict__ w_dc,
                                                    const float* __restrict__ w_scb,
                                                    const float* __restrict__ w_dcb,
                                                    const float* __restrict__ b_sc,
                                                    const float* __restrict__ b_dc,
                                                    const float* __restrict__ b_scb,
                                                    const float* __restrict__ b_dcb,
                                                    const float* __restrict__ feats,
                                                    const int* __restrict__ list,
                                                    const int* __restrict__ pcnt,
                                                    bf16* __restrict__ WtFl,
                                                    float* __restrict__ pb,
                                                    bf16* __restrict__ h) {
    __shared__ float tile[32][33];
    const int b = blockIdx.x;
    const int t = threadIdx.x;
    if (b < TWT_BLOCKS) {
        const int z = b / 576, cell = b % 576;
        const int l = z >> 2, sel2 = z & 3;
        const float* src;
        if (sel2 == 0) src = w_sc; else if (sel2 == 1) src = w_scb;
        else if (sel2 == 2) src = w_dc; else src = w_dcb;
        src += (size_t)l * FDIM * FDIM;
        bf16* dst = WtFl + (size_t)z * FDIM * FDIM;
        const int tx = t & 31, ty = t >> 5;
        const int x0 = (cell % 24) * 32, y0 = (cell / 24) * 32;
#pragma unroll
        for (int q = 0; q < 4; ++q)
            tile[ty + q * 8][tx] = src[(size_t)(y0 + ty + q * 8) * FDIM + x0 + tx];
        __syncthreads();
#pragma unroll
        for (int q = 0; q < 4; ++q)
            dst[(size_t)(x0 + ty + q * 8) * FDIM + y0 + tx] = __float2bfloat16(tile[tx][ty + q * 8]);
    } else if (b < TWT_BLOCKS + BIAS_BLOCKS) {
        const int idx = (b - TWT_BLOCKS) * 256 + t;  // < 6144
        const int l = idx / NFUSE, c = idx % NFUSE;
        const int sel2 = c / FDIM, off = c % FDIM;
        const float* src;
        if (sel2 == 0) src = b_sc; else if (sel2 == 1) src = b_scb;
        else if (sel2 == 2) src = b_dc; else src = b_dcb;
        pb[idx] = src[l * FDIM + off];
    } else {
        int c = *pcnt; if (c > A1_CAP) c = A1_CAP;
        for (int i = b - TWT_BLOCKS - BIAS_BLOCKS; i < c; i += CVT_BLOCKS) {
            const int n = list[i];
            const float* s = feats + (size_t)n * FDIM;
            bf16* d = h + (size_t)n * FDIM;
            for (int k = t; k < FDIM; k += 256) d[k] = __float2bfloat16(s[k]);
        }
    }
}

// ---------------- two-job pipelined MFMA GEMM ----------------
// Job A (blocks [0,blocksA)): rows rlA, cols [0:1536)   (fs half)
// Job B (rest):               rows rlB, cols [1536:3072) (fd half)
// C row = idxmap[node] (compact); Wt/pb are layer-base pointers.
#define NKT 12  // 768/64

__global__ __launch_bounds__(512, 1) void gemm2(const bf16* __restrict__ A,
                                                const bf16* __restrict__ Wt,
                                                const float* __restrict__ pb,
                                                bf16* __restrict__ C,
                                                const int* __restrict__ rlA,
                                                const int* __restrict__ cntAp, int capA,
                                                const int* __restrict__ rlB,
                                                const int* __restrict__ cntBp, int capB,
                                                const int* __restrict__ idxmap,
                                                int blocksA) {
    int bid = blockIdx.x;
    const int* rowlist;
    int cnt, col0;
    if (bid < blocksA) {
        rowlist = rlA; cnt = *cntAp; if (cnt > capA) cnt = capA; col0 = 0;
    } else {
        bid -= blocksA;
        rowlist = rlB; cnt = *cntBp; if (cnt > capB) cnt = capB; col0 = 1536;
    }
    const int tm = bid / 6, tn = bid % 6;
    const int m0 = tm * 256, n0 = tn * 256;
    if (m0 >= cnt) return;

    __shared__ __align__(16) short lds[2][2][2][8192];
    const int t = threadIdx.x;
    const int wid = t >> 6, lane = t & 63;
    const int wr = wid >> 2, wc = wid & 3;
    const int lr = lane & 15, lk = lane >> 4;

    const f32x4 zero4 = {0.f, 0.f, 0.f, 0.f};
    f32x4 acc[8][4];
#pragma unroll
    for (int i = 0; i < 8; ++i)
#pragma unroll
        for (int j = 0; j < 4; ++j) acc[i][j] = zero4;

    const int scol_sw = (((lane & 3) ^ ((lane >> 3) & 3)) << 3);
    int arow[2], brow[2], dstq[2];
#pragma unroll
    for (int q = 0; q < 2; ++q) {
        int rr = m0 + wid * 32 + q * 16 + (lane >> 2);
        if (rr >= cnt) rr = cnt - 1;
        arow[q] = rowlist[rr];
        brow[q] = col0 + n0 + wid * 32 + q * 16 + (lane >> 2);
        dstq[q] = wid * 2048 + q * 1024;
    }
    const int rsw = ((lk ^ ((lr >> 1) & 3)) << 3);
    const int abase = wr * 128 + lr;
    const int bbase = wc * 64 + lr;

#define STG_A(d, kh, kt) {                                                                  \
        load_lds16(A + (size_t)arow[0] * FDIM + (kt) * 64 + (kh) * 32 + scol_sw,            \
                   (char*)&lds[d][0][kh][0] + dstq[0]);                                     \
        load_lds16(A + (size_t)arow[1] * FDIM + (kt) * 64 + (kh) * 32 + scol_sw,            \
                   (char*)&lds[d][0][kh][0] + dstq[1]); }
#define STG_B(d, kh, kt) {                                                                  \
        load_lds16(Wt + (size_t)brow[0] * FDIM + (kt) * 64 + (kh) * 32 + scol_sw,           \
                   (char*)&lds[d][1][kh][0] + dstq[0]);                                     \
        load_lds16(Wt + (size_t)brow[1] * FDIM + (kt) * 64 + (kh) * 32 + scol_sw,           \
                   (char*)&lds[d][1][kh][0] + dstq[1]); }

    STG_A(0, 0, 0); STG_B(0, 0, 0); STG_A(0, 1, 0); STG_B(0, 1, 0);
    asm volatile("s_waitcnt vmcnt(4)");
    __builtin_amdgcn_s_barrier();
    __builtin_amdgcn_sched_barrier(0);

    int db = 0;
    for (int j = 0; j < NKT; ++j) {
        const int nd = db ^ 1;
        const bool st = (j + 1) < NKT;
        const short* Ak0 = &lds[db][0][0][0];
        const short* Bk0 = &lds[db][1][0][0];
        const short* Ak1 = &lds[db][0][1][0];
        const short* Bk1 = &lds[db][1][1][0];
        bf16x8 av[4], bv[4], av2[4];

        // P1
#pragma unroll
        for (int i = 0; i < 4; ++i) av[i] = *(const bf16x8*)&Ak0[(abase + i * 16) * 32 + rsw];
#pragma unroll
        for (int jj = 0; jj < 4; ++jj) bv[jj] = *(const bf16x8*)&Bk0[(bbase + jj * 16) * 32 + rsw];
        if (st) STG_A(nd, 0, j + 1);
        __builtin_amdgcn_s_barrier();
        asm volatile("s_waitcnt lgkmcnt(0)");
        __builtin_amdgcn_sched_barrier(0);
        __builtin_amdgcn_s_setprio(1);
#pragma unroll
        for (int i = 0; i < 4; ++i)
#pragma unroll
            for (int jj = 0; jj < 4; ++jj)
                acc[i][jj] = __builtin_amdgcn_mfma_f32_16x16x32_bf16(bv[jj], av[i], acc[i][jj], 0, 0, 0);
        __builtin_amdgcn_s_setprio(0);
        __builtin_amdgcn_s_barrier();
        __builtin_amdgcn_sched_barrier(0);

        // P2
#pragma unroll
        for (int i = 0; i < 4; ++i) av2[i] = *(const bf16x8*)&Ak0[(abase + (4 + i) * 16) * 32 + rsw];
        if (st) STG_B(nd, 0, j + 1);
        __builtin_amdgcn_s_barrier();
        asm volatile("s_waitcnt lgkmcnt(0)");
        __builtin_amdgcn_sched_barrier(0);
        __builtin_amdgcn_s_setprio(1);
#pragma unroll
        for (int i = 0; i < 4; ++i)
#pragma unroll
            for (int jj = 0; jj < 4; ++jj)
                acc[4 + i][jj] = __builtin_amdgcn_mfma_f32_16x16x32_bf16(bv[jj], av2[i], acc[4 + i][jj], 0, 0, 0);
        __builtin_amdgcn_s_setprio(0);
        if (st) { asm volatile("s_waitcnt vmcnt(4)"); }
        else    { asm volatile("s_waitcnt vmcnt(0)"); }
        __builtin_amdgcn_s_barrier();
        __builtin_amdgcn_sched_barrier(0);

        // P3
#pragma unroll
        for (int i = 0; i < 4; ++i) av[i] = *(const bf16x8*)&Ak1[(abase + i * 16) * 32 + rsw];
#pragma unroll
        for (int jj = 0; jj < 4; ++jj) bv[jj] = *(const bf16x8*)&Bk1[(bbase + jj * 16) * 32 + rsw];
        if (st) STG_A(nd, 1, j + 1);
        __builtin_amdgcn_s_barrier();
        asm volatile("s_waitcnt lgkmcnt(0)");
        __builtin_amdgcn_sched_barrier(0);
        __builtin_amdgcn_s_setprio(1);
#pragma unroll
        for (int i = 0; i < 4; ++i)
#pragma unroll
            for (int jj = 0; jj < 4; ++jj)
                acc[i][jj] = __builtin_amdgcn_mfma_f32_16x16x32_bf16(bv[jj], av[i], acc[i][jj], 0, 0, 0);
        __builtin_amdgcn_s_setprio(0);
        __builtin_amdgcn_s_barrier();
        __builtin_amdgcn_sched_barrier(0);

        // P4
#pragma unroll
        for (int i = 0; i < 4; ++i) av2[i] = *(const bf16x8*)&Ak1[(abase + (4 + i) * 16) * 32 + rsw];
        if (st) STG_B(nd, 1, j + 1);
        __builtin_amdgcn_s_barrier();
        asm volatile("s_waitcnt lgkmcnt(0)");
        __builtin_amdgcn_sched_barrier(0);
        __builtin_amdgcn_s_setprio(1);
#pragma unroll
        for (int i = 0; i < 4; ++i)
#pragma unroll
            for (int jj = 0; jj < 4; ++jj)
                acc[4 + i][jj] = __builtin_amdgcn_mfma_f32_16x16x32_bf16(bv[jj], av2[i], acc[4 + i][jj], 0, 0, 0);
        __builtin_amdgcn_s_setprio(0);
        if (st) { asm volatile("s_waitcnt vmcnt(4)"); }
        __builtin_amdgcn_s_barrier();
        __builtin_amdgcn_sched_barrier(0);

        db = nd;
    }
#undef STG_A
#undef STG_B

#pragma unroll
    for (int i = 0; i < 8; ++i) {
        const int row = m0 + wr * 128 + i * 16 + lr;
        if (row < cnt) {
            const int crow = idxmap[rowlist[row]];
#pragma unroll
            for (int jj = 0; jj < 4; ++jj) {
                const int col = col0 + n0 + wc * 64 + jj * 16 + lk * 4;
                const float4 b4 = *(const float4*)(pb + col);
                ushort4 w;
                w.x = f2u(acc[i][jj][0] + b4.x);
                w.y = f2u(acc[i][jj][1] + b4.y);
                w.z = f2u(acc[i][jj][2] + b4.z);
                w.w = f2u(acc[i][jj][3] + b4.w);
                *(ushort4*)(C + (size_t)crow * NFUSE + col) = w;
            }
        }
    }
}

// ---------------- CSR build (both relations, parallel scan) ----------------
__global__ __launch_bounds__(256) void hist2_kernel(const int* __restrict__ dst0,
                                                    const int* __restrict__ dst1,
                                                    int* __restrict__ deg) {
    const int e = blockIdx.x * 256 + threadIdx.x;
    const int r = blockIdx.y;
    if (e < NE) atomicAdd(&deg[(size_t)r * N_NODES + (r ? dst1 : dst0)[e]], 1);
}

__global__ __launch_bounds__(256) void scan1_kernel(const int* __restrict__ deg,
                                                    int* __restrict__ bsum) {
    const int r = blockIdx.y, b = blockIdx.x, t = threadIdx.x;
    const int i = b * 256 + t;
    __shared__ int s[256];
    s[t] = (i < N_NODES) ? deg[(size_t)r * N_NODES + i] : 0;
    __syncthreads();
    for (int o = 128; o > 0; o >>= 1) {
        if (t < o) s[t] += s[t + o];
        __syncthreads();
    }
    if (t == 0) bsum[r * NBLK + b] = s[0];
}

__global__ __launch_bounds__(256) void scan2_kernel(int* __restrict__ bsum,
                                                    int* __restrict__ boff,
                                                    int* __restrict__ rowp0,
                                                    int* __restrict__ rowp1) {
    const int t = threadIdx.x;
    if (t < 2) {
        int run = 0;
        for (int b = 0; b < NBLK; ++b) {
            boff[t * NBLK + b] = run;
            run += bsum[t * NBLK + b];
        }
    }
    if (t == 0) rowp0[N_NODES] = NE;
    if (t == 1) rowp1[N_NODES] = NE;
}

__global__ __launch_bounds__(256) void scan3_kernel(const int* __restrict__ deg,
                                                    const int* __restrict__ boff,
                                                    int* __restrict__ rowp0, int* __restrict__ cursor0,
                                                    int* __restrict__ rowp1, int* __restrict__ cursor1) {
    const int r = blockIdx.y, b = blockIdx.x, t = threadIdx.x;
    const int i = b * 256 + t;
    int* rowp = r ? rowp1 : rowp0;
    int* cursor = r ? cursor1 : cursor0;
    __shared__ int s[256];
    const int v = (i < N_NODES) ? deg[(size_t)r * N_NODES + i] : 0;
    s[t] = v;
    __syncthreads();
    for (int o = 1; o < 256; o <<= 1) {
        int x = 0;
        if (t >= o) x = s[t - o];
        __syncthreads();
        if (t >= o) s[t] += x;
        __syncthreads();
    }
    if (i < N_NODES) {
        const int p = boff[r * NBLK + b] + s[t] - v;
        rowp[i] = p;
        cursor[i] = p;
    }
}

__global__ __launch_bounds__(256) void scatter2_kernel(const int* __restrict__ dst0,
                                                       const int* __restrict__ dst1,
                                                       int* __restrict__ cursor0,
                                                       int* __restrict__ cursor1,
                                                       int* __restrict__ eid0,
                                                       int* __restrict__ eid1) {
    const int e = blockIdx.x * 256 + threadIdx.x;
    const int r = blockIdx.y;
    if (e < NE) {
        if (r == 0) { const int p = atomicAdd(&cursor0[dst0[e]], 1); eid0[p] = e; }
        else        { const int p = atomicAdd(&cursor1[dst1[e]], 1); eid1[p] = e; }
    }
}

// ---------------- per-relation online-softmax attention ----------------
__device__ inline void att_accum(const bf16* __restrict__ fsd, const int* __restrict__ idx,
                                 int n, int lane, const float* __restrict__ attn,
                                 const int* __restrict__ rowp, const int* __restrict__ eid,
                                 const int* __restrict__ src, int fs_off, int fd_off,
                                 float* __restrict__ out) {
    float fdv[12], atv[12];
    {
        const ushort4* pfd = (const ushort4*)(fsd + (size_t)idx[n] * NFUSE + fd_off + lane * 12);
        const ushort4 d0 = pfd[0], d1 = pfd[1], d2 = pfd[2];
        fdv[0] = u2f(d0.x); fdv[1] = u2f(d0.y); fdv[2] = u2f(d0.z); fdv[3] = u2f(d0.w);
        fdv[4] = u2f(d1.x); fdv[5] = u2f(d1.y); fdv[6] = u2f(d1.z); fdv[7] = u2f(d1.w);
        fdv[8] = u2f(d2.x); fdv[9] = u2f(d2.y); fdv[10] = u2f(d2.z); fdv[11] = u2f(d2.w);
        const float4* pat = (const float4*)(attn + lane * 12);
        const float4 a0 = pat[0], a1 = pat[1], a2 = pat[2];
        atv[0] = a0.x; atv[1] = a0.y; atv[2] = a0.z; atv[3] = a0.w;
        atv[4] = a1.x; atv[5] = a1.y; atv[6] = a1.z; atv[7] = a1.w;
        atv[8] = a2.x; atv[9] = a2.y; atv[10] = a2.z; atv[11] = a2.w;
    }
    const int beg = rowp[n], end = rowp[n + 1];
    float m = -INFINITY, den = 0.f;
    float acc[12];
#pragma unroll
    for (int j = 0; j < 12; ++j) acc[j] = 0.f;

    for (int i = beg; i < end; ++i) {
        const int e = eid[i];
        const ushort4* pf = (const ushort4*)(fsd + (size_t)idx[src[e]] * NFUSE + fs_off + lane * 12);
        const ushort4 a0 = pf[0], a1 = pf[1], a2 = pf[2];
        float fsv[12];
        fsv[0] = u2f(a0.x); fsv[1] = u2f(a0.y); fsv[2] = u2f(a0.z); fsv[3] = u2f(a0.w);
        fsv[4] = u2f(a1.x); fsv[5] = u2f(a1.y); fsv[6] = u2f(a1.z); fsv[7] = u2f(a1.w);
        fsv[8] = u2f(a2.x); fsv[9] = u2f(a2.y); fsv[10] = u2f(a2.z); fsv[11] = u2f(a2.w);
        float p = 0.f;
#pragma unroll
        for (int j = 0; j < 12; ++j) {
            float x = fsv[j] + fdv[j];
            x = (x > 0.f) ? x : 0.2f * x;
            p += x * atv[j];
        }
        p += __shfl_xor(p, 1);
        p += __shfl_xor(p, 2);
        p += __shfl_xor(p, 4);
        if (p > m) {
            const float sc = expf(m - p);
            den *= sc;
#pragma unroll
            for (int j = 0; j < 12; ++j) acc[j] *= sc;
            m = p;
        }
        const float w = expf(p - m);
        den += w;
#pragma unroll
        for (int j = 0; j < 12; ++j) acc[j] += w * fsv[j];
    }
    const float inv = (den > 0.f) ? 1.f / den : 0.f;
#pragma unroll
    for (int j = 0; j < 12; ++j) out[j] = acc[j] * inv;
}

// fsd col layout: [fs_calls | fs_cb | fd_calls | fd_cb] at 0,768,1536,2304
__global__ __launch_bounds__(256) void aggL_kernel(const bf16* __restrict__ fsd,
                                                   const int* __restrict__ idx,
                                                   const float* __restrict__ attn0,
                                                   const float* __restrict__ attn1,
                                                   const int* __restrict__ rowp0,
                                                   const int* __restrict__ eid0,
                                                   const int* __restrict__ src0,
                                                   const int* __restrict__ rowp1,
                                                   const int* __restrict__ eid1,
                                                   const int* __restrict__ src1,
                                                   bf16* __restrict__ h,
                                                   const int* __restrict__ list,
                                                   const int* __restrict__ pcnt,
                                                   int cap) {
    const int wid = threadIdx.x >> 6;
    const int lane = threadIdx.x & 63;
    int cnt = *pcnt; if (cnt > cap) cnt = cap;
    const int i = blockIdx.x * 4 + wid;
    if (i >= cnt) return;
    const int n = list[i];

    float a0[12], a1[12];
    att_accum(fsd, idx, n, lane, attn0, rowp0, eid0, src0, 0, 1536, a0);
    att_accum(fsd, idx, n, lane, attn1, rowp1, eid1, src1, 768, 2304, a1);

    const size_t base = (size_t)n * FDIM + lane * 12;
    const ushort4* ph = (const ushort4*)(h + base);
    const ushort4 h0 = ph[0], h1 = ph[1], h2 = ph[2];
    ushort4 r0, r1, r2;
    r0.x = f2u(u2f(h0.x) + a0[0] + a1[0]);  r0.y = f2u(u2f(h0.y) + a0[1] + a1[1]);
    r0.z = f2u(u2f(h0.z) + a0[2] + a1[2]);  r0.w = f2u(u2f(h0.w) + a0[3] + a1[3]);
    r1.x = f2u(u2f(h1.x) + a0[4] + a1[4]);  r1.y = f2u(u2f(h1.y) + a0[5] + a1[5]);
    r1.z = f2u(u2f(h1.z) + a0[6] + a1[6]);  r1.w = f2u(u2f(h1.w) + a0[7] + a1[7]);
    r2.x = f2u(u2f(h2.x) + a0[8] + a1[8]);  r2.y = f2u(u2f(h2.y) + a0[9] + a1[9]);
    r2.z = f2u(u2f(h2.z) + a0[10] + a1[10]); r2.w = f2u(u2f(h2.w) + a0[11] + a1[11]);
    ((ushort4*)(h + base))[0] = r0; ((ushort4*)(h + base))[1] = r1; ((ushort4*)(h + base))[2] = r2;
}

// ---------------- MLP head ----------------
__global__ __launch_bounds__(256) void head_kernel(const bf16* __restrict__ h,
                                                   const int* __restrict__ gsi,
                                                   const float* __restrict__ fc1w,
                                                   const float* __restrict__ fc1b,
                                                   const float* __restrict__ fc2w,
                                                   const float* __restrict__ fc2b,
                                                   float* __restrict__ out) {
    __shared__ float fe[FDIM];
    __shared__ float hid[256];
    const int b = blockIdx.x, t = threadIdx.x;
    const int node = gsi[b];
    for (int i = t; i < FDIM; i += 256) fe[i] = __bfloat162float(h[(size_t)node * FDIM + i]);
    __syncthreads();
    float acc = fc1b[t];
    for (int k = 0; k < FDIM; ++k) acc += fe[k] * fc1w[k * 256 + t];
    hid[t] = (acc > 0.f) ? acc : 0.f;
    __syncthreads();
    if (t < NC) {
        float acc2 = fc2b[t];
        for (int k = 0; k < 256; ++k) acc2 += hid[k] * fc2w[k * NC + t];
        out[1 + b * NC + t] = acc2;
    }
}

// ---------------- loss ----------------
__global__ __launch_bounds__(256) void loss_kernel(const float* __restrict__ logits,
                                                   const int* __restrict__ labels,
                                                   float* __restrict__ out) {
    __shared__ float red[256];
    const int b = threadIdx.x;
    float m = -INFINITY;
    for (int c = 0; c < NC; ++c) m = fmaxf(m, logits[b * NC + c]);
    float sum = 0.f;
    for (int c = 0; c < NC; ++c) sum += expf(logits[b * NC + c] - m);
    const float lse = m + logf(sum);
    const float ll = logits[b * NC + labels[b]];
    red[b] = lse - ll;
    __syncthreads();
    for (int s = 128; s > 0; s >>= 1) {
        if (b < s) red[b] += red[b + s];
        __syncthreads();
    }
    if (b == 0) out[0] = red[0] / (float)NB;
}

extern "C" void kernel_launch(void* const* d_in, const int* in_sizes, int n_in,
                              void* d_out, int out_size, void* d_ws, size_t ws_size,
                              hipStream_t stream) {
    const float* feats = (const float*)d_in[0];
    const float* fc1w  = (const float*)d_in[11];
    const float* fc1b  = (const float*)d_in[12];
    const float* fc2w  = (const float*)d_in[13];
    const float* fc2b  = (const float*)d_in[14];
    const int* src0    = (const int*)d_in[15];
    const int* dst0    = (const int*)d_in[16];
    const int* src1    = (const int*)d_in[17];
    const int* dst1    = (const int*)d_in[18];
    const int* gsi     = (const int*)d_in[19];
    const int* labels  = (const int*)d_in[20];

    const size_t NF = (size_t)N_NODES * FDIM;
    const size_t WSZ = (size_t)FDIM * FDIM;
    char* p = (char*)d_ws;
    bf16* h    = (bf16*)p;  p += NF * 2;
    bf16* fsd  = (bf16*)p;  p += (size_t)A1_CAP * NFUSE * 2;
    bf16* WtFl = (bf16*)p;  p += 8 * WSZ * 2;
    float* pb  = (float*)p; p += 2 * NFUSE * 4;
    int* flagL2 = (int*)p;  p += (size_t)N_NODES * 4;
    int* flagL1 = (int*)p;  p += (size_t)N_NODES * 4;
    int* flagA1 = (int*)p;  p += (size_t)N_NODES * 4;
    int* cnts   = (int*)p;  p += 64;
    const size_t flag_bytes = 3 * (size_t)N_NODES * 4 + 64;
    int* idx1  = (int*)p;   p += (size_t)N_NODES * 4;
    int* idx2  = (int*)p;   p += (size_t)N_NODES * 4;
    int* list1 = (int*)p;   p += (size_t)A1_CAP * 4;
    int* list2 = (int*)p;   p += (size_t)N1_CAP * 4;
    int* list0 = (int*)p;   p += 256 * 4;
    int* deg   = (int*)p;   p += 2 * (size_t)N_NODES * 4;
    int* bsum  = (int*)p;   p += 2 * NBLK * 4;
    int* boff  = (int*)p;   p += 2 * NBLK * 4;
    int* rowp0 = (int*)p;   p += ((size_t)N_NODES + 1) * 4 + 252;
    int* rowp1 = (int*)p;   p += ((size_t)N_NODES + 1) * 4 + 252;
    int* cursor0 = (int*)p; p += (size_t)N_NODES * 4;
    int* cursor1 = (int*)p; p += (size_t)N_NODES * 4;
    int* eid0  = (int*)p;   p += (size_t)NE * 4;
    int* eid1  = (int*)p;   p += (size_t)NE * 4;

    const int eb = (NE + 255) / 256;

    // --- receptive-field sets (2 fused passes) ---
    hipMemsetAsync(flagL2, 0, flag_bytes, stream);
    mark_gsi_kernel<<<1, 256, 0, stream>>>(gsi, flagL2, flagL1, flagA1);
    mark2_kernel<<<dim3(eb, 2), 256, 0, stream>>>(src0, dst0, src1, dst1, flagL2, flagL1, flagA1);
    mark2_kernel<<<dim3(eb, 2), 256, 0, stream>>>(src0, dst0, src1, dst1, flagL1, flagA1, (int*)nullptr);
    compact_kernel<<<(N_NODES + 255) / 256, 256, 0, stream>>>(
        flagA1, flagL1, flagL2, list1, idx1, list2, idx2, list0, cnts);

    // --- CSR (both relations, parallel scan) ---
    hipMemsetAsync(deg, 0, 2 * sizeof(int) * N_NODES, stream);
    hist2_kernel<<<dim3(eb, 2), 256, 0, stream>>>(dst0, dst1, deg);
    scan1_kernel<<<dim3(NBLK, 2), 256, 0, stream>>>(deg, bsum);
    scan2_kernel<<<1, 256, 0, stream>>>(bsum, boff, rowp0, rowp1);
    scan3_kernel<<<dim3(NBLK, 2), 256, 0, stream>>>(deg, boff, rowp0, cursor0, rowp1, cursor1);
    scatter2_kernel<<<dim3(eb, 2), 256, 0, stream>>>(dst0, dst1, cursor0, cursor1, eid0, eid1);

    // --- setup: weight transpose + bias pack + gathered cvt (one dispatch) ---
    setup_kernel<<<SETUP_BLOCKS, 256, 0, stream>>>(
        (const float*)d_in[1], (const float*)d_in[3], (const float*)d_in[6], (const float*)d_in[8],
        (const float*)d_in[2], (const float*)d_in[4], (const float*)d_in[7], (const float*)d_in[9],
        feats, list1, &cnts[0], WtFl, pb, h);

    const int blocksA0 = (A1_CAP / 256) * 6;   // 384
    const int blocksB0 = (N1_CAP / 256) * 6;   // 96
    const int blocksA1 = (N1_CAP / 256) * 6;   // 96
    const int blocksB1 = 6;

    // --- layer 0: fs over A1, fd over N1 (one dispatch) ---
    gemm2<<<blocksA0 + blocksB0, 512, 0, stream>>>(
        h, WtFl, pb, fsd,
        list1, &cnts[0], A1_CAP, list2, &cnts[1], N1_CAP, idx1, blocksA0);
    aggL_kernel<<<(N1_CAP + 3) / 4, 256, 0, stream>>>(
        fsd, idx1, (const float*)d_in[5], (const float*)d_in[10],
        rowp0, eid0, src0, rowp1, eid1, src1, h, list2, &cnts[1], N1_CAP);

    // --- layer 1: fs over N1, fd over S0 (one dispatch) ---
    gemm2<<<blocksA1 + blocksB1, 512, 0, stream>>>(
        h, WtFl + 4 * WSZ, pb + NFUSE, fsd,
        list2, &cnts[1], N1_CAP, list0, &cnts[2], 256, idx2, blocksA1);
    aggL_kernel<<<64, 256, 0, stream>>>(
        fsd, idx2, (const float*)d_in[5] + FDIM, (const float*)d_in[10] + FDIM,
        rowp0, eid0, src0, rowp1, eid1, src1, h, list0, &cnts[2], 256);

    head_kernel<<<NB, 256, 0, stream>>>(h, gsi, fc1w, fc1b, fc2w, fc2b, (float*)d_out);
    loss_kernel<<<1, 256, 0, stream>>>((float*)d_out + 1, labels, (float*)d_out);
}

// Round 12
// 192.373 us; speedup vs baseline: 97.8218x; 1.1532x over previous
//
#include <hip/hip_runtime.h>
#include <hip/hip_bf16.h>
#include <math.h>

#define N_NODES 50000
#define NE      100000
#define FDIM    768
#define NFUSE   3072
#define NB      256
#define NC      31

#define A1_CAP  16384
#define N1_CAP  4096
#define NBLK    ((N_NODES + 255) / 256)   // 196
#define EB      ((NE + 255) / 256)        // 391
#define GTN     12                        // 1536/128 col-tiles per job

// setup kernel partition
#define TWT_BLOCKS  (8 * 576)
#define BIAS_BLOCKS 24
#define CVT_BLOCKS  512
#define SETUP_BLOCKS (TWT_BLOCKS + BIAS_BLOCKS + CVT_BLOCKS)

typedef __hip_bfloat16 bf16;
typedef __attribute__((ext_vector_type(8))) short bf16x8;
typedef __attribute__((ext_vector_type(4))) float f32x4;

__device__ inline float u2f(unsigned short u) { return __uint_as_float(((unsigned int)u) << 16); }
__device__ inline unsigned short f2u(float f) { return __bfloat16_as_ushort(__float2bfloat16(f)); }

__device__ inline void load_lds16(const void* g, void* l) {
    __builtin_amdgcn_global_load_lds(
        (const __attribute__((address_space(1))) void*)g,
        (__attribute__((address_space(3))) void*)l, 16, 0, 0);
}

// ---------------- receptive-field construction ----------------
__global__ __launch_bounds__(256) void mark_gsi_kernel(const int* __restrict__ gsi,
                                                       int* __restrict__ fL2,
                                                       int* __restrict__ fL1,
                                                       int* __restrict__ fA1) {
    const int n = gsi[threadIdx.x];
    fL2[n] = 1; fL1[n] = 1; fA1[n] = 1;
}

__global__ __launch_bounds__(256) void mark2_kernel(const int* __restrict__ src0,
                                                    const int* __restrict__ dst0,
                                                    const int* __restrict__ src1,
                                                    const int* __restrict__ dst1,
                                                    const int* __restrict__ dflag,
                                                    int* __restrict__ f1,
                                                    int* __restrict__ f2) {
    const int e = blockIdx.x * 256 + threadIdx.x;
    if (e >= NE) return;
    const int* src = blockIdx.y ? src1 : src0;
    const int* dst = blockIdx.y ? dst1 : dst0;
    if (dflag[dst[e]]) {
        const int s = src[e];
        f1[s] = 1;
        if (f2) f2[s] = 1;
    }
}

// ---------------- merged compact (node part) + hist (edge part) ----------------
__global__ __launch_bounds__(256) void comphist_kernel(const int* __restrict__ fA1,
                                                       const int* __restrict__ fL1,
                                                       const int* __restrict__ fL2,
                                                       int* __restrict__ list1, int* __restrict__ idx1,
                                                       int* __restrict__ list2, int* __restrict__ idx2,
                                                       int* __restrict__ list0,
                                                       int* __restrict__ cnts,
                                                       const int* __restrict__ dst0,
                                                       const int* __restrict__ dst1,
                                                       int* __restrict__ deg) {
    const int b = blockIdx.x, t = threadIdx.x;
    if (b < NBLK) {
        const int n = b * 256 + t;
        if (n >= N_NODES) return;
        if (fA1[n]) {
            const int p = atomicAdd(&cnts[0], 1);
            if (p < A1_CAP) { list1[p] = n; idx1[n] = p; } else idx1[n] = 0;
        }
        if (fL1[n]) {
            const int p = atomicAdd(&cnts[1], 1);
            if (p < N1_CAP) { list2[p] = n; idx2[n] = p; } else idx2[n] = 0;
        }
        if (fL2[n]) {
            const int p = atomicAdd(&cnts[2], 1);
            if (p < 256) list0[p] = n;
        }
    } else {
        const int eb_id = b - NBLK;
        const int r = (eb_id >= EB) ? 1 : 0;
        const int e = (eb_id - r * EB) * 256 + t;
        if (e < NE) atomicAdd(&deg[(size_t)r * N_NODES + (r ? dst1 : dst0)[e]], 1);
    }
}

// ---------------- fused setup: weight transpose (8) + bias pack + gathered cvt ----------------
__global__ __launch_bounds__(256) void setup_kernel(const float* __restrict__ w_sc,
                                                    const float* __restrict__ w_dc,
                                                    const float* __restrict__ w_scb,
                                                    const float* __restrict__ w_dcb,
                                                    const float* __restrict__ b_sc,
                                                    const float* __restrict__ b_dc,
                                                    const float* __restrict__ b_scb,
                                                    const float* __restrict__ b_dcb,
                                                    const float* __restrict__ feats,
                                                    const int* __restrict__ list,
                                                    const int* __restrict__ pcnt,
                                                    bf16* __restrict__ WtFl,
                                                    float* __restrict__ pb,
                                                    bf16* __restrict__ h) {
    __shared__ float tile[32][33];
    const int b = blockIdx.x;
    const int t = threadIdx.x;
    if (b < TWT_BLOCKS) {
        const int z = b / 576, cell = b % 576;
        const int l = z >> 2, sel2 = z & 3;
        const float* src;
        if (sel2 == 0) src = w_sc; else if (sel2 == 1) src = w_scb;
        else if (sel2 == 2) src = w_dc; else src = w_dcb;
        src += (size_t)l * FDIM * FDIM;
        bf16* dst = WtFl + (size_t)z * FDIM * FDIM;
        const int tx = t & 31, ty = t >> 5;
        const int x0 = (cell % 24) * 32, y0 = (cell / 24) * 32;
#pragma unroll
        for (int q = 0; q < 4; ++q)
            tile[ty + q * 8][tx] = src[(size_t)(y0 + ty + q * 8) * FDIM + x0 + tx];
        __syncthreads();
#pragma unroll
        for (int q = 0; q < 4; ++q)
            dst[(size_t)(x0 + ty + q * 8) * FDIM + y0 + tx] = __float2bfloat16(tile[tx][ty + q * 8]);
    } else if (b < TWT_BLOCKS + BIAS_BLOCKS) {
        const int idx = (b - TWT_BLOCKS) * 256 + t;
        const int l = idx / NFUSE, c = idx % NFUSE;
        const int sel2 = c / FDIM, off = c % FDIM;
        const float* src;
        if (sel2 == 0) src = b_sc; else if (sel2 == 1) src = b_scb;
        else if (sel2 == 2) src = b_dc; else src = b_dcb;
        pb[idx] = src[l * FDIM + off];
    } else {
        int c = *pcnt; if (c > A1_CAP) c = A1_CAP;
        for (int i = b - TWT_BLOCKS - BIAS_BLOCKS; i < c; i += CVT_BLOCKS) {
            const int n = list[i];
            const float* s = feats + (size_t)n * FDIM;
            bf16* d = h + (size_t)n * FDIM;
            for (int k = t; k < FDIM; k += 256) d[k] = __float2bfloat16(s[k]);
        }
    }
}

// ---------------- two-job 128x128 MFMA GEMM (m97 structure, latency-optimized) ----------------
// Job A (blocks [0,blocksA)): rows rlA, cols [0:1536)   (fs half)
// Job B (rest):               rows rlB, cols [1536:3072) (fd half)
// C row = idxmap[node] (compact). Wt/pb are layer-base pointers.
__global__ __launch_bounds__(256) void gemm2(const bf16* __restrict__ A,
                                             const bf16* __restrict__ Wt,
                                             const float* __restrict__ pb,
                                             bf16* __restrict__ C,
                                             const int* __restrict__ rlA,
                                             const int* __restrict__ cntAp, int capA,
                                             const int* __restrict__ rlB,
                                             const int* __restrict__ cntBp, int capB,
                                             const int* __restrict__ idxmap,
                                             int blocksA) {
    int bid = blockIdx.x;
    const int* rowlist;
    int cnt, col0;
    if (bid < blocksA) {
        rowlist = rlA; cnt = *cntAp; if (cnt > capA) cnt = capA; col0 = 0;
    } else {
        bid -= blocksA;
        rowlist = rlB; cnt = *cntBp; if (cnt > capB) cnt = capB; col0 = 1536;
    }
    const int tm = bid / GTN, tn = bid % GTN;
    const int m0 = tm * 128, n0 = tn * 128;
    if (m0 >= cnt) return;

    __shared__ __align__(16) short Abuf[128 * 64];  // 16 KB
    __shared__ __align__(16) short Bbuf[128 * 64];  // 16 KB
    const int t = threadIdx.x;
    const int wid = t >> 6, lane = t & 63;
    const int wr = wid >> 1, wc = wid & 1;
    const int lr = lane & 15, lk = lane >> 4;

    const f32x4 zero4 = {0.f, 0.f, 0.f, 0.f};
    f32x4 acc[4][4];
#pragma unroll
    for (int i = 0; i < 4; ++i)
#pragma unroll
        for (int j = 0; j < 4; ++j) acc[i][j] = zero4;

    // staging slots: s = i*256+t -> row rr=s>>3, chunk p=s&7; source chunk p^(rr&7)
    int arow[4], brow[4], acol[4], ldsoff[4];
#pragma unroll
    for (int i = 0; i < 4; ++i) {
        const int s = i * 256 + t;
        const int rr = s >> 3, pch = s & 7;
        int ri = m0 + rr; if (ri >= cnt) ri = cnt - 1;
        arow[i] = rowlist[ri];
        brow[i] = col0 + n0 + rr;
        acol[i] = (pch ^ (rr & 7)) << 3;
        ldsoff[i] = (i * 256 + wid * 64) * 16;
    }

    for (int kt = 0; kt < FDIM / 64; ++kt) {
        const int k0 = kt * 64;
#pragma unroll
        for (int i = 0; i < 4; ++i) {
            load_lds16(A + (size_t)arow[i] * FDIM + k0 + acol[i], (char*)Abuf + ldsoff[i]);
            load_lds16(Wt + (size_t)brow[i] * FDIM + k0 + acol[i], (char*)Bbuf + ldsoff[i]);
        }
        __syncthreads();
#pragma unroll
        for (int kh = 0; kh < 2; ++kh) {
            bf16x8 av[4], bv[4];
            const int c = kh * 4 + lk;
#pragma unroll
            for (int i = 0; i < 4; ++i) {
                const int mm = wr * 64 + i * 16 + lr;
                av[i] = *(const bf16x8*)((const char*)Abuf + mm * 128 + ((c ^ (mm & 7)) << 4));
            }
#pragma unroll
            for (int j = 0; j < 4; ++j) {
                const int nn = wc * 64 + j * 16 + lr;
                bv[j] = *(const bf16x8*)((const char*)Bbuf + nn * 128 + ((c ^ (nn & 7)) << 4));
            }
            // swapped operands: lane owns row m=..+lr, cols n=..+lk*4+reg
#pragma unroll
            for (int i = 0; i < 4; ++i)
#pragma unroll
                for (int j = 0; j < 4; ++j)
                    acc[i][j] = __builtin_amdgcn_mfma_f32_16x16x32_bf16(bv[j], av[i], acc[i][j], 0, 0, 0);
        }
        __syncthreads();
    }

#pragma unroll
    for (int i = 0; i < 4; ++i) {
        const int row = m0 + wr * 64 + i * 16 + lr;
        if (row < cnt) {
            const int crow = idxmap[rowlist[row]];
#pragma unroll
            for (int j = 0; j < 4; ++j) {
                const int col = col0 + n0 + wc * 64 + j * 16 + lk * 4;
                const float4 b4 = *(const float4*)(pb + col);
                ushort4 w;
                w.x = f2u(acc[i][j][0] + b4.x);
                w.y = f2u(acc[i][j][1] + b4.y);
                w.z = f2u(acc[i][j][2] + b4.z);
                w.w = f2u(acc[i][j][3] + b4.w);
                *(ushort4*)(C + (size_t)crow * NFUSE + col) = w;
            }
        }
    }
}

// ---------------- CSR scan (parallel) + scatter ----------------
__global__ __launch_bounds__(256) void scan1_kernel(const int* __restrict__ deg,
                                                    int* __restrict__ bsum) {
    const int r = blockIdx.y, b = blockIdx.x, t = threadIdx.x;
    const int i = b * 256 + t;
    __shared__ int s[256];
    s[t] = (i < N_NODES) ? deg[(size_t)r * N_NODES + i] : 0;
    __syncthreads();
    for (int o = 128; o > 0; o >>= 1) {
        if (t < o) s[t] += s[t + o];
        __syncthreads();
    }
    if (t == 0) bsum[r * NBLK + b] = s[0];
}

__global__ __launch_bounds__(256) void scan2_kernel(int* __restrict__ bsum,
                                                    int* __restrict__ boff,
                                                    int* __restrict__ rowp0,
                                                    int* __restrict__ rowp1) {
    const int t = threadIdx.x;
    if (t < 2) {
        int run = 0;
        for (int b = 0; b < NBLK; ++b) {
            boff[t * NBLK + b] = run;
            run += bsum[t * NBLK + b];
        }
    }
    if (t == 0) rowp0[N_NODES] = NE;
    if (t == 1) rowp1[N_NODES] = NE;
}

__global__ __launch_bounds__(256) void scan3_kernel(const int* __restrict__ deg,
                                                    const int* __restrict__ boff,
                                                    int* __restrict__ rowp0, int* __restrict__ cursor0,
                                                    int* __restrict__ rowp1, int* __restrict__ cursor1) {
    const int r = blockIdx.y, b = blockIdx.x, t = threadIdx.x;
    const int i = b * 256 + t;
    int* rowp = r ? rowp1 : rowp0;
    int* cursor = r ? cursor1 : cursor0;
    __shared__ int s[256];
    const int v = (i < N_NODES) ? deg[(size_t)r * N_NODES + i] : 0;
    s[t] = v;
    __syncthreads();
    for (int o = 1; o < 256; o <<= 1) {
        int x = 0;
        if (t >= o) x = s[t - o];
        __syncthreads();
        if (t >= o) s[t] += x;
        __syncthreads();
    }
    if (i < N_NODES) {
        const int p = boff[r * NBLK + b] + s[t] - v;
        rowp[i] = p;
        cursor[i] = p;
    }
}

__global__ __launch_bounds__(256) void scatter2_kernel(const int* __restrict__ dst0,
                                                       const int* __restrict__ dst1,
                                                       int* __restrict__ cursor0,
                                                       int* __restrict__ cursor1,
                                                       int* __restrict__ eid0,
                                                       int* __restrict__ eid1) {
    const int e = blockIdx.x * 256 + threadIdx.x;
    const int r = blockIdx.y;
    if (e < NE) {
        if (r == 0) { const int p = atomicAdd(&cursor0[dst0[e]], 1); eid0[p] = e; }
        else        { const int p = atomicAdd(&cursor1[dst1[e]], 1); eid1[p] = e; }
    }
}

// ---------------- per-relation online-softmax attention ----------------
__device__ inline void att_accum(const bf16* __restrict__ fsd, const int* __restrict__ idx,
                                 int n, int lane, const float* __restrict__ attn,
                                 const int* __restrict__ rowp, const int* __restrict__ eid,
                                 const int* __restrict__ src, int fs_off, int fd_off,
                                 float* __restrict__ out) {
    float fdv[12], atv[12];
    {
        const ushort4* pfd = (const ushort4*)(fsd + (size_t)idx[n] * NFUSE + fd_off + lane * 12);
        const ushort4 d0 = pfd[0], d1 = pfd[1], d2 = pfd[2];
        fdv[0] = u2f(d0.x); fdv[1] = u2f(d0.y); fdv[2] = u2f(d0.z); fdv[3] = u2f(d0.w);
        fdv[4] = u2f(d1.x); fdv[5] = u2f(d1.y); fdv[6] = u2f(d1.z); fdv[7] = u2f(d1.w);
        fdv[8] = u2f(d2.x); fdv[9] = u2f(d2.y); fdv[10] = u2f(d2.z); fdv[11] = u2f(d2.w);
        const float4* pat = (const float4*)(attn + lane * 12);
        const float4 a0 = pat[0], a1 = pat[1], a2 = pat[2];
        atv[0] = a0.x; atv[1] = a0.y; atv[2] = a0.z; atv[3] = a0.w;
        atv[4] = a1.x; atv[5] = a1.y; atv[6] = a1.z; atv[7] = a1.w;
        atv[8] = a2.x; atv[9] = a2.y; atv[10] = a2.z; atv[11] = a2.w;
    }
    const int beg = rowp[n], end = rowp[n + 1];
    float m = -INFINITY, den = 0.f;
    float acc[12];
#pragma unroll
    for (int j = 0; j < 12; ++j) acc[j] = 0.f;

    for (int i = beg; i < end; ++i) {
        const int e = eid[i];
        const ushort4* pf = (const ushort4*)(fsd + (size_t)idx[src[e]] * NFUSE + fs_off + lane * 12);
        const ushort4 a0 = pf[0], a1 = pf[1], a2 = pf[2];
        float fsv[12];
        fsv[0] = u2f(a0.x); fsv[1] = u2f(a0.y); fsv[2] = u2f(a0.z); fsv[3] = u2f(a0.w);
        fsv[4] = u2f(a1.x); fsv[5] = u2f(a1.y); fsv[6] = u2f(a1.z); fsv[7] = u2f(a1.w);
        fsv[8] = u2f(a2.x); fsv[9] = u2f(a2.y); fsv[10] = u2f(a2.z); fsv[11] = u2f(a2.w);
        float p = 0.f;
#pragma unroll
        for (int j = 0; j < 12; ++j) {
            float x = fsv[j] + fdv[j];
            x = (x > 0.f) ? x : 0.2f * x;
            p += x * atv[j];
        }
        p += __shfl_xor(p, 1);
        p += __shfl_xor(p, 2);
        p += __shfl_xor(p, 4);
        if (p > m) {
            const float sc = expf(m - p);
            den *= sc;
#pragma unroll
            for (int j = 0; j < 12; ++j) acc[j] *= sc;
            m = p;
        }
        const float w = expf(p - m);
        den += w;
#pragma unroll
        for (int j = 0; j < 12; ++j) acc[j] += w * fsv[j];
    }
    const float inv = (den > 0.f) ? 1.f / den : 0.f;
#pragma unroll
    for (int j = 0; j < 12; ++j) out[j] = acc[j] * inv;
}

// fsd col layout: [fs_calls | fs_cb | fd_calls | fd_cb] at 0,768,1536,2304
__global__ __launch_bounds__(256) void aggL_kernel(const bf16* __restrict__ fsd,
                                                   const int* __restrict__ idx,
                                                   const float* __restrict__ attn0,
                                                   const float* __restrict__ attn1,
                                                   const int* __restrict__ rowp0,
                                                   const int* __restrict__ eid0,
                                                   const int* __restrict__ src0,
                                                   const int* __restrict__ rowp1,
                                                   const int* __restrict__ eid1,
                                                   const int* __restrict__ src1,
                                                   bf16* __restrict__ h,
                                                   const int* __restrict__ list,
                                                   const int* __restrict__ pcnt,
                                                   int cap) {
    const int wid = threadIdx.x >> 6;
    const int lane = threadIdx.x & 63;
    int cnt = *pcnt; if (cnt > cap) cnt = cap;
    const int i = blockIdx.x * 4 + wid;
    if (i >= cnt) return;
    const int n = list[i];

    float a0[12], a1[12];
    att_accum(fsd, idx, n, lane, attn0, rowp0, eid0, src0, 0, 1536, a0);
    att_accum(fsd, idx, n, lane, attn1, rowp1, eid1, src1, 768, 2304, a1);

    const size_t base = (size_t)n * FDIM + lane * 12;
    const ushort4* ph = (const ushort4*)(h + base);
    const ushort4 h0 = ph[0], h1 = ph[1], h2 = ph[2];
    ushort4 r0, r1, r2;
    r0.x = f2u(u2f(h0.x) + a0[0] + a1[0]);  r0.y = f2u(u2f(h0.y) + a0[1] + a1[1]);
    r0.z = f2u(u2f(h0.z) + a0[2] + a1[2]);  r0.w = f2u(u2f(h0.w) + a0[3] + a1[3]);
    r1.x = f2u(u2f(h1.x) + a0[4] + a1[4]);  r1.y = f2u(u2f(h1.y) + a0[5] + a1[5]);
    r1.z = f2u(u2f(h1.z) + a0[6] + a1[6]);  r1.w = f2u(u2f(h1.w) + a0[7] + a1[7]);
    r2.x = f2u(u2f(h2.x) + a0[8] + a1[8]);  r2.y = f2u(u2f(h2.y) + a0[9] + a1[9]);
    r2.z = f2u(u2f(h2.z) + a0[10] + a1[10]); r2.w = f2u(u2f(h2.w) + a0[11] + a1[11]);
    ((ushort4*)(h + base))[0] = r0; ((ushort4*)(h + base))[1] = r1; ((ushort4*)(h + base))[2] = r2;
}

// ---------------- MLP head ----------------
__global__ __launch_bounds__(256) void head_kernel(const bf16* __restrict__ h,
                                                   const int* __restrict__ gsi,
                                                   const float* __restrict__ fc1w,
                                                   const float* __restrict__ fc1b,
                                                   const float* __restrict__ fc2w,
                                                   const float* __restrict__ fc2b,
                                                   float* __restrict__ out) {
    __shared__ float fe[FDIM];
    __shared__ float hid[256];
    const int b = blockIdx.x, t = threadIdx.x;
    const int node = gsi[b];
    for (int i = t; i < FDIM; i += 256) fe[i] = __bfloat162float(h[(size_t)node * FDIM + i]);
    __syncthreads();
    float acc = fc1b[t];
    for (int k = 0; k < FDIM; ++k) acc += fe[k] * fc1w[k * 256 + t];
    hid[t] = (acc > 0.f) ? acc : 0.f;
    __syncthreads();
    if (t < NC) {
        float acc2 = fc2b[t];
        for (int k = 0; k < 256; ++k) acc2 += hid[k] * fc2w[k * NC + t];
        out[1 + b * NC + t] = acc2;
    }
}

// ---------------- loss ----------------
__global__ __launch_bounds__(256) void loss_kernel(const float* __restrict__ logits,
                                                   const int* __restrict__ labels,
                                                   float* __restrict__ out) {
    __shared__ float red[256];
    const int b = threadIdx.x;
    float m = -INFINITY;
    for (int c = 0; c < NC; ++c) m = fmaxf(m, logits[b * NC + c]);
    float sum = 0.f;
    for (int c = 0; c < NC; ++c) sum += expf(logits[b * NC + c] - m);
    const float lse = m + logf(sum);
    const float ll = logits[b * NC + labels[b]];
    red[b] = lse - ll;
    __syncthreads();
    for (int s = 128; s > 0; s >>= 1) {
        if (b < s) red[b] += red[b + s];
        __syncthreads();
    }
    if (b == 0) out[0] = red[0] / (float)NB;
}

extern "C" void kernel_launch(void* const* d_in, const int* in_sizes, int n_in,
                              void* d_out, int out_size, void* d_ws, size_t ws_size,
                              hipStream_t stream) {
    const float* feats = (const float*)d_in[0];
    const float* fc1w  = (const float*)d_in[11];
    const float* fc1b  = (const float*)d_in[12];
    const float* fc2w  = (const float*)d_in[13];
    const float* fc2b  = (const float*)d_in[14];
    const int* src0    = (const int*)d_in[15];
    const int* dst0    = (const int*)d_in[16];
    const int* src1    = (const int*)d_in[17];
    const int* dst1    = (const int*)d_in[18];
    const int* gsi     = (const int*)d_in[19];
    const int* labels  = (const int*)d_in[20];

    const size_t NF = (size_t)N_NODES * FDIM;
    const size_t WSZ = (size_t)FDIM * FDIM;
    char* p = (char*)d_ws;
    bf16* h    = (bf16*)p;  p += NF * 2;
    bf16* fsd  = (bf16*)p;  p += (size_t)A1_CAP * NFUSE * 2;
    bf16* WtFl = (bf16*)p;  p += 8 * WSZ * 2;
    float* pb  = (float*)p; p += 2 * NFUSE * 4;
    // contiguous zero-init region: flags (3N) + cnts (64) + deg (2N)
    int* flagL2 = (int*)p;  p += (size_t)N_NODES * 4;
    int* flagL1 = (int*)p;  p += (size_t)N_NODES * 4;
    int* flagA1 = (int*)p;  p += (size_t)N_NODES * 4;
    int* cnts   = (int*)p;  p += 64 * 4;
    int* deg    = (int*)p;  p += 2 * (size_t)N_NODES * 4;
    const size_t zero_bytes = (3 * (size_t)N_NODES + 64 + 2 * (size_t)N_NODES) * 4;
    int* idx1  = (int*)p;   p += (size_t)N_NODES * 4;
    int* idx2  = (int*)p;   p += (size_t)N_NODES * 4;
    int* list1 = (int*)p;   p += (size_t)A1_CAP * 4;
    int* list2 = (int*)p;   p += (size_t)N1_CAP * 4;
    int* list0 = (int*)p;   p += 256 * 4;
    int* bsum  = (int*)p;   p += 2 * NBLK * 4;
    int* boff  = (int*)p;   p += 2 * NBLK * 4;
    int* rowp0 = (int*)p;   p += ((size_t)N_NODES + 1) * 4 + 252;
    int* rowp1 = (int*)p;   p += ((size_t)N_NODES + 1) * 4 + 252;
    int* cursor0 = (int*)p; p += (size_t)N_NODES * 4;
    int* cursor1 = (int*)p; p += (size_t)N_NODES * 4;
    int* eid0  = (int*)p;   p += (size_t)NE * 4;
    int* eid1  = (int*)p;   p += (size_t)NE * 4;

    // --- receptive-field sets ---
    hipMemsetAsync(flagL2, 0, zero_bytes, stream);
    mark_gsi_kernel<<<1, 256, 0, stream>>>(gsi, flagL2, flagL1, flagA1);
    mark2_kernel<<<dim3(EB, 2), 256, 0, stream>>>(src0, dst0, src1, dst1, flagL2, flagL1, flagA1);
    mark2_kernel<<<dim3(EB, 2), 256, 0, stream>>>(src0, dst0, src1, dst1, flagL1, flagA1, (int*)nullptr);
    comphist_kernel<<<NBLK + 2 * EB, 256, 0, stream>>>(
        flagA1, flagL1, flagL2, list1, idx1, list2, idx2, list0, cnts, dst0, dst1, deg);

    // --- CSR scan + scatter ---
    scan1_kernel<<<dim3(NBLK, 2), 256, 0, stream>>>(deg, bsum);
    scan2_kernel<<<1, 256, 0, stream>>>(bsum, boff, rowp0, rowp1);
    scan3_kernel<<<dim3(NBLK, 2), 256, 0, stream>>>(deg, boff, rowp0, cursor0, rowp1, cursor1);
    scatter2_kernel<<<dim3(EB, 2), 256, 0, stream>>>(dst0, dst1, cursor0, cursor1, eid0, eid1);

    // --- setup: weight transpose + bias pack + gathered cvt ---
    setup_kernel<<<SETUP_BLOCKS, 256, 0, stream>>>(
        (const float*)d_in[1], (const float*)d_in[3], (const float*)d_in[6], (const float*)d_in[8],
        (const float*)d_in[2], (const float*)d_in[4], (const float*)d_in[7], (const float*)d_in[9],
        feats, list1, &cnts[0], WtFl, pb, h);

    const int blocksA0 = (A1_CAP / 128) * GTN;   // 1536
    const int blocksB0 = (N1_CAP / 128) * GTN;   // 384
    const int blocksA1 = (N1_CAP / 128) * GTN;   // 384
    const int blocksB1 = (256 / 128) * GTN;      // 24

    // --- layer 0: fs over A1, fd over N1 ---
    gemm2<<<blocksA0 + blocksB0, 256, 0, stream>>>(
        h, WtFl, pb, fsd,
        list1, &cnts[0], A1_CAP, list2, &cnts[1], N1_CAP, idx1, blocksA0);
    aggL_kernel<<<(N1_CAP + 3) / 4, 256, 0, stream>>>(
        fsd, idx1, (const float*)d_in[5], (const float*)d_in[10],
        rowp0, eid0, src0, rowp1, eid1, src1, h, list2, &cnts[1], N1_CAP);

    // --- layer 1: fs over N1, fd over S0 ---
    gemm2<<<blocksA1 + blocksB1, 256, 0, stream>>>(
        h, WtFl + 4 * WSZ, pb + NFUSE, fsd,
        list2, &cnts[1], N1_CAP, list0, &cnts[2], 256, idx2, blocksA1);
    aggL_kernel<<<64, 256, 0, stream>>>(
        fsd, idx2, (const float*)d_in[5] + FDIM, (const float*)d_in[10] + FDIM,
        rowp0, eid0, src0, rowp1, eid1, src1, h, list0, &cnts[2], 256);

    head_kernel<<<NB, 256, 0, stream>>>(h, gsi, fc1w, fc1b, fc2w, fc2b, (float*)d_out);
    loss_kernel<<<1, 256, 0, stream>>>((float*)d_out + 1, labels, (float*)d_out);
}

// Round 13
// 159.485 us; speedup vs baseline: 117.9945x; 1.2062x over previous
//
#include <hip/hip_runtime.h>
#include <hip/hip_bf16.h>
#include <math.h>

#define N_NODES 50000
#define NE      100000
#define FDIM    768
#define NFUSE   3072
#define NB      256
#define NC      31

#define A1_CAP  16384
#define N1_CAP  4096
#define NBLK    ((N_NODES + 255) / 256)   // 196
#define EB      ((NE + 255) / 256)        // 391
#define GTN     12                        // 1536/128 col-tiles per job

// setup kernel partition: twt + bias + cvt + hist
#define TWT_BLOCKS  (8 * 576)
#define BIAS_BLOCKS 24
#define CVT_BLOCKS  512
#define SETUP_BLOCKS (TWT_BLOCKS + BIAS_BLOCKS + CVT_BLOCKS)
#define SETUPH_BLOCKS (SETUP_BLOCKS + 2 * EB)

typedef __hip_bfloat16 bf16;
typedef __attribute__((ext_vector_type(8))) short bf16x8;
typedef __attribute__((ext_vector_type(4))) float f32x4;

__device__ inline float u2f(unsigned short u) { return __uint_as_float(((unsigned int)u) << 16); }
__device__ inline unsigned short f2u(float f) { return __bfloat16_as_ushort(__float2bfloat16(f)); }

__device__ inline void load_lds16(const void* g, void* l) {
    __builtin_amdgcn_global_load_lds(
        (const __attribute__((address_space(1))) void*)g,
        (__attribute__((address_space(3))) void*)l, 16, 0, 0);
}

// ---------------- markA: gsi dedupe/list0 + pass1 (dst in gsi via bsearch) ----------------
__global__ __launch_bounds__(256) void markA_kernel(const int* __restrict__ gsi,
                                                    const int* __restrict__ src0,
                                                    const int* __restrict__ dst0,
                                                    const int* __restrict__ src1,
                                                    const int* __restrict__ dst1,
                                                    int* __restrict__ fL1,
                                                    int* __restrict__ fA1,
                                                    int* __restrict__ list0,
                                                    int* __restrict__ cnts) {
    const int t = threadIdx.x, b = blockIdx.x;
    if (b == 0) {
        const int n = gsi[t];
        fL1[n] = 1; fA1[n] = 1;
        const bool first = (t == 0) || (gsi[t - 1] != n);
        if (first) {
            const int p = atomicAdd(&cnts[2], 1);
            if (p < 256) list0[p] = n;
        }
        return;
    }
    __shared__ int g[256];
    g[t] = gsi[t];
    __syncthreads();
    const int eb = b - 1;
    const int r = (eb >= EB) ? 1 : 0;
    const int e = (eb - r * EB) * 256 + t;
    if (e >= NE) return;
    const int d = (r ? dst1 : dst0)[e];
    int lo = 0, hi = 256;
    while (lo < hi) { const int mid = (lo + hi) >> 1; if (g[mid] < d) lo = mid + 1; else hi = mid; }
    if (lo < 256 && g[lo] == d) {
        const int s = (r ? src1 : src0)[e];
        fL1[s] = 1; fA1[s] = 1;
    }
}

// ---------------- markB: pass2 (dst in fL1 -> fA1[src]) ----------------
__global__ __launch_bounds__(256) void markB_kernel(const int* __restrict__ src0,
                                                    const int* __restrict__ dst0,
                                                    const int* __restrict__ src1,
                                                    const int* __restrict__ dst1,
                                                    const int* __restrict__ fL1,
                                                    int* __restrict__ fA1) {
    const int e = blockIdx.x * 256 + threadIdx.x;
    if (e >= NE) return;
    const int r = blockIdx.y;
    if (fL1[(r ? dst1 : dst0)[e]]) fA1[(r ? src1 : src0)[e]] = 1;
}

// ---------------- compact ----------------
__global__ __launch_bounds__(256) void compact_kernel(const int* __restrict__ fA1,
                                                      const int* __restrict__ fL1,
                                                      int* __restrict__ list1, int* __restrict__ idx1,
                                                      int* __restrict__ list2, int* __restrict__ idx2,
                                                      int* __restrict__ cnts) {
    const int n = blockIdx.x * 256 + threadIdx.x;
    if (n >= N_NODES) return;
    if (fA1[n]) {
        const int p = atomicAdd(&cnts[0], 1);
        if (p < A1_CAP) { list1[p] = n; idx1[n] = p; } else idx1[n] = 0;
    }
    if (fL1[n]) {
        const int p = atomicAdd(&cnts[1], 1);
        if (p < N1_CAP) { list2[p] = n; idx2[n] = p; } else idx2[n] = 0;
    }
}

// ---------------- setup (+ active hist): twt8 | bias | cvt | hist ----------------
__global__ __launch_bounds__(256) void setup_kernel(const float* __restrict__ w_sc,
                                                    const float* __restrict__ w_dc,
                                                    const float* __restrict__ w_scb,
                                                    const float* __restrict__ w_dcb,
                                                    const float* __restrict__ b_sc,
                                                    const float* __restrict__ b_dc,
                                                    const float* __restrict__ b_scb,
                                                    const float* __restrict__ b_dcb,
                                                    const float* __restrict__ feats,
                                                    const int* __restrict__ list,
                                                    const int* __restrict__ pcnt,
                                                    bf16* __restrict__ WtFl,
                                                    float* __restrict__ pb,
                                                    bf16* __restrict__ h,
                                                    const int* __restrict__ dst0,
                                                    const int* __restrict__ dst1,
                                                    const int* __restrict__ fL1,
                                                    const int* __restrict__ idx2,
                                                    int* __restrict__ dega) {
    __shared__ float tile[32][33];
    const int b = blockIdx.x;
    const int t = threadIdx.x;
    if (b < TWT_BLOCKS) {
        const int z = b / 576, cell = b % 576;
        const int l = z >> 2, sel2 = z & 3;
        const float* src;
        if (sel2 == 0) src = w_sc; else if (sel2 == 1) src = w_scb;
        else if (sel2 == 2) src = w_dc; else src = w_dcb;
        src += (size_t)l * FDIM * FDIM;
        bf16* dst = WtFl + (size_t)z * FDIM * FDIM;
        const int tx = t & 31, ty = t >> 5;
        const int x0 = (cell % 24) * 32, y0 = (cell / 24) * 32;
#pragma unroll
        for (int q = 0; q < 4; ++q)
            tile[ty + q * 8][tx] = src[(size_t)(y0 + ty + q * 8) * FDIM + x0 + tx];
        __syncthreads();
#pragma unroll
        for (int q = 0; q < 4; ++q)
            dst[(size_t)(x0 + ty + q * 8) * FDIM + y0 + tx] = __float2bfloat16(tile[tx][ty + q * 8]);
    } else if (b < TWT_BLOCKS + BIAS_BLOCKS) {
        const int idx = (b - TWT_BLOCKS) * 256 + t;
        const int l = idx / NFUSE, c = idx % NFUSE;
        const int sel2 = c / FDIM, off = c % FDIM;
        const float* src;
        if (sel2 == 0) src = b_sc; else if (sel2 == 1) src = b_scb;
        else if (sel2 == 2) src = b_dc; else src = b_dcb;
        pb[idx] = src[l * FDIM + off];
    } else if (b < SETUP_BLOCKS) {
        int c = *pcnt; if (c > A1_CAP) c = A1_CAP;
        for (int i = b - TWT_BLOCKS - BIAS_BLOCKS; i < c; i += CVT_BLOCKS) {
            const int n = list[i];
            const float* s = feats + (size_t)n * FDIM;
            bf16* d = h + (size_t)n * FDIM;
            for (int k = t; k < FDIM; k += 256) d[k] = __float2bfloat16(s[k]);
        }
    } else {
        const int eb = b - SETUP_BLOCKS;
        const int r = (eb >= EB) ? 1 : 0;
        const int e = (eb - r * EB) * 256 + t;
        if (e < NE) {
            const int d = (r ? dst1 : dst0)[e];
            if (fL1[d]) atomicAdd(&dega[r * N1_CAP + idx2[d]], 1);
        }
    }
}

// ---------------- active scan: dega[2][N1_CAP] -> rowpa[2][N1_CAP+1], cursora ----------------
__global__ __launch_bounds__(256) void scana_kernel(const int* __restrict__ dega,
                                                    int* __restrict__ rowpa,
                                                    int* __restrict__ cursora) {
    __shared__ int part[256];
    const int t = threadIdx.x;
    for (int r = 0; r < 2; ++r) {
        const int base = r * N1_CAP;
        int loc[16];
        int s = 0;
#pragma unroll
        for (int q = 0; q < 16; ++q) { loc[q] = dega[base + t * 16 + q]; s += loc[q]; }
        part[t] = s;
        __syncthreads();
        for (int o = 1; o < 256; o <<= 1) {
            int x = (t >= o) ? part[t - o] : 0;
            __syncthreads();
            part[t] += x;
            __syncthreads();
        }
        int run = part[t] - s;  // exclusive prefix of this thread's chunk
        const int rbase = r * (N1_CAP + 1);
#pragma unroll
        for (int q = 0; q < 16; ++q) {
            rowpa[rbase + t * 16 + q] = run;
            cursora[base + t * 16 + q] = run;
            run += loc[q];
        }
        if (t == 255) rowpa[rbase + N1_CAP] = run;
        __syncthreads();
    }
}

__global__ __launch_bounds__(256) void scattera_kernel(const int* __restrict__ dst0,
                                                       const int* __restrict__ dst1,
                                                       const int* __restrict__ fL1,
                                                       const int* __restrict__ idx2,
                                                       int* __restrict__ cursora,
                                                       int* __restrict__ eida) {
    const int e = blockIdx.x * 256 + threadIdx.x;
    if (e >= NE) return;
    const int r = blockIdx.y;
    const int d = (r ? dst1 : dst0)[e];
    if (fL1[d]) {
        const int p = atomicAdd(&cursora[r * N1_CAP + idx2[d]], 1);
        eida[(size_t)r * NE + p] = e;
    }
}

// ---------------- two-job 128x128 MFMA GEMM (unchanged from round 12) ----------------
__global__ __launch_bounds__(256) void gemm2(const bf16* __restrict__ A,
                                             const bf16* __restrict__ Wt,
                                             const float* __restrict__ pb,
                                             bf16* __restrict__ C,
                                             const int* __restrict__ rlA,
                                             const int* __restrict__ cntAp, int capA,
                                             const int* __restrict__ rlB,
                                             const int* __restrict__ cntBp, int capB,
                                             const int* __restrict__ idxmap,
                                             int blocksA) {
    int bid = blockIdx.x;
    const int* rowlist;
    int cnt, col0;
    if (bid < blocksA) {
        rowlist = rlA; cnt = *cntAp; if (cnt > capA) cnt = capA; col0 = 0;
    } else {
        bid -= blocksA;
        rowlist = rlB; cnt = *cntBp; if (cnt > capB) cnt = capB; col0 = 1536;
    }
    const int tm = bid / GTN, tn = bid % GTN;
    const int m0 = tm * 128, n0 = tn * 128;
    if (m0 >= cnt) return;

    __shared__ __align__(16) short Abuf[128 * 64];
    __shared__ __align__(16) short Bbuf[128 * 64];
    const int t = threadIdx.x;
    const int wid = t >> 6, lane = t & 63;
    const int wr = wid >> 1, wc = wid & 1;
    const int lr = lane & 15, lk = lane >> 4;

    const f32x4 zero4 = {0.f, 0.f, 0.f, 0.f};
    f32x4 acc[4][4];
#pragma unroll
    for (int i = 0; i < 4; ++i)
#pragma unroll
        for (int j = 0; j < 4; ++j) acc[i][j] = zero4;

    int arow[4], brow[4], acol[4], ldsoff[4];
#pragma unroll
    for (int i = 0; i < 4; ++i) {
        const int s = i * 256 + t;
        const int rr = s >> 3, pch = s & 7;
        int ri = m0 + rr; if (ri >= cnt) ri = cnt - 1;
        arow[i] = rowlist[ri];
        brow[i] = col0 + n0 + rr;
        acol[i] = (pch ^ (rr & 7)) << 3;
        ldsoff[i] = (i * 256 + wid * 64) * 16;
    }

    for (int kt = 0; kt < FDIM / 64; ++kt) {
        const int k0 = kt * 64;
#pragma unroll
        for (int i = 0; i < 4; ++i) {
            load_lds16(A + (size_t)arow[i] * FDIM + k0 + acol[i], (char*)Abuf + ldsoff[i]);
            load_lds16(Wt + (size_t)brow[i] * FDIM + k0 + acol[i], (char*)Bbuf + ldsoff[i]);
        }
        __syncthreads();
#pragma unroll
        for (int kh = 0; kh < 2; ++kh) {
            bf16x8 av[4], bv[4];
            const int c = kh * 4 + lk;
#pragma unroll
            for (int i = 0; i < 4; ++i) {
                const int mm = wr * 64 + i * 16 + lr;
                av[i] = *(const bf16x8*)((const char*)Abuf + mm * 128 + ((c ^ (mm & 7)) << 4));
            }
#pragma unroll
            for (int j = 0; j < 4; ++j) {
                const int nn = wc * 64 + j * 16 + lr;
                bv[j] = *(const bf16x8*)((const char*)Bbuf + nn * 128 + ((c ^ (nn & 7)) << 4));
            }
#pragma unroll
            for (int i = 0; i < 4; ++i)
#pragma unroll
                for (int j = 0; j < 4; ++j)
                    acc[i][j] = __builtin_amdgcn_mfma_f32_16x16x32_bf16(bv[j], av[i], acc[i][j], 0, 0, 0);
        }
        __syncthreads();
    }

#pragma unroll
    for (int i = 0; i < 4; ++i) {
        const int row = m0 + wr * 64 + i * 16 + lr;
        if (row < cnt) {
            const int crow = idxmap[rowlist[row]];
#pragma unroll
            for (int j = 0; j < 4; ++j) {
                const int col = col0 + n0 + wc * 64 + j * 16 + lk * 4;
                const float4 b4 = *(const float4*)(pb + col);
                ushort4 w;
                w.x = f2u(acc[i][j][0] + b4.x);
                w.y = f2u(acc[i][j][1] + b4.y);
                w.z = f2u(acc[i][j][2] + b4.z);
                w.w = f2u(acc[i][j][3] + b4.w);
                *(ushort4*)(C + (size_t)crow * NFUSE + col) = w;
            }
        }
    }
}

// ---------------- online-softmax attention over an active-CSR row ----------------
__device__ inline void att_accum(const bf16* __restrict__ fsd, const int* __restrict__ idxsrc,
                                 int fdrow, int lane, const float* __restrict__ attn,
                                 int beg, int end,
                                 const int* __restrict__ eid, const int* __restrict__ src,
                                 int fs_off, int fd_off, float* __restrict__ out) {
    float fdv[12], atv[12];
    {
        const ushort4* pfd = (const ushort4*)(fsd + (size_t)fdrow * NFUSE + fd_off + lane * 12);
        const ushort4 d0 = pfd[0], d1 = pfd[1], d2 = pfd[2];
        fdv[0] = u2f(d0.x); fdv[1] = u2f(d0.y); fdv[2] = u2f(d0.z); fdv[3] = u2f(d0.w);
        fdv[4] = u2f(d1.x); fdv[5] = u2f(d1.y); fdv[6] = u2f(d1.z); fdv[7] = u2f(d1.w);
        fdv[8] = u2f(d2.x); fdv[9] = u2f(d2.y); fdv[10] = u2f(d2.z); fdv[11] = u2f(d2.w);
        const float4* pat = (const float4*)(attn + lane * 12);
        const float4 a0 = pat[0], a1 = pat[1], a2 = pat[2];
        atv[0] = a0.x; atv[1] = a0.y; atv[2] = a0.z; atv[3] = a0.w;
        atv[4] = a1.x; atv[5] = a1.y; atv[6] = a1.z; atv[7] = a1.w;
        atv[8] = a2.x; atv[9] = a2.y; atv[10] = a2.z; atv[11] = a2.w;
    }
    float m = -INFINITY, den = 0.f;
    float acc[12];
#pragma unroll
    for (int j = 0; j < 12; ++j) acc[j] = 0.f;

    for (int i = beg; i < end; ++i) {
        const int e = eid[i];
        const ushort4* pf = (const ushort4*)(fsd + (size_t)idxsrc[src[e]] * NFUSE + fs_off + lane * 12);
        const ushort4 a0 = pf[0], a1 = pf[1], a2 = pf[2];
        float fsv[12];
        fsv[0] = u2f(a0.x); fsv[1] = u2f(a0.y); fsv[2] = u2f(a0.z); fsv[3] = u2f(a0.w);
        fsv[4] = u2f(a1.x); fsv[5] = u2f(a1.y); fsv[6] = u2f(a1.z); fsv[7] = u2f(a1.w);
        fsv[8] = u2f(a2.x); fsv[9] = u2f(a2.y); fsv[10] = u2f(a2.z); fsv[11] = u2f(a2.w);
        float p = 0.f;
#pragma unroll
        for (int j = 0; j < 12; ++j) {
            float x = fsv[j] + fdv[j];
            x = (x > 0.f) ? x : 0.2f * x;
            p += x * atv[j];
        }
        p += __shfl_xor(p, 1);
        p += __shfl_xor(p, 2);
        p += __shfl_xor(p, 4);
        if (p > m) {
            const float sc = expf(m - p);
            den *= sc;
#pragma unroll
            for (int j = 0; j < 12; ++j) acc[j] *= sc;
            m = p;
        }
        const float w = expf(p - m);
        den += w;
#pragma unroll
        for (int j = 0; j < 12; ++j) acc[j] += w * fsv[j];
    }
    const float inv = (den > 0.f) ? 1.f / den : 0.f;
#pragma unroll
    for (int j = 0; j < 12; ++j) out[j] = acc[j] * inv;
}

// ---------------- layer-0 agg: h[n] = bf16(h + att_r0 + att_r1) over list2 ----------------
__global__ __launch_bounds__(256) void aggL_kernel(const bf16* __restrict__ fsd,
                                                   const int* __restrict__ idx1,
                                                   const float* __restrict__ attn0,
                                                   const float* __restrict__ attn1,
                                                   const int* __restrict__ rowpa,
                                                   const int* __restrict__ eida,
                                                   const int* __restrict__ src0,
                                                   const int* __restrict__ src1,
                                                   bf16* __restrict__ h,
                                                   const int* __restrict__ list2,
                                                   const int* __restrict__ pcnt) {
    const int wid = threadIdx.x >> 6;
    const int lane = threadIdx.x & 63;
    int cnt = *pcnt; if (cnt > N1_CAP) cnt = N1_CAP;
    const int i = blockIdx.x * 4 + wid;
    if (i >= cnt) return;
    const int n = list2[i];
    const int fdrow = idx1[n];

    float a0[12], a1[12];
    att_accum(fsd, idx1, fdrow, lane, attn0, rowpa[i], rowpa[i + 1],
              eida, src0, 0, 1536, a0);
    att_accum(fsd, idx1, fdrow, lane, attn1, rowpa[(N1_CAP + 1) + i], rowpa[(N1_CAP + 1) + i + 1],
              eida + NE, src1, 768, 2304, a1);

    const size_t base = (size_t)n * FDIM + lane * 12;
    const ushort4* ph = (const ushort4*)(h + base);
    const ushort4 h0 = ph[0], h1 = ph[1], h2 = ph[2];
    ushort4 r0, r1, r2;
    r0.x = f2u(u2f(h0.x) + a0[0] + a1[0]);  r0.y = f2u(u2f(h0.y) + a0[1] + a1[1]);
    r0.z = f2u(u2f(h0.z) + a0[2] + a1[2]);  r0.w = f2u(u2f(h0.w) + a0[3] + a1[3]);
    r1.x = f2u(u2f(h1.x) + a0[4] + a1[4]);  r1.y = f2u(u2f(h1.y) + a0[5] + a1[5]);
    r1.z = f2u(u2f(h1.z) + a0[6] + a1[6]);  r1.w = f2u(u2f(h1.w) + a0[7] + a1[7]);
    r2.x = f2u(u2f(h2.x) + a0[8] + a1[8]);  r2.y = f2u(u2f(h2.y) + a0[9] + a1[9]);
    r2.z = f2u(u2f(h2.z) + a0[10] + a1[10]); r2.w = f2u(u2f(h2.w) + a0[11] + a1[11]);
    ((ushort4*)(h + base))[0] = r0; ((ushort4*)(h + base))[1] = r1; ((ushort4*)(h + base))[2] = r2;
}

// ---------------- fused layer-1 agg + MLP head: block b -> batch element b ----------------
__global__ __launch_bounds__(256) void agghead_kernel(const bf16* __restrict__ fsd,
                                                      const int* __restrict__ idx2,
                                                      const float* __restrict__ attn0,
                                                      const float* __restrict__ attn1,
                                                      const int* __restrict__ rowpa,
                                                      const int* __restrict__ eida,
                                                      const int* __restrict__ src0,
                                                      const int* __restrict__ src1,
                                                      const bf16* __restrict__ h,
                                                      const int* __restrict__ gsi,
                                                      const float* __restrict__ fc1w,
                                                      const float* __restrict__ fc1b,
                                                      const float* __restrict__ fc2w,
                                                      const float* __restrict__ fc2b,
                                                      float* __restrict__ out) {
    __shared__ float a0s[FDIM], a1s[FDIM], fe[FDIM];
    __shared__ float hid[256];
    const int b = blockIdx.x, t = threadIdx.x;
    const int n = gsi[b];
    const int wv = t >> 6, lane = t & 63;
    if (wv < 2) {
        const int j = idx2[n];
        const int rb = wv * (N1_CAP + 1);
        float a[12];
        att_accum(fsd, idx2, j, lane, wv ? attn1 : attn0,
                  rowpa[rb + j], rowpa[rb + j + 1],
                  eida + (size_t)wv * NE, wv ? src1 : src0,
                  wv ? 768 : 0, wv ? 2304 : 1536, a);
        float* dl = wv ? a1s : a0s;
#pragma unroll
        for (int q = 0; q < 12; ++q) dl[lane * 12 + q] = a[q];
    }
    __syncthreads();
    for (int d = t; d < FDIM; d += 256)
        fe[d] = u2f(__bfloat16_as_ushort(h[(size_t)n * FDIM + d])) + a0s[d] + a1s[d];
    __syncthreads();
    float acc = fc1b[t];
    for (int k = 0; k < FDIM; ++k) acc += fe[k] * fc1w[k * 256 + t];
    hid[t] = (acc > 0.f) ? acc : 0.f;
    __syncthreads();
    if (t < NC) {
        float a2 = fc2b[t];
        for (int k = 0; k < 256; ++k) a2 += hid[k] * fc2w[k * NC + t];
        out[1 + b * NC + t] = a2;
    }
}

// ---------------- loss ----------------
__global__ __launch_bounds__(256) void loss_kernel(const float* __restrict__ logits,
                                                   const int* __restrict__ labels,
                                                   float* __restrict__ out) {
    __shared__ float red[256];
    const int b = threadIdx.x;
    float m = -INFINITY;
    for (int c = 0; c < NC; ++c) m = fmaxf(m, logits[b * NC + c]);
    float sum = 0.f;
    for (int c = 0; c < NC; ++c) sum += expf(logits[b * NC + c] - m);
    const float lse = m + logf(sum);
    const float ll = logits[b * NC + labels[b]];
    red[b] = lse - ll;
    __syncthreads();
    for (int s = 128; s > 0; s >>= 1) {
        if (b < s) red[b] += red[b + s];
        __syncthreads();
    }
    if (b == 0) out[0] = red[0] / (float)NB;
}

extern "C" void kernel_launch(void* const* d_in, const int* in_sizes, int n_in,
                              void* d_out, int out_size, void* d_ws, size_t ws_size,
                              hipStream_t stream) {
    const float* feats = (const float*)d_in[0];
    const float* fc1w  = (const float*)d_in[11];
    const float* fc1b  = (const float*)d_in[12];
    const float* fc2w  = (const float*)d_in[13];
    const float* fc2b  = (const float*)d_in[14];
    const int* src0    = (const int*)d_in[15];
    const int* dst0    = (const int*)d_in[16];
    const int* src1    = (const int*)d_in[17];
    const int* dst1    = (const int*)d_in[18];
    const int* gsi     = (const int*)d_in[19];
    const int* labels  = (const int*)d_in[20];

    const size_t NF = (size_t)N_NODES * FDIM;
    const size_t WSZ = (size_t)FDIM * FDIM;
    char* p = (char*)d_ws;
    bf16* h    = (bf16*)p;  p += NF * 2;
    bf16* fsd  = (bf16*)p;  p += (size_t)A1_CAP * NFUSE * 2;
    bf16* WtFl = (bf16*)p;  p += 8 * WSZ * 2;
    float* pb  = (float*)p; p += 2 * NFUSE * 4;
    // contiguous zero region: fA1, fL1, cnts, dega
    int* fA1  = (int*)p;    p += (size_t)N_NODES * 4;
    int* fL1  = (int*)p;    p += (size_t)N_NODES * 4;
    int* cnts = (int*)p;    p += 64 * 4;
    int* dega = (int*)p;    p += 2 * (size_t)N1_CAP * 4;
    const size_t zero_bytes = (2 * (size_t)N_NODES + 64 + 2 * (size_t)N1_CAP) * 4;
    int* idx1  = (int*)p;   p += (size_t)N_NODES * 4;
    int* idx2  = (int*)p;   p += (size_t)N_NODES * 4;
    int* list1 = (int*)p;   p += (size_t)A1_CAP * 4;
    int* list2 = (int*)p;   p += (size_t)N1_CAP * 4;
    int* list0 = (int*)p;   p += 256 * 4;
    int* rowpa = (int*)p;   p += 2 * ((size_t)N1_CAP + 1) * 4;
    int* cursora = (int*)p; p += 2 * (size_t)N1_CAP * 4;
    int* eida  = (int*)p;   p += 2 * (size_t)NE * 4;

    // 1. zero flags/cnts/dega
    hipMemsetAsync(fA1, 0, zero_bytes, stream);
    // 2. markA: gsi list0 + pass1 via bsearch
    markA_kernel<<<1 + 2 * EB, 256, 0, stream>>>(gsi, src0, dst0, src1, dst1, fL1, fA1, list0, cnts);
    // 3. markB: pass2
    markB_kernel<<<dim3(EB, 2), 256, 0, stream>>>(src0, dst0, src1, dst1, fL1, fA1);
    // 4. compact
    compact_kernel<<<NBLK, 256, 0, stream>>>(fA1, fL1, list1, idx1, list2, idx2, cnts);
    // 5. setup (twt + bias + cvt) + active hist
    setup_kernel<<<SETUPH_BLOCKS, 256, 0, stream>>>(
        (const float*)d_in[1], (const float*)d_in[3], (const float*)d_in[6], (const float*)d_in[8],
        (const float*)d_in[2], (const float*)d_in[4], (const float*)d_in[7], (const float*)d_in[9],
        feats, list1, &cnts[0], WtFl, pb, h, dst0, dst1, fL1, idx2, dega);
    // 6. active scan
    scana_kernel<<<1, 256, 0, stream>>>(dega, rowpa, cursora);
    // 7. active scatter
    scattera_kernel<<<dim3(EB, 2), 256, 0, stream>>>(dst0, dst1, fL1, idx2, cursora, eida);

    const int blocksA0 = (A1_CAP / 128) * GTN;
    const int blocksB0 = (N1_CAP / 128) * GTN;
    const int blocksA1 = (N1_CAP / 128) * GTN;
    const int blocksB1 = (256 / 128) * GTN;

    // 8-9. layer 0
    gemm2<<<blocksA0 + blocksB0, 256, 0, stream>>>(
        h, WtFl, pb, fsd,
        list1, &cnts[0], A1_CAP, list2, &cnts[1], N1_CAP, idx1, blocksA0);
    aggL_kernel<<<(N1_CAP + 3) / 4, 256, 0, stream>>>(
        fsd, idx1, (const float*)d_in[5], (const float*)d_in[10],
        rowpa, eida, src0, src1, h, list2, &cnts[1]);

    // 10-11. layer 1 + fused head
    gemm2<<<blocksA1 + blocksB1, 256, 0, stream>>>(
        h, WtFl + 4 * WSZ, pb + NFUSE, fsd,
        list2, &cnts[1], N1_CAP, list0, &cnts[2], 256, idx2, blocksA1);
    agghead_kernel<<<NB, 256, 0, stream>>>(
        fsd, idx2, (const float*)d_in[5] + FDIM, (const float*)d_in[10] + FDIM,
        rowpa, eida, src0, src1, h, gsi, fc1w, fc1b, fc2w, fc2b, (float*)d_out);

    // 12. loss
    loss_kernel<<<1, 256, 0, stream>>>((float*)d_out + 1, labels, (float*)d_out);
}